// Round 1
// baseline (460.949 us; speedup 1.0000x reference)
//
#include <hip/hip_runtime.h>
#include <math.h>

// Problem constants (fixed by setup_inputs)
#define BB 8
#define NN 128
#define AA 64
#define RR 32
#define RA 16
#define PP 8128            // N*(N-1)/2
#define DP 32
#define HH 512
#define EE 256
#define XDIM 2560          // RR*AA + RA*DP = 2048 + 512

// workspace layout (float offsets)
static constexpr size_t WS_PAIR  = 0;                          // B*P*DP      = 2,080,768
static constexpr size_t WS_X     = WS_PAIR + (size_t)BB*PP*DP; // B*N*XDIM    = 2,621,440
static constexpr size_t WS_GAVP  = WS_X    + (size_t)BB*NN*XDIM; // 8*B*2048*32 = 4,194,304
static constexpr size_t WS_MLP1P = WS_GAVP + (size_t)8*BB*2048*DP; // 2*1024*512 = 1,048,576

__device__ __forceinline__ float gelu_f(float x) {
    float u = 0.7978845608028654f * (x + 0.044715f * x * x * x);
    return 0.5f * x * (1.0f + tanhf(u));
}

// ---------------------------------------------------------------------------
// Kernel 1: pair MLP.  afv_pair = concat(ai+aj, ai*aj) -> gelu(x@cw1+cb1)@cw2+cb2
// grid 1016 (8 b * 127 pair-tiles of 64), block 256
// ---------------------------------------------------------------------------
__global__ __launch_bounds__(256) void pair_mlp_k(
    const float* __restrict__ afv, const float* __restrict__ cw1,
    const float* __restrict__ cb1, const float* __restrict__ cw2,
    const float* __restrict__ cb2, float* __restrict__ pair_out)
{
    __shared__ int ii_s[64], jj_s[64];
    __shared__ float Xs[64 * 132];   // X tile, later reused for H
    __shared__ float W1c[32 * 132];  // cw1 K-chunk
    const int bid = blockIdx.x;
    const int b = bid / 127;
    const int pbase = (bid % 127) * 64;
    const int t = threadIdx.x;

    if (t < 64) {
        int p = pbase + t;
        int i = 0;
        while (i < 126) {
            int nx = i + 1;
            int off = nx * 127 - (nx * (nx - 1)) / 2;
            if (off <= p) i = nx; else break;
        }
        int off = i * 127 - (i * (i - 1)) / 2;
        ii_s[t] = i;
        jj_s[t] = i + 1 + (p - off);
    }
    __syncthreads();
    // build X tile: X[pp][k<64]=ai+aj ; X[pp][64+k]=ai*aj
    {
        int pp = t & 63, seg = t >> 6;
        const float* ar = afv + (size_t)(b * NN + ii_s[pp]) * AA;
        const float* br = afv + (size_t)(b * NN + jj_s[pp]) * AA;
        #pragma unroll
        for (int kk = 0; kk < 16; ++kk) {
            int k = seg * 16 + kk;
            float x = ar[k], y = br[k];
            Xs[pp * 132 + k]      = x + y;
            Xs[pp * 132 + 64 + k] = x * y;
        }
    }
    const int tc = t & 15, tr = t >> 4;
    const int j0 = tc * 8, p0 = tr * 4;    // thread tile: 4 pairs x 8 hidden
    float acc[4][8];
    #pragma unroll
    for (int i = 0; i < 4; ++i)
        #pragma unroll
        for (int j = 0; j < 8; ++j) acc[i][j] = 0.f;

    for (int kc = 0; kc < 4; ++kc) {
        __syncthreads();
        #pragma unroll
        for (int pz = 0; pz < 4; ++pz) {
            int pos = t + pz * 256;            // 1024 float4 slots
            int kk = pos >> 5, j4 = (pos & 31) * 4;
            float4 v = *(const float4*)(cw1 + (size_t)(kc * 32 + kk) * 128 + j4);
            *(float4*)(W1c + kk * 132 + j4) = v;
        }
        __syncthreads();
        #pragma unroll 4
        for (int kk = 0; kk < 32; ++kk) {
            int k = kc * 32 + kk;
            float4 wa = *(const float4*)(W1c + kk * 132 + j0);
            float4 wb = *(const float4*)(W1c + kk * 132 + j0 + 4);
            float w[8] = {wa.x, wa.y, wa.z, wa.w, wb.x, wb.y, wb.z, wb.w};
            #pragma unroll
            for (int i = 0; i < 4; ++i) {
                float x = Xs[(p0 + i) * 132 + k];
                #pragma unroll
                for (int j = 0; j < 8; ++j) acc[i][j] += x * w[j];
            }
        }
    }
    // bias + gelu, write H into Xs (after everyone finished reading X)
    __syncthreads();
    #pragma unroll
    for (int i = 0; i < 4; ++i) {
        #pragma unroll
        for (int j = 0; j < 8; ++j) {
            float h = gelu_f(acc[i][j] + cb1[j0 + j]);
            Xs[(p0 + i) * 132 + j0 + j] = h;
        }
    }
    __syncthreads();
    // layer 2: H(64x128) @ cw2(128x32) + cb2
    const int d0 = (t & 7) * 4;
    const int q0 = (t >> 3) * 2;
    float a2[2][4];
    #pragma unroll
    for (int i = 0; i < 2; ++i)
        #pragma unroll
        for (int d = 0; d < 4; ++d) a2[i][d] = 0.f;
    #pragma unroll 4
    for (int k = 0; k < 128; ++k) {
        float4 w = *(const float4*)(cw2 + (size_t)k * 32 + d0);
        #pragma unroll
        for (int i = 0; i < 2; ++i) {
            float h = Xs[(q0 + i) * 132 + k];
            a2[i][0] += h * w.x; a2[i][1] += h * w.y;
            a2[i][2] += h * w.z; a2[i][3] += h * w.w;
        }
    }
    #pragma unroll
    for (int i = 0; i < 2; ++i) {
        float4 o;
        o.x = a2[i][0] + cb2[d0 + 0];
        o.y = a2[i][1] + cb2[d0 + 1];
        o.z = a2[i][2] + cb2[d0 + 2];
        o.w = a2[i][3] + cb2[d0 + 3];
        *(float4*)(pair_out + ((size_t)b * PP + pbase + q0 + i) * DP + d0) = o;
    }
}

// ---------------------------------------------------------------------------
// Kernel 2: grv = gr[b,n] (32x128) @ afv[b] (128x64) -> X[..., r*64+a]
// grid 1024 (b,n), block 256
// ---------------------------------------------------------------------------
__global__ __launch_bounds__(256) void grv_k(
    const float* __restrict__ gr, const float* __restrict__ afv,
    float* __restrict__ Xout)
{
    __shared__ float afvT[64 * 132];  // [a][m]
    __shared__ float grs[32 * 132];   // [r][m]
    const int bid = blockIdx.x;
    const int b = bid >> 7, n = bid & 127;
    const int t = threadIdx.x;
    #pragma unroll
    for (int pz = 0; pz < 8; ++pz) {
        int pos = t + pz * 256;          // 2048 f4: afv[b] 128x64
        int m = pos >> 4, a4 = (pos & 15) * 4;
        float4 v = *(const float4*)(afv + (size_t)(b * NN + m) * AA + a4);
        afvT[(a4 + 0) * 132 + m] = v.x;
        afvT[(a4 + 1) * 132 + m] = v.y;
        afvT[(a4 + 2) * 132 + m] = v.z;
        afvT[(a4 + 3) * 132 + m] = v.w;
    }
    #pragma unroll
    for (int pz = 0; pz < 4; ++pz) {
        int pos = t + pz * 256;          // 1024 f4: gr[b,n] 32x128
        int r = pos >> 5, m4 = (pos & 31) * 4;
        float4 v = *(const float4*)(gr + ((size_t)(b * NN + n) * RR + r) * NN + m4);
        *(float4*)(grs + r * 132 + m4) = v;
    }
    __syncthreads();
    const int a = t & 31, rg = t >> 5;   // cols {a, a+32}, rows rg*4+i
    float acc[4][2];
    #pragma unroll
    for (int i = 0; i < 4; ++i) { acc[i][0] = 0.f; acc[i][1] = 0.f; }
    for (int m4 = 0; m4 < 32; ++m4) {
        float4 va = *(const float4*)(afvT + a * 132 + m4 * 4);
        float4 vb = *(const float4*)(afvT + (a + 32) * 132 + m4 * 4);
        #pragma unroll
        for (int i = 0; i < 4; ++i) {
            float4 g = *(const float4*)(grs + (rg * 4 + i) * 132 + m4 * 4);
            acc[i][0] += g.x * va.x + g.y * va.y + g.z * va.z + g.w * va.w;
            acc[i][1] += g.x * vb.x + g.y * vb.y + g.z * vb.z + g.w * vb.w;
        }
    }
    float* xrow = Xout + (size_t)(b * NN + n) * XDIM;
    #pragma unroll
    for (int i = 0; i < 4; ++i) {
        xrow[(rg * 4 + i) * 64 + a]      = acc[i][0];
        xrow[(rg * 4 + i) * 64 + a + 32] = acc[i][1];
    }
}

// ---------------------------------------------------------------------------
// Kernel 3: gav partials.  Per b: (2048 x 8128) @ (8128 x 32), K split 8.
// grid 512 = b(8) x rowtile(8, 256 rows) x kchunk(8), block 256
// ---------------------------------------------------------------------------
__global__ __launch_bounds__(256) void gav_k(
    const float* __restrict__ ga, const float* __restrict__ pair,
    float* __restrict__ part)
{
    __shared__ float At[32 * 260];   // [kk][row], transposed A tile
    __shared__ float Bs[32 * 36];    // [kk][d]
    const int bid = blockIdx.x;
    const int c = bid & 7, rt = (bid >> 3) & 7, b = bid >> 6;
    const int rbase = rt * 256;
    const int kstart = c * 1024;
    const int kend = min(kstart + 1024, PP);
    const int t = threadIdx.x;
    const int tcv = t & 7, trv = t >> 3;
    const int r0 = trv * 8, d0 = tcv * 4;    // thread tile 8 rows x 4 cols
    float acc[8][4];
    #pragma unroll
    for (int i = 0; i < 8; ++i)
        #pragma unroll
        for (int d = 0; d < 4; ++d) acc[i][d] = 0.f;

    const float* gab = ga + (size_t)(b * 2048 + rbase) * PP;
    const float* pb = pair + (size_t)b * PP * DP;

    for (int k0 = kstart; k0 < kend; k0 += 32) {
        __syncthreads();
        #pragma unroll
        for (int pz = 0; pz < 8; ++pz) {
            int pos = t + pz * 256;          // 2048 f4: 256 rows x 8 slots
            int row = pos >> 3, f4i = (pos & 7) * 4;
            float4 v = *(const float4*)(gab + (size_t)row * PP + k0 + f4i);
            At[(f4i + 0) * 260 + row] = v.x;
            At[(f4i + 1) * 260 + row] = v.y;
            At[(f4i + 2) * 260 + row] = v.z;
            At[(f4i + 3) * 260 + row] = v.w;
        }
        {
            int kk = t >> 3, d4 = (t & 7) * 4;
            float4 v = *(const float4*)(pb + (size_t)(k0 + kk) * DP + d4);
            *(float4*)(Bs + kk * 36 + d4) = v;
        }
        __syncthreads();
        #pragma unroll 4
        for (int kk = 0; kk < 32; ++kk) {
            float4 alo = *(const float4*)(At + kk * 260 + r0);
            float4 ahi = *(const float4*)(At + kk * 260 + r0 + 4);
            float4 bv  = *(const float4*)(Bs + kk * 36 + d0);
            float av[8] = {alo.x, alo.y, alo.z, alo.w, ahi.x, ahi.y, ahi.z, ahi.w};
            float bb2[4] = {bv.x, bv.y, bv.z, bv.w};
            #pragma unroll
            for (int i = 0; i < 8; ++i)
                #pragma unroll
                for (int d = 0; d < 4; ++d) acc[i][d] += av[i] * bb2[d];
        }
    }
    float* pout = part + ((size_t)(c * 8 + b) * 2048 + rbase) * DP;
    #pragma unroll
    for (int i = 0; i < 8; ++i) {
        float4 o = make_float4(acc[i][0], acc[i][1], acc[i][2], acc[i][3]);
        *(float4*)(pout + (size_t)(r0 + i) * DP + d0) = o;
    }
}

// ---------------------------------------------------------------------------
// Kernel 4: reduce gav partials (8 chunks) -> X[..., 2048 + a*32 + d]
// grid 512, block 256 (1 float4 per thread)
// ---------------------------------------------------------------------------
__global__ __launch_bounds__(256) void gavred_k(
    const float* __restrict__ part, float* __restrict__ Xout)
{
    int idx = blockIdx.x * 256 + threadIdx.x;   // f4 index over 131072
    int e = idx * 4;
    int row = e >> 5;          // global row b*2048+r
    int d0 = e & 31;
    int b = row >> 11, r = row & 2047;
    float4 s = make_float4(0.f, 0.f, 0.f, 0.f);
    #pragma unroll
    for (int c = 0; c < 8; ++c) {
        float4 v = *(const float4*)(part + ((size_t)(c * 8 + b) * 2048 + r) * DP + d0);
        s.x += v.x; s.y += v.y; s.z += v.z; s.w += v.w;
    }
    int n = r >> 4, a = r & 15;
    *(float4*)(Xout + (size_t)(b * NN + n) * XDIM + 2048 + a * DP + d0) = s;
}

// ---------------------------------------------------------------------------
// Kernel 5: mlp layer1 partials: X(1024x2560) @ ew1(2560x512), K split 2
// grid 256 = rt(16, 64 rows) x ct(8, 64 cols) x c(2), block 256, thread 4x4
// ---------------------------------------------------------------------------
__global__ __launch_bounds__(256) void mlp1_k(
    const float* __restrict__ X, const float* __restrict__ ew1,
    float* __restrict__ part)
{
    __shared__ float At[32 * 68];   // [kk][row]
    __shared__ float Ws[32 * 68];   // [kk][j]
    const int bid = blockIdx.x;
    const int c = bid & 1, ct = (bid >> 1) & 7, rt = bid >> 4;
    const int rbase = rt * 64, jb = ct * 64;
    const int kstart = c * 1280;
    const int t = threadIdx.x;
    const int tcv = t & 15, trv = t >> 4;
    const int r0 = trv * 4, j0 = tcv * 4;
    float acc[4][4];
    #pragma unroll
    for (int i = 0; i < 4; ++i)
        #pragma unroll
        for (int j = 0; j < 4; ++j) acc[i][j] = 0.f;

    for (int k0 = kstart; k0 < kstart + 1280; k0 += 32) {
        __syncthreads();
        #pragma unroll
        for (int pz = 0; pz < 2; ++pz) {
            int pos = t + pz * 256;          // 512 f4: 64 rows x 8
            int row = pos >> 3, k4 = (pos & 7) * 4;
            float4 v = *(const float4*)(X + (size_t)(rbase + row) * XDIM + k0 + k4);
            At[(k4 + 0) * 68 + row] = v.x;
            At[(k4 + 1) * 68 + row] = v.y;
            At[(k4 + 2) * 68 + row] = v.z;
            At[(k4 + 3) * 68 + row] = v.w;
        }
        #pragma unroll
        for (int pz = 0; pz < 2; ++pz) {
            int pos = t + pz * 256;          // 512 f4: 32 kk x 16
            int kk = pos >> 4, j4 = (pos & 15) * 4;
            float4 v = *(const float4*)(ew1 + (size_t)(k0 + kk) * HH + jb + j4);
            *(float4*)(Ws + kk * 68 + j4) = v;
        }
        __syncthreads();
        #pragma unroll 4
        for (int kk = 0; kk < 32; ++kk) {
            float4 a4 = *(const float4*)(At + kk * 68 + r0);
            float4 w4 = *(const float4*)(Ws + kk * 68 + j0);
            float av[4] = {a4.x, a4.y, a4.z, a4.w};
            float wv[4] = {w4.x, w4.y, w4.z, w4.w};
            #pragma unroll
            for (int i = 0; i < 4; ++i)
                #pragma unroll
                for (int j = 0; j < 4; ++j) acc[i][j] += av[i] * wv[j];
        }
    }
    float* po = part + (size_t)c * 1024 * HH;
    #pragma unroll
    for (int i = 0; i < 4; ++i) {
        float4 o = make_float4(acc[i][0], acc[i][1], acc[i][2], acc[i][3]);
        *(float4*)(po + (size_t)(rbase + r0 + i) * HH + jb + j0) = o;
    }
}

// ---------------------------------------------------------------------------
// Kernel 6: reduce mlp1 partials + bias + gelu -> H tile; H @ ew2 + eb2 -> aef
// grid 64 (16 rows each), block 256
// ---------------------------------------------------------------------------
__global__ __launch_bounds__(256) void mlp2_k(
    const float* __restrict__ part, const float* __restrict__ eb1,
    const float* __restrict__ ew2, const float* __restrict__ eb2,
    float* __restrict__ out)
{
    __shared__ float Hs[16 * 516];
    const int rb = blockIdx.x;
    const int rbase = rb * 16;
    const int t = threadIdx.x;
    #pragma unroll
    for (int pz = 0; pz < 8; ++pz) {
        int pos = t + pz * 256;          // 2048 f4: 16 rows x 128
        int r = pos >> 7, j4 = (pos & 127) * 4;
        float4 v0 = *(const float4*)(part + (size_t)(rbase + r) * HH + j4);
        float4 v1 = *(const float4*)(part + (size_t)1024 * HH + (size_t)(rbase + r) * HH + j4);
        float4 bb = *(const float4*)(eb1 + j4);
        float4 h;
        h.x = gelu_f(v0.x + v1.x + bb.x);
        h.y = gelu_f(v0.y + v1.y + bb.y);
        h.z = gelu_f(v0.z + v1.z + bb.z);
        h.w = gelu_f(v0.w + v1.w + bb.w);
        *(float4*)(Hs + r * 516 + j4) = h;
    }
    __syncthreads();
    const int tcv = t & 31, trv = t >> 5;
    const int c0 = tcv * 8;                 // rows {trv, trv+8}, cols c0..c0+7
    float acc[2][8];
    #pragma unroll
    for (int i = 0; i < 2; ++i)
        #pragma unroll
        for (int j = 0; j < 8; ++j) acc[i][j] = 0.f;
    #pragma unroll 2
    for (int k = 0; k < HH; ++k) {
        float h0 = Hs[trv * 516 + k];
        float h1 = Hs[(trv + 8) * 516 + k];
        float4 wA = *(const float4*)(ew2 + (size_t)k * EE + c0);
        float4 wB = *(const float4*)(ew2 + (size_t)k * EE + c0 + 4);
        float w[8] = {wA.x, wA.y, wA.z, wA.w, wB.x, wB.y, wB.z, wB.w};
        #pragma unroll
        for (int j = 0; j < 8; ++j) {
            acc[0][j] += h0 * w[j];
            acc[1][j] += h1 * w[j];
        }
    }
    #pragma unroll
    for (int i = 0; i < 2; ++i) {
        int row = rbase + trv + i * 8;
        float4 oA, oB;
        oA.x = acc[i][0] + eb2[c0 + 0]; oA.y = acc[i][1] + eb2[c0 + 1];
        oA.z = acc[i][2] + eb2[c0 + 2]; oA.w = acc[i][3] + eb2[c0 + 3];
        oB.x = acc[i][4] + eb2[c0 + 4]; oB.y = acc[i][5] + eb2[c0 + 5];
        oB.z = acc[i][6] + eb2[c0 + 6]; oB.w = acc[i][7] + eb2[c0 + 7];
        *(float4*)(out + (size_t)row * EE + c0)     = oA;
        *(float4*)(out + (size_t)row * EE + c0 + 4) = oB;
    }
}

// ---------------------------------------------------------------------------
// Kernel 7: copy afv to second output
// ---------------------------------------------------------------------------
__global__ __launch_bounds__(256) void copy_afv_k(
    const float* __restrict__ afv, float* __restrict__ out)
{
    int idx = blockIdx.x * 256 + threadIdx.x;   // 16384 f4
    float4 v = *(const float4*)(afv + (size_t)idx * 4);
    *(float4*)(out + (size_t)idx * 4) = v;
}

extern "C" void kernel_launch(void* const* d_in, const int* in_sizes, int n_in,
                              void* d_out, int out_size, void* d_ws, size_t ws_size,
                              hipStream_t stream) {
    const float* gr  = (const float*)d_in[0];
    const float* ga  = (const float*)d_in[1];
    const float* afv = (const float*)d_in[2];
    const float* cw1 = (const float*)d_in[3];
    const float* cb1 = (const float*)d_in[4];
    const float* cw2 = (const float*)d_in[5];
    const float* cb2 = (const float*)d_in[6];
    const float* ew1 = (const float*)d_in[7];
    const float* eb1 = (const float*)d_in[8];
    const float* ew2 = (const float*)d_in[9];
    const float* eb2 = (const float*)d_in[10];
    float* out = (float*)d_out;
    float* ws = (float*)d_ws;

    float* pair  = ws + WS_PAIR;
    float* X     = ws + WS_X;
    float* gavp  = ws + WS_GAVP;
    float* mlp1p = ws + WS_MLP1P;

    pair_mlp_k<<<dim3(1016), dim3(256), 0, stream>>>(afv, cw1, cb1, cw2, cb2, pair);
    grv_k<<<dim3(1024), dim3(256), 0, stream>>>(gr, afv, X);
    gav_k<<<dim3(512), dim3(256), 0, stream>>>(ga, pair, gavp);
    gavred_k<<<dim3(512), dim3(256), 0, stream>>>(gavp, X);
    mlp1_k<<<dim3(256), dim3(256), 0, stream>>>(X, ew1, mlp1p);
    mlp2_k<<<dim3(64), dim3(256), 0, stream>>>(mlp1p, eb1, ew2, eb2, out);
    copy_afv_k<<<dim3(64), dim3(256), 0, stream>>>(afv, out + (size_t)BB * NN * EE);
}

// Round 2
// 365.751 us; speedup vs baseline: 1.2603x; 1.2603x over previous
//
#include <hip/hip_runtime.h>
#include <math.h>

// Problem constants (fixed by setup_inputs)
#define BB 8
#define NN 128
#define AA 64
#define RR 32
#define RA 16
#define PP 8128            // N*(N-1)/2
#define DP 32
#define HH 512
#define EE 256
#define XDIM 2560          // RR*AA + RA*DP = 2048 + 512

// workspace layout (float offsets)
static constexpr size_t WS_PAIR  = 0;                              // B*P*DP      = 2,080,768
static constexpr size_t WS_X     = WS_PAIR + (size_t)BB*PP*DP;     // B*N*XDIM    = 2,621,440
static constexpr size_t WS_GAVP  = WS_X    + (size_t)BB*NN*XDIM;   // 8*B*2048*32 = 4,194,304
static constexpr size_t WS_MLP1P = WS_GAVP + (size_t)8*BB*2048*DP; // 4*1024*512  = 2,097,152

__device__ __forceinline__ float gelu_f(float x) {
    float u = 0.7978845608028654f * (x + 0.044715f * x * x * x);
    return 0.5f * x * (1.0f + tanhf(u));
}

// ---------------------------------------------------------------------------
// Kernel 1: pair MLP.  afv_pair = concat(ai+aj, ai*aj) -> gelu(x@cw1+cb1)@cw2+cb2
// grid 1016 (8 b * 127 pair-tiles of 64), block 256
// ---------------------------------------------------------------------------
__global__ __launch_bounds__(256) void pair_mlp_k(
    const float* __restrict__ afv, const float* __restrict__ cw1,
    const float* __restrict__ cb1, const float* __restrict__ cw2,
    const float* __restrict__ cb2, float* __restrict__ pair_out)
{
    __shared__ int ii_s[64], jj_s[64];
    __shared__ float Xs[64 * 132];   // X tile, later reused for H
    __shared__ float W1c[32 * 132];  // cw1 K-chunk
    const int bid = blockIdx.x;
    const int b = bid / 127;
    const int pbase = (bid % 127) * 64;
    const int t = threadIdx.x;

    if (t < 64) {
        int p = pbase + t;
        int i = 0;
        while (i < 126) {
            int nx = i + 1;
            int off = nx * 127 - (nx * (nx - 1)) / 2;
            if (off <= p) i = nx; else break;
        }
        int off = i * 127 - (i * (i - 1)) / 2;
        ii_s[t] = i;
        jj_s[t] = i + 1 + (p - off);
    }
    __syncthreads();
    // build X tile: X[pp][k<64]=ai+aj ; X[pp][64+k]=ai*aj
    {
        int pp = t & 63, seg = t >> 6;
        const float* ar = afv + (size_t)(b * NN + ii_s[pp]) * AA;
        const float* br = afv + (size_t)(b * NN + jj_s[pp]) * AA;
        #pragma unroll
        for (int kk = 0; kk < 16; ++kk) {
            int k = seg * 16 + kk;
            float x = ar[k], y = br[k];
            Xs[pp * 132 + k]      = x + y;
            Xs[pp * 132 + 64 + k] = x * y;
        }
    }
    const int tc = t & 15, tr = t >> 4;
    const int j0 = tc * 8, p0 = tr * 4;    // thread tile: 4 pairs x 8 hidden
    float acc[4][8];
    #pragma unroll
    for (int i = 0; i < 4; ++i)
        #pragma unroll
        for (int j = 0; j < 8; ++j) acc[i][j] = 0.f;

    for (int kc = 0; kc < 4; ++kc) {
        __syncthreads();
        #pragma unroll
        for (int pz = 0; pz < 4; ++pz) {
            int pos = t + pz * 256;            // 1024 float4 slots
            int kk = pos >> 5, j4 = (pos & 31) * 4;
            float4 v = *(const float4*)(cw1 + (size_t)(kc * 32 + kk) * 128 + j4);
            *(float4*)(W1c + kk * 132 + j4) = v;
        }
        __syncthreads();
        #pragma unroll 4
        for (int kk = 0; kk < 32; ++kk) {
            int k = kc * 32 + kk;
            float4 wa = *(const float4*)(W1c + kk * 132 + j0);
            float4 wb = *(const float4*)(W1c + kk * 132 + j0 + 4);
            float w[8] = {wa.x, wa.y, wa.z, wa.w, wb.x, wb.y, wb.z, wb.w};
            #pragma unroll
            for (int i = 0; i < 4; ++i) {
                float x = Xs[(p0 + i) * 132 + k];
                #pragma unroll
                for (int j = 0; j < 8; ++j) acc[i][j] += x * w[j];
            }
        }
    }
    // bias + gelu, write H into Xs (after everyone finished reading X)
    __syncthreads();
    #pragma unroll
    for (int i = 0; i < 4; ++i) {
        #pragma unroll
        for (int j = 0; j < 8; ++j) {
            float h = gelu_f(acc[i][j] + cb1[j0 + j]);
            Xs[(p0 + i) * 132 + j0 + j] = h;
        }
    }
    __syncthreads();
    // layer 2: H(64x128) @ cw2(128x32) + cb2
    const int d0 = (t & 7) * 4;
    const int q0 = (t >> 3) * 2;
    float a2[2][4];
    #pragma unroll
    for (int i = 0; i < 2; ++i)
        #pragma unroll
        for (int d = 0; d < 4; ++d) a2[i][d] = 0.f;
    #pragma unroll 4
    for (int k = 0; k < 128; ++k) {
        float4 w = *(const float4*)(cw2 + (size_t)k * 32 + d0);
        #pragma unroll
        for (int i = 0; i < 2; ++i) {
            float h = Xs[(q0 + i) * 132 + k];
            a2[i][0] += h * w.x; a2[i][1] += h * w.y;
            a2[i][2] += h * w.z; a2[i][3] += h * w.w;
        }
    }
    #pragma unroll
    for (int i = 0; i < 2; ++i) {
        float4 o;
        o.x = a2[i][0] + cb2[d0 + 0];
        o.y = a2[i][1] + cb2[d0 + 1];
        o.z = a2[i][2] + cb2[d0 + 2];
        o.w = a2[i][3] + cb2[d0 + 3];
        *(float4*)(pair_out + ((size_t)b * PP + pbase + q0 + i) * DP + d0) = o;
    }
}

// ---------------------------------------------------------------------------
// Kernel 2: grv = gr[b,n] (32x128) @ afv[b] (128x64) -> X[..., r*64+a]
// Also copies afv into out2 (fused former copy kernel).
// grid 1024 (b,n), block 256
// ---------------------------------------------------------------------------
__global__ __launch_bounds__(256) void grv_k(
    const float* __restrict__ gr, const float* __restrict__ afv,
    float* __restrict__ Xout, float* __restrict__ out2)
{
    __shared__ float afvT[64 * 132];  // [a][m]
    __shared__ float grs[32 * 132];   // [r][m]
    const int bid = blockIdx.x;
    const int b = bid >> 7, n = bid & 127;
    const int t = threadIdx.x;
    #pragma unroll
    for (int pz = 0; pz < 8; ++pz) {
        int pos = t + pz * 256;          // 2048 f4: afv[b] 128x64
        int m = pos >> 4, a4 = (pos & 15) * 4;
        float4 v = *(const float4*)(afv + (size_t)(b * NN + m) * AA + a4);
        afvT[(a4 + 0) * 132 + m] = v.x;
        afvT[(a4 + 1) * 132 + m] = v.y;
        afvT[(a4 + 2) * 132 + m] = v.z;
        afvT[(a4 + 3) * 132 + m] = v.w;
    }
    #pragma unroll
    for (int pz = 0; pz < 4; ++pz) {
        int pos = t + pz * 256;          // 1024 f4: gr[b,n] 32x128
        int r = pos >> 5, m4 = (pos & 31) * 4;
        float4 v = *(const float4*)(gr + ((size_t)(b * NN + n) * RR + r) * NN + m4);
        *(float4*)(grs + r * 132 + m4) = v;
    }
    // fused copy of afv row (b,n) to second output
    if (t < 16) {
        float4 v = *(const float4*)(afv + (size_t)(b * NN + n) * AA + t * 4);
        *(float4*)(out2 + (size_t)(b * NN + n) * AA + t * 4) = v;
    }
    __syncthreads();
    const int a = t & 31, rg = t >> 5;   // cols {a, a+32}, rows rg*4+i
    float acc[4][2];
    #pragma unroll
    for (int i = 0; i < 4; ++i) { acc[i][0] = 0.f; acc[i][1] = 0.f; }
    for (int m4 = 0; m4 < 32; ++m4) {
        float4 va = *(const float4*)(afvT + a * 132 + m4 * 4);
        float4 vb = *(const float4*)(afvT + (a + 32) * 132 + m4 * 4);
        #pragma unroll
        for (int i = 0; i < 4; ++i) {
            float4 g = *(const float4*)(grs + (rg * 4 + i) * 132 + m4 * 4);
            acc[i][0] += g.x * va.x + g.y * va.y + g.z * va.z + g.w * va.w;
            acc[i][1] += g.x * vb.x + g.y * vb.y + g.z * vb.z + g.w * vb.w;
        }
    }
    float* xrow = Xout + (size_t)(b * NN + n) * XDIM;
    #pragma unroll
    for (int i = 0; i < 4; ++i) {
        xrow[(rg * 4 + i) * 64 + a]      = acc[i][0];
        xrow[(rg * 4 + i) * 64 + a + 32] = acc[i][1];
    }
}

// ---------------------------------------------------------------------------
// Kernel 3: gav partials.  Per b: (2048 x 8128) @ (8128 x 32), K split 8.
// 2-phase reg-staged pipeline: issue next tile's loads before FMA phase.
// grid 1024 = b(8) x rowtile(16, 128 rows) x kchunk(8), block 256, 4 blk/CU
// ---------------------------------------------------------------------------
__global__ __launch_bounds__(256, 4) void gav_k(
    const float* __restrict__ ga, const float* __restrict__ pair,
    float* __restrict__ part)
{
    __shared__ float At[32 * 132];   // [kk][row], transposed A tile (128 rows)
    __shared__ float Bs[32 * 36];    // [kk][d]
    const int bid = blockIdx.x;
    const int c = bid & 7, rt = (bid >> 3) & 15, b = bid >> 7;
    const int rbase = rt * 128;
    const int kstart = c * 1024;
    const int kend = (kstart + 1024 < PP) ? (kstart + 1024) : PP;
    const int niter = (kend - kstart) >> 5;       // 32 (c<7) or 30 (c==7)
    const int t = threadIdx.x;
    const int trow = t >> 3, slot = t & 7;        // staging coords
    const int trv = t >> 3, tcv = t & 7;
    const int r0 = trv * 4, d0 = tcv * 4;         // thread tile 4 rows x 4 cols
    float acc[4][4];
    #pragma unroll
    for (int i = 0; i < 4; ++i)
        #pragma unroll
        for (int d = 0; d < 4; ++d) acc[i][d] = 0.f;

    const float* gab = ga + (size_t)(b * 2048 + rbase) * PP;
    const float* pb = pair + (size_t)b * PP * DP;

    // prologue: stage iter 0 into regs
    float4 ra[4], rb;
    #pragma unroll
    for (int pz = 0; pz < 4; ++pz) {
        int row = trow + 32 * pz;
        ra[pz] = *(const float4*)(gab + (size_t)row * PP + kstart + slot * 4);
    }
    rb = *(const float4*)(pb + (size_t)(kstart + trow) * DP + slot * 4);

    for (int it = 0; it < niter; ++it) {
        const int k = kstart + it * 32;
        __syncthreads();   // previous FMA phase done reading LDS
        // write staged regs -> LDS (vmcnt wait lands here; loads issued one
        // full FMA phase ago so latency is hidden)
        #pragma unroll
        for (int pz = 0; pz < 4; ++pz) {
            int row = trow + 32 * pz;
            int sb = slot * 4;
            At[(sb + 0) * 132 + row] = ra[pz].x;
            At[(sb + 1) * 132 + row] = ra[pz].y;
            At[(sb + 2) * 132 + row] = ra[pz].z;
            At[(sb + 3) * 132 + row] = ra[pz].w;
        }
        *(float4*)(Bs + trow * 36 + slot * 4) = rb;
        __syncthreads();
        // issue next tile's loads (no wait — consumed next iter)
        if (it + 1 < niter) {
            int kn = k + 32;
            #pragma unroll
            for (int pz = 0; pz < 4; ++pz) {
                int row = trow + 32 * pz;
                ra[pz] = *(const float4*)(gab + (size_t)row * PP + kn + slot * 4);
            }
            rb = *(const float4*)(pb + (size_t)(kn + trow) * DP + slot * 4);
        }
        // FMA phase (broadcast-friendly LDS reads)
        #pragma unroll 8
        for (int kk = 0; kk < 32; ++kk) {
            float4 a4 = *(const float4*)(At + kk * 132 + r0);
            float4 b4 = *(const float4*)(Bs + kk * 36 + d0);
            float av[4] = {a4.x, a4.y, a4.z, a4.w};
            float bv[4] = {b4.x, b4.y, b4.z, b4.w};
            #pragma unroll
            for (int i = 0; i < 4; ++i)
                #pragma unroll
                for (int d = 0; d < 4; ++d) acc[i][d] += av[i] * bv[d];
        }
    }
    float* pout = part + ((size_t)(c * 8 + b) * 2048 + rbase) * DP;
    #pragma unroll
    for (int i = 0; i < 4; ++i) {
        float4 o = make_float4(acc[i][0], acc[i][1], acc[i][2], acc[i][3]);
        *(float4*)(pout + (size_t)(r0 + i) * DP + d0) = o;
    }
}

// ---------------------------------------------------------------------------
// Kernel 4: reduce gav partials (8 chunks) -> X[..., 2048 + a*32 + d]
// grid 512, block 256 (1 float4 per thread)
// ---------------------------------------------------------------------------
__global__ __launch_bounds__(256) void gavred_k(
    const float* __restrict__ part, float* __restrict__ Xout)
{
    int idx = blockIdx.x * 256 + threadIdx.x;   // f4 index over 131072
    int e = idx * 4;
    int row = e >> 5;          // global row b*2048+r
    int d0 = e & 31;
    int b = row >> 11, r = row & 2047;
    float4 s = make_float4(0.f, 0.f, 0.f, 0.f);
    #pragma unroll
    for (int c = 0; c < 8; ++c) {
        float4 v = *(const float4*)(part + ((size_t)(c * 8 + b) * 2048 + r) * DP + d0);
        s.x += v.x; s.y += v.y; s.z += v.z; s.w += v.w;
    }
    int n = r >> 4, a = r & 15;
    *(float4*)(Xout + (size_t)(b * NN + n) * XDIM + 2048 + a * DP + d0) = s;
}

// ---------------------------------------------------------------------------
// Kernel 5: mlp layer1 partials: X(1024x2560) @ ew1(2560x512), K split 4
// 2-phase reg-staged pipeline like gav_k.
// grid 512 = rt(16, 64 rows) x ct(8, 64 cols) x c(4), block 256, thread 4x4
// ---------------------------------------------------------------------------
__global__ __launch_bounds__(256) void mlp1_k(
    const float* __restrict__ X, const float* __restrict__ ew1,
    float* __restrict__ part)
{
    __shared__ float Xt[32 * 68];   // [kk][row]
    __shared__ float Ws[32 * 68];   // [kk][j]
    const int bid = blockIdx.x;
    const int c = bid & 3, ct = (bid >> 2) & 7, rt = bid >> 5;
    const int rbase = rt * 64, jb = ct * 64;
    const int kstart = c * 640;                   // 20 iters of 32
    const int t = threadIdx.x;
    const int tcv = t & 15, trv = t >> 4;
    const int r0 = trv * 4, j0 = tcv * 4;
    float acc[4][4];
    #pragma unroll
    for (int i = 0; i < 4; ++i)
        #pragma unroll
        for (int j = 0; j < 4; ++j) acc[i][j] = 0.f;

    // staging coords
    const int xrow_lo = t >> 3, xslot = t & 7;    // X: 64 rows x 8 f4-slots
    const int wkk_lo = t >> 4, wj4 = (t & 15) * 4;// W: 32 kk x 16 f4-slots

    float4 rx[2], rw[2];
    #pragma unroll
    for (int pz = 0; pz < 2; ++pz) {
        int row = xrow_lo + 32 * pz;
        rx[pz] = *(const float4*)(X + (size_t)(rbase + row) * XDIM + kstart + xslot * 4);
        int kk = wkk_lo + 16 * pz;
        rw[pz] = *(const float4*)(ew1 + (size_t)(kstart + kk) * HH + jb + wj4);
    }

    for (int it = 0; it < 20; ++it) {
        const int k = kstart + it * 32;
        __syncthreads();
        #pragma unroll
        for (int pz = 0; pz < 2; ++pz) {
            int row = xrow_lo + 32 * pz;
            int sb = xslot * 4;
            Xt[(sb + 0) * 68 + row] = rx[pz].x;
            Xt[(sb + 1) * 68 + row] = rx[pz].y;
            Xt[(sb + 2) * 68 + row] = rx[pz].z;
            Xt[(sb + 3) * 68 + row] = rx[pz].w;
            int kk = wkk_lo + 16 * pz;
            *(float4*)(Ws + kk * 68 + wj4) = rw[pz];
        }
        __syncthreads();
        if (it + 1 < 20) {
            int kn = k + 32;
            #pragma unroll
            for (int pz = 0; pz < 2; ++pz) {
                int row = xrow_lo + 32 * pz;
                rx[pz] = *(const float4*)(X + (size_t)(rbase + row) * XDIM + kn + xslot * 4);
                int kk = wkk_lo + 16 * pz;
                rw[pz] = *(const float4*)(ew1 + (size_t)(kn + kk) * HH + jb + wj4);
            }
        }
        #pragma unroll 8
        for (int kk = 0; kk < 32; ++kk) {
            float4 a4 = *(const float4*)(Xt + kk * 68 + r0);
            float4 w4 = *(const float4*)(Ws + kk * 68 + j0);
            float av[4] = {a4.x, a4.y, a4.z, a4.w};
            float wv[4] = {w4.x, w4.y, w4.z, w4.w};
            #pragma unroll
            for (int i = 0; i < 4; ++i)
                #pragma unroll
                for (int j = 0; j < 4; ++j) acc[i][j] += av[i] * wv[j];
        }
    }
    float* po = part + (size_t)c * 1024 * HH;
    #pragma unroll
    for (int i = 0; i < 4; ++i) {
        float4 o = make_float4(acc[i][0], acc[i][1], acc[i][2], acc[i][3]);
        *(float4*)(po + (size_t)(rbase + r0 + i) * HH + jb + j0) = o;
    }
}

// ---------------------------------------------------------------------------
// Kernel 6: reduce mlp1 partials (4) + bias + gelu -> H tile; H @ ew2 + eb2 -> aef
// grid 256 (4 rows each), block 256
// ---------------------------------------------------------------------------
__global__ __launch_bounds__(256) void mlp2_k(
    const float* __restrict__ part, const float* __restrict__ eb1,
    const float* __restrict__ ew2, const float* __restrict__ eb2,
    float* __restrict__ out)
{
    __shared__ float Hs[4 * 520];
    const int rbase = blockIdx.x * 4;
    const int t = threadIdx.x;
    #pragma unroll
    for (int pz = 0; pz < 2; ++pz) {
        int pos = t + pz * 256;          // 512 f4: 4 rows x 128
        int r = pos >> 7, j4 = (pos & 127) * 4;
        float4 s = *(const float4*)(eb1 + j4);
        #pragma unroll
        for (int cc = 0; cc < 4; ++cc) {
            float4 v = *(const float4*)(part + (size_t)cc * 1024 * HH +
                                        (size_t)(rbase + r) * HH + j4);
            s.x += v.x; s.y += v.y; s.z += v.z; s.w += v.w;
        }
        float4 h;
        h.x = gelu_f(s.x); h.y = gelu_f(s.y);
        h.z = gelu_f(s.z); h.w = gelu_f(s.w);
        *(float4*)(Hs + r * 520 + j4) = h;
    }
    __syncthreads();
    const int row = t >> 6;              // 0..3
    const int c0 = (t & 63) * 4;         // 0..252
    float4 a = make_float4(0.f, 0.f, 0.f, 0.f);
    #pragma unroll 4
    for (int k = 0; k < HH; ++k) {
        float h = Hs[row * 520 + k];
        float4 w = *(const float4*)(ew2 + (size_t)k * EE + c0);
        a.x += h * w.x; a.y += h * w.y; a.z += h * w.z; a.w += h * w.w;
    }
    float4 bb = *(const float4*)(eb2 + c0);
    a.x += bb.x; a.y += bb.y; a.z += bb.z; a.w += bb.w;
    *(float4*)(out + (size_t)(rbase + row) * EE + c0) = a;
}

extern "C" void kernel_launch(void* const* d_in, const int* in_sizes, int n_in,
                              void* d_out, int out_size, void* d_ws, size_t ws_size,
                              hipStream_t stream) {
    const float* gr  = (const float*)d_in[0];
    const float* ga  = (const float*)d_in[1];
    const float* afv = (const float*)d_in[2];
    const float* cw1 = (const float*)d_in[3];
    const float* cb1 = (const float*)d_in[4];
    const float* cw2 = (const float*)d_in[5];
    const float* cb2 = (const float*)d_in[6];
    const float* ew1 = (const float*)d_in[7];
    const float* eb1 = (const float*)d_in[8];
    const float* ew2 = (const float*)d_in[9];
    const float* eb2 = (const float*)d_in[10];
    float* out = (float*)d_out;
    float* ws = (float*)d_ws;

    float* pair  = ws + WS_PAIR;
    float* X     = ws + WS_X;
    float* gavp  = ws + WS_GAVP;
    float* mlp1p = ws + WS_MLP1P;

    pair_mlp_k<<<dim3(1016), dim3(256), 0, stream>>>(afv, cw1, cb1, cw2, cb2, pair);
    grv_k<<<dim3(1024), dim3(256), 0, stream>>>(gr, afv, X, out + (size_t)BB * NN * EE);
    gav_k<<<dim3(1024), dim3(256), 0, stream>>>(ga, pair, gavp);
    gavred_k<<<dim3(512), dim3(256), 0, stream>>>(gavp, X);
    mlp1_k<<<dim3(512), dim3(256), 0, stream>>>(X, ew1, mlp1p);
    mlp2_k<<<dim3(256), dim3(256), 0, stream>>>(mlp1p, eb1, ew2, eb2, out);
}

// Round 3
// 316.851 us; speedup vs baseline: 1.4548x; 1.1543x over previous
//
#include <hip/hip_runtime.h>
#include <math.h>

// Problem constants (fixed by setup_inputs)
#define BB 8
#define NN 128
#define AA 64
#define RR 32
#define RA 16
#define PP 8128            // N*(N-1)/2
#define DP 32
#define HH 512
#define EE 256
#define XDIM 2560          // RR*AA + RA*DP = 2048 + 512

// workspace layout (float offsets)
static constexpr size_t WS_PAIR  = 0;                              // B*P*DP      = 2,080,768
static constexpr size_t WS_X     = WS_PAIR + (size_t)BB*PP*DP;     // B*N*XDIM    = 2,621,440
static constexpr size_t WS_GAVP  = WS_X    + (size_t)BB*NN*XDIM;   // 8*B*2048*32 = 4,194,304
static constexpr size_t WS_MLP1P = WS_GAVP + (size_t)8*BB*2048*DP; // 4*1024*512  = 2,097,152

// fast, numerically-stable gelu (tanh approx, matches jax.nn.gelu approximate)
__device__ __forceinline__ float gelu_f(float x) {
    float u = 0.7978845608028654f * (x + 0.044715f * x * x * x);
    float au = fabsf(u);
    float e = __expf(-2.0f * au);
    float th = (1.0f - e) / (1.0f + e);
    th = copysignf(th, u);
    return 0.5f * x * (1.0f + th);
}

// ---------------------------------------------------------------------------
// Kernel A: fused stage-1.
//   blocks [0,1016): pair MLP -> pair_out
//   blocks [1016,2040): grv einsum -> X[..., 0:2048], + afv copy to out2
// block 256
// ---------------------------------------------------------------------------
#define GRVS 136   // padded stride for grv tiles (word-stride 34 == 2 mod 32)

__global__ __launch_bounds__(256) void stage1_k(
    const float* __restrict__ afv, const float* __restrict__ cw1,
    const float* __restrict__ cb1, const float* __restrict__ cw2,
    const float* __restrict__ cb2, float* __restrict__ pair_out,
    const float* __restrict__ gr, float* __restrict__ Xout,
    float* __restrict__ out2)
{
    __shared__ float smem[64 * GRVS + 32 * GRVS + 128];  // 13184 floats = 52.7 KB
    const int bid = blockIdx.x;
    const int t = threadIdx.x;

    if (bid < 1016) {
        // ---------------- pair MLP path ----------------
        float* Xs  = smem;                 // [64][132]  X tile, later H tile
        float* W1c = smem + 64 * 132;      // [32][132]  cw1 K-chunk
        int*   ii_s = (int*)(smem + 64 * 132 + 32 * 132);
        int*   jj_s = ii_s + 64;
        const int b = bid / 127;
        const int pbase = (bid % 127) * 64;

        if (t < 64) {
            int p = pbase + t;
            int i = 0;
            while (i < 126) {
                int nx = i + 1;
                int off = nx * 127 - (nx * (nx - 1)) / 2;
                if (off <= p) i = nx; else break;
            }
            int off = i * 127 - (i * (i - 1)) / 2;
            ii_s[t] = i;
            jj_s[t] = i + 1 + (p - off);
        }
        __syncthreads();
        // build X tile vectorized: X[pp][k<64]=ai+aj ; X[pp][64+k]=ai*aj
        {
            int pp = t & 63, seg = t >> 6;   // seg 0..3 -> k seg*16..+15
            const float* ar = afv + (size_t)(b * NN + ii_s[pp]) * AA + seg * 16;
            const float* br = afv + (size_t)(b * NN + jj_s[pp]) * AA + seg * 16;
            #pragma unroll
            for (int i = 0; i < 4; ++i) {
                float4 x = *(const float4*)(ar + i * 4);
                float4 y = *(const float4*)(br + i * 4);
                float4 s = make_float4(x.x + y.x, x.y + y.y, x.z + y.z, x.w + y.w);
                float4 p = make_float4(x.x * y.x, x.y * y.y, x.z * y.z, x.w * y.w);
                *(float4*)(Xs + pp * 132 + seg * 16 + i * 4) = s;
                *(float4*)(Xs + pp * 132 + 64 + seg * 16 + i * 4) = p;
            }
        }
        const int tc = t & 15, tr = t >> 4;
        const int c0 = tc * 4, p0 = tr * 4;   // cols {c0..c0+3, 64+c0..}, rows p0..p0+3
        float acc[4][8];
        #pragma unroll
        for (int i = 0; i < 4; ++i)
            #pragma unroll
            for (int j = 0; j < 8; ++j) acc[i][j] = 0.f;

        for (int kc = 0; kc < 4; ++kc) {
            __syncthreads();
            #pragma unroll
            for (int pz = 0; pz < 4; ++pz) {
                int pos = t + pz * 256;            // 1024 float4 slots
                int kk = pos >> 5, j4 = (pos & 31) * 4;
                float4 v = *(const float4*)(cw1 + (size_t)(kc * 32 + kk) * 128 + j4);
                *(float4*)(W1c + kk * 132 + j4) = v;
            }
            __syncthreads();
            #pragma unroll 4
            for (int kk = 0; kk < 32; ++kk) {
                int k = kc * 32 + kk;
                float4 wa = *(const float4*)(W1c + kk * 132 + c0);       // 2-way, free
                float4 wb = *(const float4*)(W1c + kk * 132 + 64 + c0);
                float w[8] = {wa.x, wa.y, wa.z, wa.w, wb.x, wb.y, wb.z, wb.w};
                #pragma unroll
                for (int i = 0; i < 4; ++i) {
                    float x = Xs[(p0 + i) * 132 + k];                    // broadcast
                    #pragma unroll
                    for (int j = 0; j < 8; ++j) acc[i][j] += x * w[j];
                }
            }
        }
        __syncthreads();
        // bias + gelu, write H into Xs
        #pragma unroll
        for (int i = 0; i < 4; ++i) {
            float4 ha, hb;
            ha.x = gelu_f(acc[i][0] + cb1[c0 + 0]);
            ha.y = gelu_f(acc[i][1] + cb1[c0 + 1]);
            ha.z = gelu_f(acc[i][2] + cb1[c0 + 2]);
            ha.w = gelu_f(acc[i][3] + cb1[c0 + 3]);
            hb.x = gelu_f(acc[i][4] + cb1[64 + c0 + 0]);
            hb.y = gelu_f(acc[i][5] + cb1[64 + c0 + 1]);
            hb.z = gelu_f(acc[i][6] + cb1[64 + c0 + 2]);
            hb.w = gelu_f(acc[i][7] + cb1[64 + c0 + 3]);
            *(float4*)(Xs + (p0 + i) * 132 + c0) = ha;
            *(float4*)(Xs + (p0 + i) * 132 + 64 + c0) = hb;
        }
        __syncthreads();
        // layer 2: H(64x128) @ cw2(128x32) + cb2
        const int d0 = (t & 7) * 4;
        const int q0 = (t >> 3) * 2;
        float a2[2][4];
        #pragma unroll
        for (int i = 0; i < 2; ++i)
            #pragma unroll
            for (int d = 0; d < 4; ++d) a2[i][d] = 0.f;
        #pragma unroll 4
        for (int k = 0; k < 128; ++k) {
            float4 w = *(const float4*)(cw2 + (size_t)k * 32 + d0);
            #pragma unroll
            for (int i = 0; i < 2; ++i) {
                float h = Xs[(q0 + i) * 132 + k];
                a2[i][0] += h * w.x; a2[i][1] += h * w.y;
                a2[i][2] += h * w.z; a2[i][3] += h * w.w;
            }
        }
        #pragma unroll
        for (int i = 0; i < 2; ++i) {
            float4 o;
            o.x = a2[i][0] + cb2[d0 + 0];
            o.y = a2[i][1] + cb2[d0 + 1];
            o.z = a2[i][2] + cb2[d0 + 2];
            o.w = a2[i][3] + cb2[d0 + 3];
            *(float4*)(pair_out + ((size_t)b * PP + pbase + q0 + i) * DP + d0) = o;
        }
    } else {
        // ---------------- grv path ----------------
        float* afvT = smem;                 // [64][GRVS]  (a, m)
        float* grs  = smem + 64 * GRVS;     // [32][GRVS]  (r, m)
        const int gb = bid - 1016;
        const int b = gb >> 7, n = gb & 127;
        #pragma unroll
        for (int pz = 0; pz < 8; ++pz) {
            int pos = t + pz * 256;          // 2048 f4: afv[b] 128x64
            int m = pos >> 4, a4 = (pos & 15) * 4;
            float4 v = *(const float4*)(afv + (size_t)(b * NN + m) * AA + a4);
            afvT[(a4 + 0) * GRVS + m] = v.x;
            afvT[(a4 + 1) * GRVS + m] = v.y;
            afvT[(a4 + 2) * GRVS + m] = v.z;
            afvT[(a4 + 3) * GRVS + m] = v.w;
        }
        #pragma unroll
        for (int pz = 0; pz < 4; ++pz) {
            int pos = t + pz * 256;          // 1024 f4: gr[b,n] 32x128
            int r = pos >> 5, m4 = (pos & 31) * 4;
            float4 v = *(const float4*)(gr + ((size_t)(b * NN + n) * RR + r) * NN + m4);
            *(float4*)(grs + r * GRVS + m4) = v;
        }
        // fused copy of afv row (b,n) to second output
        if (t < 16) {
            float4 v = *(const float4*)(afv + (size_t)(b * NN + n) * AA + t * 4);
            *(float4*)(out2 + (size_t)(b * NN + n) * AA + t * 4) = v;
        }
        __syncthreads();
        const int a = t & 31, rg = t >> 5;   // cols {a, a+32}, rows rg*4+i
        float acc[4][2];
        #pragma unroll
        for (int i = 0; i < 4; ++i) { acc[i][0] = 0.f; acc[i][1] = 0.f; }
        for (int m4 = 0; m4 < 32; ++m4) {
            float4 va = *(const float4*)(afvT + a * GRVS + m4 * 4);        // 2-way, free
            float4 vb = *(const float4*)(afvT + (a + 32) * GRVS + m4 * 4);
            #pragma unroll
            for (int i = 0; i < 4; ++i) {
                float4 g = *(const float4*)(grs + (rg * 4 + i) * GRVS + m4 * 4);
                acc[i][0] += g.x * va.x + g.y * va.y + g.z * va.z + g.w * va.w;
                acc[i][1] += g.x * vb.x + g.y * vb.y + g.z * vb.z + g.w * vb.w;
            }
        }
        float* xrow = Xout + (size_t)(b * NN + n) * XDIM;
        #pragma unroll
        for (int i = 0; i < 4; ++i) {
            xrow[(rg * 4 + i) * 64 + a]      = acc[i][0];
            xrow[(rg * 4 + i) * 64 + a + 32] = acc[i][1];
        }
    }
}

// ---------------------------------------------------------------------------
// Kernel B: gav partials.  Per b: (2048 x 8128) @ (8128 x 32), K split 8.
// 2-phase reg-staged pipeline; At stride 136 (2-way write conflicts only).
// grid 1024 = b(8) x rowtile(16, 128 rows) x kchunk(8), block 256, 4 blk/CU
// ---------------------------------------------------------------------------
#define ATS 136

__global__ __launch_bounds__(256, 4) void gav_k(
    const float* __restrict__ ga, const float* __restrict__ pair,
    float* __restrict__ part)
{
    __shared__ float At[32 * ATS];   // [kk][row], transposed A tile (128 rows)
    __shared__ float Bs[32 * 36];    // [kk][d]
    const int bid = blockIdx.x;
    const int c = bid & 7, rt = (bid >> 3) & 15, b = bid >> 7;
    const int rbase = rt * 128;
    const int kstart = c * 1024;
    const int kend = (kstart + 1024 < PP) ? (kstart + 1024) : PP;
    const int niter = (kend - kstart) >> 5;       // 32 (c<7) or 30 (c==7)
    const int t = threadIdx.x;
    const int trow = t >> 3, slot = t & 7;        // staging coords
    const int trv = t >> 3, tcv = t & 7;
    const int r0 = trv * 4, d0 = tcv * 4;         // thread tile 4 rows x 4 cols
    float acc[4][4];
    #pragma unroll
    for (int i = 0; i < 4; ++i)
        #pragma unroll
        for (int d = 0; d < 4; ++d) acc[i][d] = 0.f;

    const float* gab = ga + (size_t)(b * 2048 + rbase) * PP;
    const float* pb = pair + (size_t)b * PP * DP;

    // prologue: stage iter 0 into regs
    float4 ra[4], rb;
    #pragma unroll
    for (int pz = 0; pz < 4; ++pz) {
        int row = trow + 32 * pz;
        ra[pz] = *(const float4*)(gab + (size_t)row * PP + kstart + slot * 4);
    }
    rb = *(const float4*)(pb + (size_t)(kstart + trow) * DP + slot * 4);

    for (int it = 0; it < niter; ++it) {
        const int k = kstart + it * 32;
        __syncthreads();   // previous FMA phase done reading LDS
        #pragma unroll
        for (int pz = 0; pz < 4; ++pz) {
            int row = trow + 32 * pz;
            int sb = slot * 4;
            At[(sb + 0) * ATS + row] = ra[pz].x;
            At[(sb + 1) * ATS + row] = ra[pz].y;
            At[(sb + 2) * ATS + row] = ra[pz].z;
            At[(sb + 3) * ATS + row] = ra[pz].w;
        }
        *(float4*)(Bs + trow * 36 + slot * 4) = rb;
        __syncthreads();
        // issue next tile's loads (no wait — consumed next iter)
        if (it + 1 < niter) {
            int kn = k + 32;
            #pragma unroll
            for (int pz = 0; pz < 4; ++pz) {
                int row = trow + 32 * pz;
                ra[pz] = *(const float4*)(gab + (size_t)row * PP + kn + slot * 4);
            }
            rb = *(const float4*)(pb + (size_t)(kn + trow) * DP + slot * 4);
        }
        // FMA phase
        #pragma unroll 8
        for (int kk = 0; kk < 32; ++kk) {
            float4 a4 = *(const float4*)(At + kk * ATS + r0);
            float4 b4 = *(const float4*)(Bs + kk * 36 + d0);
            float av[4] = {a4.x, a4.y, a4.z, a4.w};
            float bv[4] = {b4.x, b4.y, b4.z, b4.w};
            #pragma unroll
            for (int i = 0; i < 4; ++i)
                #pragma unroll
                for (int d = 0; d < 4; ++d) acc[i][d] += av[i] * bv[d];
        }
    }
    float* pout = part + ((size_t)(c * 8 + b) * 2048 + rbase) * DP;
    #pragma unroll
    for (int i = 0; i < 4; ++i) {
        float4 o = make_float4(acc[i][0], acc[i][1], acc[i][2], acc[i][3]);
        *(float4*)(pout + (size_t)(r0 + i) * DP + d0) = o;
    }
}

// ---------------------------------------------------------------------------
// Kernel C: reduce gav partials (8 chunks) -> X[..., 2048 + a*32 + d]
// grid 512, block 256 (1 float4 per thread)
// ---------------------------------------------------------------------------
__global__ __launch_bounds__(256) void gavred_k(
    const float* __restrict__ part, float* __restrict__ Xout)
{
    int idx = blockIdx.x * 256 + threadIdx.x;   // f4 index over 131072
    int e = idx * 4;
    int row = e >> 5;          // global row b*2048+r
    int d0 = e & 31;
    int b = row >> 11, r = row & 2047;
    float4 s = make_float4(0.f, 0.f, 0.f, 0.f);
    #pragma unroll
    for (int c = 0; c < 8; ++c) {
        float4 v = *(const float4*)(part + ((size_t)(c * 8 + b) * 2048 + r) * DP + d0);
        s.x += v.x; s.y += v.y; s.z += v.z; s.w += v.w;
    }
    int n = r >> 4, a = r & 15;
    *(float4*)(Xout + (size_t)(b * NN + n) * XDIM + 2048 + a * DP + d0) = s;
}

// ---------------------------------------------------------------------------
// Kernel D: mlp layer1 partials: X(1024x2560) @ ew1(2560x512), K split 4
// 2-phase reg-staged pipeline.
// grid 512 = rt(16, 64 rows) x ct(8, 64 cols) x c(4), block 256, thread 4x4
// ---------------------------------------------------------------------------
__global__ __launch_bounds__(256) void mlp1_k(
    const float* __restrict__ X, const float* __restrict__ ew1,
    float* __restrict__ part)
{
    __shared__ float Xt[32 * 68];   // [kk][row]
    __shared__ float Ws[32 * 68];   // [kk][j]
    const int bid = blockIdx.x;
    const int c = bid & 3, ct = (bid >> 2) & 7, rt = bid >> 5;
    const int rbase = rt * 64, jb = ct * 64;
    const int kstart = c * 640;                   // 20 iters of 32
    const int t = threadIdx.x;
    const int tcv = t & 15, trv = t >> 4;
    const int r0 = trv * 4, j0 = tcv * 4;
    float acc[4][4];
    #pragma unroll
    for (int i = 0; i < 4; ++i)
        #pragma unroll
        for (int j = 0; j < 4; ++j) acc[i][j] = 0.f;

    const int xrow_lo = t >> 3, xslot = t & 7;    // X: 64 rows x 8 f4-slots
    const int wkk_lo = t >> 4, wj4 = (t & 15) * 4;// W: 32 kk x 16 f4-slots

    float4 rx[2], rw[2];
    #pragma unroll
    for (int pz = 0; pz < 2; ++pz) {
        int row = xrow_lo + 32 * pz;
        rx[pz] = *(const float4*)(X + (size_t)(rbase + row) * XDIM + kstart + xslot * 4);
        int kk = wkk_lo + 16 * pz;
        rw[pz] = *(const float4*)(ew1 + (size_t)(kstart + kk) * HH + jb + wj4);
    }

    for (int it = 0; it < 20; ++it) {
        const int k = kstart + it * 32;
        __syncthreads();
        #pragma unroll
        for (int pz = 0; pz < 2; ++pz) {
            int row = xrow_lo + 32 * pz;
            int sb = xslot * 4;
            Xt[(sb + 0) * 68 + row] = rx[pz].x;
            Xt[(sb + 1) * 68 + row] = rx[pz].y;
            Xt[(sb + 2) * 68 + row] = rx[pz].z;
            Xt[(sb + 3) * 68 + row] = rx[pz].w;
            int kk = wkk_lo + 16 * pz;
            *(float4*)(Ws + kk * 68 + wj4) = rw[pz];
        }
        __syncthreads();
        if (it + 1 < 20) {
            int kn = k + 32;
            #pragma unroll
            for (int pz = 0; pz < 2; ++pz) {
                int row = xrow_lo + 32 * pz;
                rx[pz] = *(const float4*)(X + (size_t)(rbase + row) * XDIM + kn + xslot * 4);
                int kk = wkk_lo + 16 * pz;
                rw[pz] = *(const float4*)(ew1 + (size_t)(kn + kk) * HH + jb + wj4);
            }
        }
        #pragma unroll 8
        for (int kk = 0; kk < 32; ++kk) {
            float4 a4 = *(const float4*)(Xt + kk * 68 + r0);
            float4 w4 = *(const float4*)(Ws + kk * 68 + j0);
            float av[4] = {a4.x, a4.y, a4.z, a4.w};
            float wv[4] = {w4.x, w4.y, w4.z, w4.w};
            #pragma unroll
            for (int i = 0; i < 4; ++i)
                #pragma unroll
                for (int j = 0; j < 4; ++j) acc[i][j] += av[i] * wv[j];
        }
    }
    float* po = part + (size_t)c * 1024 * HH;
    #pragma unroll
    for (int i = 0; i < 4; ++i) {
        float4 o = make_float4(acc[i][0], acc[i][1], acc[i][2], acc[i][3]);
        *(float4*)(po + (size_t)(rbase + r0 + i) * HH + jb + j0) = o;
    }
}

// ---------------------------------------------------------------------------
// Kernel E: reduce mlp1 partials (4) + bias + gelu -> H tile; H @ ew2 + eb2 -> aef
// grid 256 (4 rows each), block 256, unroll 16 for L2-latency ILP
// ---------------------------------------------------------------------------
__global__ __launch_bounds__(256) void mlp2_k(
    const float* __restrict__ part, const float* __restrict__ eb1,
    const float* __restrict__ ew2, const float* __restrict__ eb2,
    float* __restrict__ out)
{
    __shared__ float Hs[4 * 520];
    const int rbase = blockIdx.x * 4;
    const int t = threadIdx.x;
    #pragma unroll
    for (int pz = 0; pz < 2; ++pz) {
        int pos = t + pz * 256;          // 512 f4: 4 rows x 128
        int r = pos >> 7, j4 = (pos & 127) * 4;
        float4 s = *(const float4*)(eb1 + j4);
        #pragma unroll
        for (int cc = 0; cc < 4; ++cc) {
            float4 v = *(const float4*)(part + (size_t)cc * 1024 * HH +
                                        (size_t)(rbase + r) * HH + j4);
            s.x += v.x; s.y += v.y; s.z += v.z; s.w += v.w;
        }
        float4 h;
        h.x = gelu_f(s.x); h.y = gelu_f(s.y);
        h.z = gelu_f(s.z); h.w = gelu_f(s.w);
        *(float4*)(Hs + r * 520 + j4) = h;
    }
    __syncthreads();
    const int row = t >> 6;              // 0..3 (wave-uniform -> broadcast reads)
    const int c0 = (t & 63) * 4;         // 0..252
    float4 a = make_float4(0.f, 0.f, 0.f, 0.f);
    #pragma unroll 16
    for (int k = 0; k < HH; ++k) {
        float h = Hs[row * 520 + k];
        float4 w = *(const float4*)(ew2 + (size_t)k * EE + c0);
        a.x += h * w.x; a.y += h * w.y; a.z += h * w.z; a.w += h * w.w;
    }
    float4 bb = *(const float4*)(eb2 + c0);
    a.x += bb.x; a.y += bb.y; a.z += bb.z; a.w += bb.w;
    *(float4*)(out + (size_t)(rbase + row) * EE + c0) = a;
}

extern "C" void kernel_launch(void* const* d_in, const int* in_sizes, int n_in,
                              void* d_out, int out_size, void* d_ws, size_t ws_size,
                              hipStream_t stream) {
    const float* gr  = (const float*)d_in[0];
    const float* ga  = (const float*)d_in[1];
    const float* afv = (const float*)d_in[2];
    const float* cw1 = (const float*)d_in[3];
    const float* cb1 = (const float*)d_in[4];
    const float* cw2 = (const float*)d_in[5];
    const float* cb2 = (const float*)d_in[6];
    const float* ew1 = (const float*)d_in[7];
    const float* eb1 = (const float*)d_in[8];
    const float* ew2 = (const float*)d_in[9];
    const float* eb2 = (const float*)d_in[10];
    float* out = (float*)d_out;
    float* ws = (float*)d_ws;

    float* pair  = ws + WS_PAIR;
    float* X     = ws + WS_X;
    float* gavp  = ws + WS_GAVP;
    float* mlp1p = ws + WS_MLP1P;

    stage1_k<<<dim3(2040), dim3(256), 0, stream>>>(afv, cw1, cb1, cw2, cb2, pair,
                                                   gr, X, out + (size_t)BB * NN * EE);
    gav_k<<<dim3(1024), dim3(256), 0, stream>>>(ga, pair, gavp);
    gavred_k<<<dim3(512), dim3(256), 0, stream>>>(gavp, X);
    mlp1_k<<<dim3(512), dim3(256), 0, stream>>>(X, ew1, mlp1p);
    mlp2_k<<<dim3(256), dim3(256), 0, stream>>>(mlp1p, eb1, ew2, eb2, out);
}

// Round 4
// 301.585 us; speedup vs baseline: 1.5284x; 1.0506x over previous
//
#include <hip/hip_runtime.h>
#include <math.h>

// Problem constants (fixed by setup_inputs)
#define BB 8
#define NN 128
#define AA 64
#define RR 32
#define RA 16
#define PP 8128            // N*(N-1)/2
#define DP 32
#define HH 512
#define EE 256
#define XDIM 2560          // RR*AA + RA*DP = 2048 + 512

// workspace layout (float offsets)
static constexpr size_t WS_PAIR = 0;                                // 2,080,768 f32
static constexpr size_t WS_XB   = WS_PAIR + (size_t)BB*PP*DP;       // X bf16: 1024x2560 ushort = 1,310,720 f32-slots
static constexpr size_t WS_GAVP = WS_XB + (size_t)BB*NN*XDIM/2;     // gav partials / mlp1 partials (aliased): 4,194,304 f32
static constexpr size_t WS_EW1B = WS_GAVP + (size_t)8*BB*2048*DP;   // ew1^T bf16: 512x2560 ushort = 655,360 f32-slots
// total ~8.24M floats = 33 MB

typedef __attribute__((ext_vector_type(8))) short bf16x8;
typedef __attribute__((ext_vector_type(4))) float f32x4;

__device__ __forceinline__ float gelu_f(float x) {
    float u = 0.7978845608028654f * (x + 0.044715f * x * x * x);
    float au = fabsf(u);
    float e = __expf(-2.0f * au);
    float th = (1.0f - e) / (1.0f + e);
    th = copysignf(th, u);
    return 0.5f * x * (1.0f + th);
}

__device__ __forceinline__ unsigned short f2bf(float x) {
    union { float f; unsigned u; } v; v.f = x;
    unsigned r = v.u + 0x7fffu + ((v.u >> 16) & 1u);   // RTNE
    return (unsigned short)(r >> 16);
}

// ---------------------------------------------------------------------------
// Kernel A: fused stage-1.
//   blocks [0,1016): pair MLP -> pair_out
//   blocks [1016,2040): grv einsum -> Xb[..., 0:2048] (bf16), + afv copy to out2
//   blocks [2040,3320): ew1 -> ew1bT (bf16, transposed [n][k])
// block 256
// ---------------------------------------------------------------------------
#define GRVS 136   // padded stride for grv tiles (word-stride 34 == 2 mod 32)

__global__ __launch_bounds__(256) void stage1_k(
    const float* __restrict__ afv, const float* __restrict__ cw1,
    const float* __restrict__ cb1, const float* __restrict__ cw2,
    const float* __restrict__ cb2, float* __restrict__ pair_out,
    const float* __restrict__ gr, unsigned short* __restrict__ Xb,
    float* __restrict__ out2,
    const float* __restrict__ ew1, unsigned short* __restrict__ ew1bT)
{
    __shared__ float smem[64 * GRVS + 32 * GRVS + 128];  // 13184 floats = 52.7 KB
    const int bid = blockIdx.x;
    const int t = threadIdx.x;

    if (bid >= 2040) {
        // ---------------- ew1 convert+transpose path ----------------
        int q = (bid - 2040) * 256 + t;      // 0..327679
        int n = q & 511;
        int k0 = (q >> 9) * 4;               // 0..2556
        ushort4 o;
        o.x = f2bf(ew1[(size_t)(k0 + 0) * HH + n]);
        o.y = f2bf(ew1[(size_t)(k0 + 1) * HH + n]);
        o.z = f2bf(ew1[(size_t)(k0 + 2) * HH + n]);
        o.w = f2bf(ew1[(size_t)(k0 + 3) * HH + n]);
        *(ushort4*)(ew1bT + (size_t)n * XDIM + k0) = o;
        return;
    }

    if (bid < 1016) {
        // ---------------- pair MLP path ----------------
        float* Xs  = smem;                 // [64][132]  X tile, later H tile
        float* W1c = smem + 64 * 132;      // [32][132]  cw1 K-chunk
        int*   ii_s = (int*)(smem + 64 * 132 + 32 * 132);
        int*   jj_s = ii_s + 64;
        const int b = bid / 127;
        const int pbase = (bid % 127) * 64;

        if (t < 64) {
            int p = pbase + t;
            int i = 0;
            while (i < 126) {
                int nx = i + 1;
                int off = nx * 127 - (nx * (nx - 1)) / 2;
                if (off <= p) i = nx; else break;
            }
            int off = i * 127 - (i * (i - 1)) / 2;
            ii_s[t] = i;
            jj_s[t] = i + 1 + (p - off);
        }
        __syncthreads();
        {
            int pp = t & 63, seg = t >> 6;   // seg 0..3 -> k seg*16..+15
            const float* ar = afv + (size_t)(b * NN + ii_s[pp]) * AA + seg * 16;
            const float* br = afv + (size_t)(b * NN + jj_s[pp]) * AA + seg * 16;
            #pragma unroll
            for (int i = 0; i < 4; ++i) {
                float4 x = *(const float4*)(ar + i * 4);
                float4 y = *(const float4*)(br + i * 4);
                float4 s = make_float4(x.x + y.x, x.y + y.y, x.z + y.z, x.w + y.w);
                float4 p = make_float4(x.x * y.x, x.y * y.y, x.z * y.z, x.w * y.w);
                *(float4*)(Xs + pp * 132 + seg * 16 + i * 4) = s;
                *(float4*)(Xs + pp * 132 + 64 + seg * 16 + i * 4) = p;
            }
        }
        const int tc = t & 15, tr = t >> 4;
        const int c0 = tc * 4, p0 = tr * 4;
        float acc[4][8];
        #pragma unroll
        for (int i = 0; i < 4; ++i)
            #pragma unroll
            for (int j = 0; j < 8; ++j) acc[i][j] = 0.f;

        for (int kc = 0; kc < 4; ++kc) {
            __syncthreads();
            #pragma unroll
            for (int pz = 0; pz < 4; ++pz) {
                int pos = t + pz * 256;
                int kk = pos >> 5, j4 = (pos & 31) * 4;
                float4 v = *(const float4*)(cw1 + (size_t)(kc * 32 + kk) * 128 + j4);
                *(float4*)(W1c + kk * 132 + j4) = v;
            }
            __syncthreads();
            #pragma unroll 4
            for (int kk = 0; kk < 32; ++kk) {
                int k = kc * 32 + kk;
                float4 wa = *(const float4*)(W1c + kk * 132 + c0);
                float4 wb = *(const float4*)(W1c + kk * 132 + 64 + c0);
                float w[8] = {wa.x, wa.y, wa.z, wa.w, wb.x, wb.y, wb.z, wb.w};
                #pragma unroll
                for (int i = 0; i < 4; ++i) {
                    float x = Xs[(p0 + i) * 132 + k];
                    #pragma unroll
                    for (int j = 0; j < 8; ++j) acc[i][j] += x * w[j];
                }
            }
        }
        __syncthreads();
        #pragma unroll
        for (int i = 0; i < 4; ++i) {
            float4 ha, hb;
            ha.x = gelu_f(acc[i][0] + cb1[c0 + 0]);
            ha.y = gelu_f(acc[i][1] + cb1[c0 + 1]);
            ha.z = gelu_f(acc[i][2] + cb1[c0 + 2]);
            ha.w = gelu_f(acc[i][3] + cb1[c0 + 3]);
            hb.x = gelu_f(acc[i][4] + cb1[64 + c0 + 0]);
            hb.y = gelu_f(acc[i][5] + cb1[64 + c0 + 1]);
            hb.z = gelu_f(acc[i][6] + cb1[64 + c0 + 2]);
            hb.w = gelu_f(acc[i][7] + cb1[64 + c0 + 3]);
            *(float4*)(Xs + (p0 + i) * 132 + c0) = ha;
            *(float4*)(Xs + (p0 + i) * 132 + 64 + c0) = hb;
        }
        __syncthreads();
        const int d0 = (t & 7) * 4;
        const int q0 = (t >> 3) * 2;
        float a2[2][4];
        #pragma unroll
        for (int i = 0; i < 2; ++i)
            #pragma unroll
            for (int d = 0; d < 4; ++d) a2[i][d] = 0.f;
        #pragma unroll 4
        for (int k = 0; k < 128; ++k) {
            float4 w = *(const float4*)(cw2 + (size_t)k * 32 + d0);
            #pragma unroll
            for (int i = 0; i < 2; ++i) {
                float h = Xs[(q0 + i) * 132 + k];
                a2[i][0] += h * w.x; a2[i][1] += h * w.y;
                a2[i][2] += h * w.z; a2[i][3] += h * w.w;
            }
        }
        #pragma unroll
        for (int i = 0; i < 2; ++i) {
            float4 o;
            o.x = a2[i][0] + cb2[d0 + 0];
            o.y = a2[i][1] + cb2[d0 + 1];
            o.z = a2[i][2] + cb2[d0 + 2];
            o.w = a2[i][3] + cb2[d0 + 3];
            *(float4*)(pair_out + ((size_t)b * PP + pbase + q0 + i) * DP + d0) = o;
        }
    } else {
        // ---------------- grv path ----------------
        float* afvT = smem;                 // [64][GRVS]  (a, m)
        float* grs  = smem + 64 * GRVS;     // [32][GRVS]  (r, m)
        const int gb = bid - 1016;
        const int b = gb >> 7, n = gb & 127;
        #pragma unroll
        for (int pz = 0; pz < 8; ++pz) {
            int pos = t + pz * 256;
            int m = pos >> 4, a4 = (pos & 15) * 4;
            float4 v = *(const float4*)(afv + (size_t)(b * NN + m) * AA + a4);
            afvT[(a4 + 0) * GRVS + m] = v.x;
            afvT[(a4 + 1) * GRVS + m] = v.y;
            afvT[(a4 + 2) * GRVS + m] = v.z;
            afvT[(a4 + 3) * GRVS + m] = v.w;
        }
        #pragma unroll
        for (int pz = 0; pz < 4; ++pz) {
            int pos = t + pz * 256;
            int r = pos >> 5, m4 = (pos & 31) * 4;
            float4 v = *(const float4*)(gr + ((size_t)(b * NN + n) * RR + r) * NN + m4);
            *(float4*)(grs + r * GRVS + m4) = v;
        }
        if (t < 16) {
            float4 v = *(const float4*)(afv + (size_t)(b * NN + n) * AA + t * 4);
            *(float4*)(out2 + (size_t)(b * NN + n) * AA + t * 4) = v;
        }
        __syncthreads();
        const int a = t & 31, rg = t >> 5;
        float acc[4][2];
        #pragma unroll
        for (int i = 0; i < 4; ++i) { acc[i][0] = 0.f; acc[i][1] = 0.f; }
        for (int m4 = 0; m4 < 32; ++m4) {
            float4 va = *(const float4*)(afvT + a * GRVS + m4 * 4);
            float4 vb = *(const float4*)(afvT + (a + 32) * GRVS + m4 * 4);
            #pragma unroll
            for (int i = 0; i < 4; ++i) {
                float4 g = *(const float4*)(grs + (rg * 4 + i) * GRVS + m4 * 4);
                acc[i][0] += g.x * va.x + g.y * va.y + g.z * va.z + g.w * va.w;
                acc[i][1] += g.x * vb.x + g.y * vb.y + g.z * vb.z + g.w * vb.w;
            }
        }
        unsigned short* xrow = Xb + (size_t)(b * NN + n) * XDIM;
        #pragma unroll
        for (int i = 0; i < 4; ++i) {
            xrow[(rg * 4 + i) * 64 + a]      = f2bf(acc[i][0]);
            xrow[(rg * 4 + i) * 64 + a + 32] = f2bf(acc[i][1]);
        }
    }
}

// ---------------------------------------------------------------------------
// Kernel B: gav partials.  Per b: (2048 x 8128) @ (8128 x 32), K split 8.
// 64-wide K iterations -> 256 B contiguous per row per iter (DRAM-friendly).
// grid 1024 = b(8) x rowtile(16, 128 rows) x kchunk(8), block 256, 3 blk/CU
// ---------------------------------------------------------------------------
#define ATS 132

__global__ __launch_bounds__(256, 3) void gav_k(
    const float* __restrict__ ga, const float* __restrict__ pair,
    float* __restrict__ part)
{
    __shared__ float At[64 * ATS];   // [kk][row], transposed A tile (128 rows)
    __shared__ float Bs[64 * 36];    // [kk][d]
    const int bid = blockIdx.x;
    const int c = bid & 7, rt = (bid >> 3) & 15, b = bid >> 7;
    const int rbase = rt * 128;
    const int kstart = c * 1024;
    const int kend = (kstart + 1024 < PP) ? (kstart + 1024) : PP;
    const int niter = (kend - kstart) >> 6;       // 16 (c<7) or 15 (c==7)
    const int t = threadIdx.x;
    const int trow = t >> 3, slot = t & 7;        // staging coords (32 x 8)
    const int r0 = (t >> 3) * 4, d0 = (t & 7) * 4; // thread tile 4 rows x 4 cols
    float acc[4][4];
    #pragma unroll
    for (int i = 0; i < 4; ++i)
        #pragma unroll
        for (int d = 0; d < 4; ++d) acc[i][d] = 0.f;

    const float* gab = ga + (size_t)(b * 2048 + rbase) * PP;
    const float* pb = pair + (size_t)b * PP * DP;

    // prologue: stage iter 0 into regs (A: 4 row-groups x 2 K-halves; B: 2)
    float4 ra[4][2], rb[2];
    #pragma unroll
    for (int pz = 0; pz < 4; ++pz)
        #pragma unroll
        for (int h = 0; h < 2; ++h)
            ra[pz][h] = *(const float4*)(gab + (size_t)(trow + 32 * pz) * PP +
                                         kstart + h * 32 + slot * 4);
    #pragma unroll
    for (int h = 0; h < 2; ++h)
        rb[h] = *(const float4*)(pb + (size_t)(kstart + trow + 32 * h) * DP + slot * 4);

    for (int it = 0; it < niter; ++it) {
        const int k = kstart + it * 64;
        __syncthreads();   // previous FMA phase done reading LDS
        #pragma unroll
        for (int pz = 0; pz < 4; ++pz) {
            int row = trow + 32 * pz;
            #pragma unroll
            for (int h = 0; h < 2; ++h) {
                int sb = h * 32 + slot * 4;
                At[(sb + 0) * ATS + row] = ra[pz][h].x;
                At[(sb + 1) * ATS + row] = ra[pz][h].y;
                At[(sb + 2) * ATS + row] = ra[pz][h].z;
                At[(sb + 3) * ATS + row] = ra[pz][h].w;
            }
        }
        #pragma unroll
        for (int h = 0; h < 2; ++h)
            *(float4*)(Bs + (trow + 32 * h) * 36 + slot * 4) = rb[h];
        __syncthreads();
        // issue next tile's loads (no wait — consumed next iter)
        if (it + 1 < niter) {
            int kn = k + 64;
            #pragma unroll
            for (int pz = 0; pz < 4; ++pz)
                #pragma unroll
                for (int h = 0; h < 2; ++h)
                    ra[pz][h] = *(const float4*)(gab + (size_t)(trow + 32 * pz) * PP +
                                                 kn + h * 32 + slot * 4);
            #pragma unroll
            for (int h = 0; h < 2; ++h)
                rb[h] = *(const float4*)(pb + (size_t)(kn + trow + 32 * h) * DP + slot * 4);
        }
        // FMA phase (conflict-free broadcast LDS reads)
        #pragma unroll 8
        for (int kk = 0; kk < 64; ++kk) {
            float4 a4 = *(const float4*)(At + kk * ATS + r0);
            float4 b4 = *(const float4*)(Bs + kk * 36 + d0);
            float av[4] = {a4.x, a4.y, a4.z, a4.w};
            float bv[4] = {b4.x, b4.y, b4.z, b4.w};
            #pragma unroll
            for (int i = 0; i < 4; ++i)
                #pragma unroll
                for (int d = 0; d < 4; ++d) acc[i][d] += av[i] * bv[d];
        }
    }
    float* pout = part + ((size_t)(c * 8 + b) * 2048 + rbase) * DP;
    #pragma unroll
    for (int i = 0; i < 4; ++i) {
        float4 o = make_float4(acc[i][0], acc[i][1], acc[i][2], acc[i][3]);
        *(float4*)(pout + (size_t)(r0 + i) * DP + d0) = o;
    }
}

// ---------------------------------------------------------------------------
// Kernel C: reduce gav partials (8 chunks) -> Xb[..., 2048 + a*32 + d] (bf16)
// grid 512, block 256 (1 float4 per thread)
// ---------------------------------------------------------------------------
__global__ __launch_bounds__(256) void gavred_k(
    const float* __restrict__ part, unsigned short* __restrict__ Xb)
{
    int idx = blockIdx.x * 256 + threadIdx.x;
    int e = idx * 4;
    int row = e >> 5;          // global row b*2048+r
    int d0 = e & 31;
    int b = row >> 11, r = row & 2047;
    float4 s = make_float4(0.f, 0.f, 0.f, 0.f);
    #pragma unroll
    for (int c = 0; c < 8; ++c) {
        float4 v = *(const float4*)(part + ((size_t)(c * 8 + b) * 2048 + r) * DP + d0);
        s.x += v.x; s.y += v.y; s.z += v.z; s.w += v.w;
    }
    int n = r >> 4, a = r & 15;
    ushort4 o;
    o.x = f2bf(s.x); o.y = f2bf(s.y); o.z = f2bf(s.z); o.w = f2bf(s.w);
    *(ushort4*)(Xb + (size_t)(b * NN + n) * XDIM + 2048 + a * DP + d0) = o;
}

// ---------------------------------------------------------------------------
// Kernel D: mlp layer1 partials via bf16 MFMA.
//   Xb(1024x2560 bf16) @ ew1bT(512x2560 bf16, [n][k]) -> part f32, K split 8.
// grid 256 = rt(8: 128 rows) x ct(4: 128 cols) x kc(8: K=320), block 256
// LDS: XOR-swizzled [row][64] bf16 tiles (granule s^(row&7)) -> 2-way free.
// ---------------------------------------------------------------------------
__global__ __launch_bounds__(256) void mlp1_k(
    const unsigned short* __restrict__ Xb,
    const unsigned short* __restrict__ Wt,
    float* __restrict__ part)
{
    __shared__ unsigned short As[128 * 64];
    __shared__ unsigned short Bs[128 * 64];
    const int bid = blockIdx.x;
    const int kc = bid & 7, ct = (bid >> 3) & 3, rt = bid >> 5;
    const int rbase = rt * 128, nbase = ct * 128;
    const int k0 = kc * 320;
    const int t = threadIdx.x;
    const int w = t >> 6, lane = t & 63;
    const int wm = (w >> 1) * 64, wn = (w & 1) * 64;
    const int lm = lane & 15, lg = lane >> 4;

    f32x4 acc[4][4];
    #pragma unroll
    for (int i = 0; i < 4; ++i)
        #pragma unroll
        for (int j = 0; j < 4; ++j) acc[i][j] = 0.f;

    const int srow = t >> 1;          // 0..127
    const int sh = (t & 1) * 4;       // granule half
    const unsigned short* Arow = Xb + (size_t)(rbase + srow) * XDIM + k0;
    const unsigned short* Brow = Wt + (size_t)(nbase + srow) * XDIM + k0;

    bf16x8 rA[4], rB[4];
    #pragma unroll
    for (int q = 0; q < 4; ++q) {
        rA[q] = *(const bf16x8*)(Arow + (sh + q) * 8);
        rB[q] = *(const bf16x8*)(Brow + (sh + q) * 8);
    }

    for (int it = 0; it < 5; ++it) {
        __syncthreads();
        #pragma unroll
        for (int q = 0; q < 4; ++q) {
            int g = ((sh + q) ^ (srow & 7)) * 8;
            *(bf16x8*)(As + srow * 64 + g) = rA[q];
            *(bf16x8*)(Bs + srow * 64 + g) = rB[q];
        }
        __syncthreads();
        if (it + 1 < 5) {
            int ko = (it + 1) * 64;
            #pragma unroll
            for (int q = 0; q < 4; ++q) {
                rA[q] = *(const bf16x8*)(Arow + ko + (sh + q) * 8);
                rB[q] = *(const bf16x8*)(Brow + ko + (sh + q) * 8);
            }
        }
        bf16x8 af[4][2], bfr[4][2];
        #pragma unroll
        for (int mi = 0; mi < 4; ++mi) {
            #pragma unroll
            for (int ks = 0; ks < 2; ++ks) {
                int rowa = wm + mi * 16 + lm;
                int s = ks * 4 + lg;
                af[mi][ks] = *(const bf16x8*)(As + rowa * 64 + ((s ^ (rowa & 7)) * 8));
                int rowb = wn + mi * 16 + lm;
                bfr[mi][ks] = *(const bf16x8*)(Bs + rowb * 64 + ((s ^ (rowb & 7)) * 8));
            }
        }
        #pragma unroll
        for (int ks = 0; ks < 2; ++ks)
            #pragma unroll
            for (int mi = 0; mi < 4; ++mi)
                #pragma unroll
                for (int ni = 0; ni < 4; ++ni)
                    acc[mi][ni] = __builtin_amdgcn_mfma_f32_16x16x32_bf16(
                        af[mi][ks], bfr[ni][ks], acc[mi][ni], 0, 0, 0);
    }
    // C/D layout: col = lane&15, row = (lane>>4)*4 + reg
    float* po = part + (size_t)kc * 1024 * HH;
    #pragma unroll
    for (int mi = 0; mi < 4; ++mi) {
        #pragma unroll
        for (int ni = 0; ni < 4; ++ni) {
            #pragma unroll
            for (int r = 0; r < 4; ++r) {
                int row = rbase + wm + mi * 16 + lg * 4 + r;
                int col = nbase + wn + ni * 16 + lm;
                po[(size_t)row * HH + col] = acc[mi][ni][r];
            }
        }
    }
}

// ---------------------------------------------------------------------------
// Kernel E: reduce mlp1 partials (8) + bias + gelu -> H; H @ ew2 + eb2 -> aef
// grid 256 (4 rows each), block 256
// ---------------------------------------------------------------------------
__global__ __launch_bounds__(256) void mlp2_k(
    const float* __restrict__ part, const float* __restrict__ eb1,
    const float* __restrict__ ew2, const float* __restrict__ eb2,
    float* __restrict__ out)
{
    __shared__ float Hs[4 * 520];
    const int rbase = blockIdx.x * 4;
    const int t = threadIdx.x;
    #pragma unroll
    for (int pz = 0; pz < 2; ++pz) {
        int pos = t + pz * 256;          // 512 f4: 4 rows x 128
        int r = pos >> 7, j4 = (pos & 127) * 4;
        float4 s = *(const float4*)(eb1 + j4);
        #pragma unroll
        for (int cc = 0; cc < 8; ++cc) {
            float4 v = *(const float4*)(part + (size_t)cc * 1024 * HH +
                                        (size_t)(rbase + r) * HH + j4);
            s.x += v.x; s.y += v.y; s.z += v.z; s.w += v.w;
        }
        float4 h;
        h.x = gelu_f(s.x); h.y = gelu_f(s.y);
        h.z = gelu_f(s.z); h.w = gelu_f(s.w);
        *(float4*)(Hs + r * 520 + j4) = h;
    }
    __syncthreads();
    const int row = t >> 6;              // 0..3 (wave-uniform -> broadcast reads)
    const int c0 = (t & 63) * 4;         // 0..252
    float4 a = make_float4(0.f, 0.f, 0.f, 0.f);
    #pragma unroll 16
    for (int k = 0; k < HH; ++k) {
        float h = Hs[row * 520 + k];
        float4 w = *(const float4*)(ew2 + (size_t)k * EE + c0);
        a.x += h * w.x; a.y += h * w.y; a.z += h * w.z; a.w += h * w.w;
    }
    float4 bb = *(const float4*)(eb2 + c0);
    a.x += bb.x; a.y += bb.y; a.z += bb.z; a.w += bb.w;
    *(float4*)(out + (size_t)(rbase + row) * EE + c0) = a;
}

extern "C" void kernel_launch(void* const* d_in, const int* in_sizes, int n_in,
                              void* d_out, int out_size, void* d_ws, size_t ws_size,
                              hipStream_t stream) {
    const float* gr  = (const float*)d_in[0];
    const float* ga  = (const float*)d_in[1];
    const float* afv = (const float*)d_in[2];
    const float* cw1 = (const float*)d_in[3];
    const float* cb1 = (const float*)d_in[4];
    const float* cw2 = (const float*)d_in[5];
    const float* cb2 = (const float*)d_in[6];
    const float* ew1 = (const float*)d_in[7];
    const float* eb1 = (const float*)d_in[8];
    const float* ew2 = (const float*)d_in[9];
    const float* eb2 = (const float*)d_in[10];
    float* out = (float*)d_out;
    float* ws = (float*)d_ws;

    float* pair            = ws + WS_PAIR;
    unsigned short* Xb     = (unsigned short*)(ws + WS_XB);
    float* gavp            = ws + WS_GAVP;   // aliased with mlp1 partials (gavp dead after gavred)
    unsigned short* ew1bT  = (unsigned short*)(ws + WS_EW1B);

    stage1_k<<<dim3(3320), dim3(256), 0, stream>>>(afv, cw1, cb1, cw2, cb2, pair,
                                                   gr, Xb, out + (size_t)BB * NN * EE,
                                                   ew1, ew1bT);
    gav_k<<<dim3(1024), dim3(256), 0, stream>>>(ga, pair, gavp);
    gavred_k<<<dim3(512), dim3(256), 0, stream>>>(gavp, Xb);
    mlp1_k<<<dim3(256), dim3(256), 0, stream>>>(Xb, ew1bT, gavp);
    mlp2_k<<<dim3(256), dim3(256), 0, stream>>>(gavp, eb1, ew2, eb2, out);
}

// Round 5
// 262.222 us; speedup vs baseline: 1.7579x; 1.1501x over previous
//
#include <hip/hip_runtime.h>
#include <math.h>

// Problem constants (fixed by setup_inputs)
#define BB 8
#define NN 128
#define AA 64
#define RR 32
#define RA 16
#define PP 8128            // N*(N-1)/2
#define DP 32
#define HH 512
#define EE 256
#define XDIM 2560          // RR*AA + RA*DP = 2048 + 512

// workspace layout (float offsets)
static constexpr size_t WS_PAIRT = 0;                                // pair^T bf16 [b][32][8128] = 1,040,384 f32-slots
static constexpr size_t WS_XB    = WS_PAIRT + (size_t)BB*DP*PP/2;    // X bf16: 1024x2560 ushort = 1,310,720 f32-slots
static constexpr size_t WS_GAVP  = WS_XB + (size_t)BB*NN*XDIM/2;     // gav partials / mlp1 partials (aliased): 4,194,304 f32
static constexpr size_t WS_EW1B  = WS_GAVP + (size_t)8*BB*2048*DP;   // ew1^T bf16: 512x2560 ushort = 655,360 f32-slots

typedef __attribute__((ext_vector_type(8))) short bf16x8;
typedef __attribute__((ext_vector_type(4))) float f32x4;

__device__ __forceinline__ float gelu_f(float x) {
    float u = 0.7978845608028654f * (x + 0.044715f * x * x * x);
    float au = fabsf(u);
    float e = __expf(-2.0f * au);
    float th = (1.0f - e) / (1.0f + e);
    th = copysignf(th, u);
    return 0.5f * x * (1.0f + th);
}

__device__ __forceinline__ unsigned short f2bf(float x) {
    union { float f; unsigned u; } v; v.f = x;
    unsigned r = v.u + 0x7fffu + ((v.u >> 16) & 1u);   // RTNE
    return (unsigned short)(r >> 16);
}

__device__ __forceinline__ bf16x8 pack_bf16x8(float4 a, float4 b) {
    bf16x8 r;
    r[0] = (short)f2bf(a.x); r[1] = (short)f2bf(a.y);
    r[2] = (short)f2bf(a.z); r[3] = (short)f2bf(a.w);
    r[4] = (short)f2bf(b.x); r[5] = (short)f2bf(b.y);
    r[6] = (short)f2bf(b.z); r[7] = (short)f2bf(b.w);
    return r;
}

// ---------------------------------------------------------------------------
// Kernel A: fused stage-1.
//   blocks [0,1016): pair MLP -> pairT (bf16, [b][d][p])
//   blocks [1016,2040): grv einsum -> Xb[..., 0:2048] (bf16), + afv copy to out2
//   blocks [2040,3320): ew1 -> ew1bT (bf16, transposed [n][k])
// block 256
// ---------------------------------------------------------------------------
#define GRVS 136   // padded stride for grv tiles (word-stride 34 == 2 mod 32)

__global__ __launch_bounds__(256) void stage1_k(
    const float* __restrict__ afv, const float* __restrict__ cw1,
    const float* __restrict__ cb1, const float* __restrict__ cw2,
    const float* __restrict__ cb2, unsigned short* __restrict__ pairT,
    const float* __restrict__ gr, unsigned short* __restrict__ Xb,
    float* __restrict__ out2,
    const float* __restrict__ ew1, unsigned short* __restrict__ ew1bT)
{
    __shared__ float smem[64 * GRVS + 32 * GRVS + 128];  // 13184 floats = 52.7 KB
    const int bid = blockIdx.x;
    const int t = threadIdx.x;

    if (bid >= 2040) {
        // ---------------- ew1 convert+transpose path ----------------
        int q = (bid - 2040) * 256 + t;      // 0..327679
        int n = q & 511;
        int k0 = (q >> 9) * 4;               // 0..2556
        ushort4 o;
        o.x = f2bf(ew1[(size_t)(k0 + 0) * HH + n]);
        o.y = f2bf(ew1[(size_t)(k0 + 1) * HH + n]);
        o.z = f2bf(ew1[(size_t)(k0 + 2) * HH + n]);
        o.w = f2bf(ew1[(size_t)(k0 + 3) * HH + n]);
        *(ushort4*)(ew1bT + (size_t)n * XDIM + k0) = o;
        return;
    }

    if (bid < 1016) {
        // ---------------- pair MLP path ----------------
        float* Xs  = smem;                 // [64][132]  X tile, later H tile
        float* W1c = smem + 64 * 132;      // [32][132]  cw1 K-chunk
        int*   ii_s = (int*)(smem + 64 * 132 + 32 * 132);
        int*   jj_s = ii_s + 64;
        const int b = bid / 127;
        const int pbase = (bid % 127) * 64;

        if (t < 64) {
            int p = pbase + t;
            int i = 0;
            while (i < 126) {
                int nx = i + 1;
                int off = nx * 127 - (nx * (nx - 1)) / 2;
                if (off <= p) i = nx; else break;
            }
            int off = i * 127 - (i * (i - 1)) / 2;
            ii_s[t] = i;
            jj_s[t] = i + 1 + (p - off);
        }
        __syncthreads();
        {
            int pp = t & 63, seg = t >> 6;   // seg 0..3 -> k seg*16..+15
            const float* ar = afv + (size_t)(b * NN + ii_s[pp]) * AA + seg * 16;
            const float* br = afv + (size_t)(b * NN + jj_s[pp]) * AA + seg * 16;
            #pragma unroll
            for (int i = 0; i < 4; ++i) {
                float4 x = *(const float4*)(ar + i * 4);
                float4 y = *(const float4*)(br + i * 4);
                float4 s = make_float4(x.x + y.x, x.y + y.y, x.z + y.z, x.w + y.w);
                float4 p = make_float4(x.x * y.x, x.y * y.y, x.z * y.z, x.w * y.w);
                *(float4*)(Xs + pp * 132 + seg * 16 + i * 4) = s;
                *(float4*)(Xs + pp * 132 + 64 + seg * 16 + i * 4) = p;
            }
        }
        const int tc = t & 15, tr = t >> 4;
        const int c0 = tc * 4, p0 = tr * 4;
        float acc[4][8];
        #pragma unroll
        for (int i = 0; i < 4; ++i)
            #pragma unroll
            for (int j = 0; j < 8; ++j) acc[i][j] = 0.f;

        for (int kc = 0; kc < 4; ++kc) {
            __syncthreads();
            #pragma unroll
            for (int pz = 0; pz < 4; ++pz) {
                int pos = t + pz * 256;
                int kk = pos >> 5, j4 = (pos & 31) * 4;
                float4 v = *(const float4*)(cw1 + (size_t)(kc * 32 + kk) * 128 + j4);
                *(float4*)(W1c + kk * 132 + j4) = v;
            }
            __syncthreads();
            #pragma unroll 4
            for (int kk = 0; kk < 32; ++kk) {
                int k = kc * 32 + kk;
                float4 wa = *(const float4*)(W1c + kk * 132 + c0);
                float4 wb = *(const float4*)(W1c + kk * 132 + 64 + c0);
                float w[8] = {wa.x, wa.y, wa.z, wa.w, wb.x, wb.y, wb.z, wb.w};
                #pragma unroll
                for (int i = 0; i < 4; ++i) {
                    float x = Xs[(p0 + i) * 132 + k];
                    #pragma unroll
                    for (int j = 0; j < 8; ++j) acc[i][j] += x * w[j];
                }
            }
        }
        __syncthreads();
        #pragma unroll
        for (int i = 0; i < 4; ++i) {
            float4 ha, hb;
            ha.x = gelu_f(acc[i][0] + cb1[c0 + 0]);
            ha.y = gelu_f(acc[i][1] + cb1[c0 + 1]);
            ha.z = gelu_f(acc[i][2] + cb1[c0 + 2]);
            ha.w = gelu_f(acc[i][3] + cb1[c0 + 3]);
            hb.x = gelu_f(acc[i][4] + cb1[64 + c0 + 0]);
            hb.y = gelu_f(acc[i][5] + cb1[64 + c0 + 1]);
            hb.z = gelu_f(acc[i][6] + cb1[64 + c0 + 2]);
            hb.w = gelu_f(acc[i][7] + cb1[64 + c0 + 3]);
            *(float4*)(Xs + (p0 + i) * 132 + c0) = ha;
            *(float4*)(Xs + (p0 + i) * 132 + 64 + c0) = hb;
        }
        __syncthreads();
        // layer 2: H(64x128) @ cw2(128x32) + cb2 -> pairT bf16 [d][p]
        const int d0 = (t & 7) * 4;
        const int q0 = (t >> 3) * 2;
        float a2[2][4];
        #pragma unroll
        for (int i = 0; i < 2; ++i)
            #pragma unroll
            for (int d = 0; d < 4; ++d) a2[i][d] = 0.f;
        #pragma unroll 4
        for (int k = 0; k < 128; ++k) {
            float4 w = *(const float4*)(cw2 + (size_t)k * 32 + d0);
            #pragma unroll
            for (int i = 0; i < 2; ++i) {
                float h = Xs[(q0 + i) * 132 + k];
                a2[i][0] += h * w.x; a2[i][1] += h * w.y;
                a2[i][2] += h * w.z; a2[i][3] += h * w.w;
            }
        }
        #pragma unroll
        for (int d = 0; d < 4; ++d) {
            ushort2 w2;
            w2.x = f2bf(a2[0][d] + cb2[d0 + d]);
            w2.y = f2bf(a2[1][d] + cb2[d0 + d]);
            *(ushort2*)(pairT + ((size_t)b * DP + d0 + d) * PP + pbase + q0) = w2;
        }
    } else {
        // ---------------- grv path ----------------
        float* afvT = smem;                 // [64][GRVS]  (a, m)
        float* grs  = smem + 64 * GRVS;     // [32][GRVS]  (r, m)
        const int gb = bid - 1016;
        const int b = gb >> 7, n = gb & 127;
        #pragma unroll
        for (int pz = 0; pz < 8; ++pz) {
            int pos = t + pz * 256;
            int m = pos >> 4, a4 = (pos & 15) * 4;
            float4 v = *(const float4*)(afv + (size_t)(b * NN + m) * AA + a4);
            afvT[(a4 + 0) * GRVS + m] = v.x;
            afvT[(a4 + 1) * GRVS + m] = v.y;
            afvT[(a4 + 2) * GRVS + m] = v.z;
            afvT[(a4 + 3) * GRVS + m] = v.w;
        }
        #pragma unroll
        for (int pz = 0; pz < 4; ++pz) {
            int pos = t + pz * 256;
            int r = pos >> 5, m4 = (pos & 31) * 4;
            float4 v = *(const float4*)(gr + ((size_t)(b * NN + n) * RR + r) * NN + m4);
            *(float4*)(grs + r * GRVS + m4) = v;
        }
        if (t < 16) {
            float4 v = *(const float4*)(afv + (size_t)(b * NN + n) * AA + t * 4);
            *(float4*)(out2 + (size_t)(b * NN + n) * AA + t * 4) = v;
        }
        __syncthreads();
        const int a = t & 31, rg = t >> 5;
        float acc[4][2];
        #pragma unroll
        for (int i = 0; i < 4; ++i) { acc[i][0] = 0.f; acc[i][1] = 0.f; }
        for (int m4 = 0; m4 < 32; ++m4) {
            float4 va = *(const float4*)(afvT + a * GRVS + m4 * 4);
            float4 vb = *(const float4*)(afvT + (a + 32) * GRVS + m4 * 4);
            #pragma unroll
            for (int i = 0; i < 4; ++i) {
                float4 g = *(const float4*)(grs + (rg * 4 + i) * GRVS + m4 * 4);
                acc[i][0] += g.x * va.x + g.y * va.y + g.z * va.z + g.w * va.w;
                acc[i][1] += g.x * vb.x + g.y * vb.y + g.z * vb.z + g.w * vb.w;
            }
        }
        unsigned short* xrow = Xb + (size_t)(b * NN + n) * XDIM;
        #pragma unroll
        for (int i = 0; i < 4; ++i) {
            xrow[(rg * 4 + i) * 64 + a]      = f2bf(acc[i][0]);
            xrow[(rg * 4 + i) * 64 + a + 32] = f2bf(acc[i][1]);
        }
    }
}

// ---------------------------------------------------------------------------
// Kernel B: gav partials via bf16 MFMA with on-the-fly f32->bf16 conversion.
//   Per b: (2048 x 8128) @ (8128 x 32), K split 8, K-tile 64.
//   A staged f32->bf16 into XOR-swizzled LDS; B loaded bf16 from pairT.
// grid 1024 = b(8) x rowtile(16: 128 rows) x kchunk(8), block 256, 4 blk/CU
// ---------------------------------------------------------------------------
__global__ __launch_bounds__(256, 4) void gav_k(
    const float* __restrict__ ga, const unsigned short* __restrict__ pairT,
    float* __restrict__ part)
{
    __shared__ unsigned short As[128 * 64];   // [row][k] bf16, granule^row&7 swizzle
    __shared__ unsigned short Bs[32 * 64];    // [col][k] bf16, same swizzle
    const int bid = blockIdx.x;
    const int c = bid & 7, rt = (bid >> 3) & 15, b = bid >> 7;
    const int rbase = rt * 128;
    const int kstart = c * 1024;
    const int kend = (kstart + 1024 < PP) ? (kstart + 1024) : PP;
    const int niter = (kend - kstart) >> 6;       // 16 (c<7) or 15 (c==7)
    const int t = threadIdx.x;
    // staging roles
    const int srow = t >> 1;                  // 0..127
    const int khalf = (t & 1) * 32;           // k-half within 64
    const int bd = t >> 3, bslot = t & 7;     // B: d-row, 8-k slot
    // wave/frag roles
    const int w = t >> 6, lane = t & 63;
    const int wm = w * 32;
    const int lm = lane & 15, lg = lane >> 4;

    f32x4 acc[2][2];
    #pragma unroll
    for (int i = 0; i < 2; ++i)
        #pragma unroll
        for (int j = 0; j < 2; ++j) acc[i][j] = 0.f;

    const float* gab = ga + (size_t)(b * 2048 + rbase) * PP;
    const unsigned short* pbT = pairT + (size_t)b * DP * PP;

    // prologue: stage iter 0 into regs
    float4 ra[8];
    bf16x8 rb;
    #pragma unroll
    for (int q = 0; q < 8; ++q)
        ra[q] = *(const float4*)(gab + (size_t)srow * PP + kstart + khalf + q * 4);
    rb = *(const bf16x8*)(pbT + (size_t)bd * PP + kstart + bslot * 8);

    for (int it = 0; it < niter; ++it) {
        __syncthreads();   // previous FMA phase done reading LDS
        // convert + write LDS (vmcnt satisfied: loads issued one phase ago)
        #pragma unroll
        for (int q2 = 0; q2 < 4; ++q2) {
            bf16x8 v = pack_bf16x8(ra[2 * q2], ra[2 * q2 + 1]);
            int g = ((khalf >> 3) + q2) ^ (srow & 7);
            *(bf16x8*)(As + srow * 64 + g * 8) = v;
        }
        *(bf16x8*)(Bs + bd * 64 + ((bslot ^ (bd & 7)) * 8)) = rb;
        __syncthreads();
        // issue next tile's loads (consumed next iter)
        if (it + 1 < niter) {
            int kn = kstart + (it + 1) * 64;
            #pragma unroll
            for (int q = 0; q < 8; ++q)
                ra[q] = *(const float4*)(gab + (size_t)srow * PP + kn + khalf + q * 4);
            rb = *(const bf16x8*)(pbT + (size_t)bd * PP + kn + bslot * 8);
        }
        // fragment reads + MFMA
        bf16x8 af[2][2], bf_[2][2];
        #pragma unroll
        for (int mi = 0; mi < 2; ++mi)
            #pragma unroll
            for (int ks = 0; ks < 2; ++ks) {
                int row = wm + mi * 16 + lm;
                int s = ks * 4 + lg;
                af[mi][ks] = *(const bf16x8*)(As + row * 64 + ((s ^ (row & 7)) * 8));
            }
        #pragma unroll
        for (int ni = 0; ni < 2; ++ni)
            #pragma unroll
            for (int ks = 0; ks < 2; ++ks) {
                int col = ni * 16 + lm;
                int s = ks * 4 + lg;
                bf_[ni][ks] = *(const bf16x8*)(Bs + col * 64 + ((s ^ (col & 7)) * 8));
            }
        #pragma unroll
        for (int ks = 0; ks < 2; ++ks)
            #pragma unroll
            for (int mi = 0; mi < 2; ++mi)
                #pragma unroll
                for (int ni = 0; ni < 2; ++ni)
                    acc[mi][ni] = __builtin_amdgcn_mfma_f32_16x16x32_bf16(
                        af[mi][ks], bf_[ni][ks], acc[mi][ni], 0, 0, 0);
    }
    // C/D layout: col = lane&15, row = (lane>>4)*4 + reg
    float* pout = part + ((size_t)(c * 8 + b) * 2048 + rbase) * DP;
    #pragma unroll
    for (int mi = 0; mi < 2; ++mi)
        #pragma unroll
        for (int ni = 0; ni < 2; ++ni)
            #pragma unroll
            for (int r = 0; r < 4; ++r)
                pout[(size_t)(wm + mi * 16 + lg * 4 + r) * DP + ni * 16 + lm] =
                    acc[mi][ni][r];
}

// ---------------------------------------------------------------------------
// Kernel C: reduce gav partials (8 chunks) -> Xb[..., 2048 + a*32 + d] (bf16)
// grid 512, block 256 (1 float4 per thread)
// ---------------------------------------------------------------------------
__global__ __launch_bounds__(256) void gavred_k(
    const float* __restrict__ part, unsigned short* __restrict__ Xb)
{
    int idx = blockIdx.x * 256 + threadIdx.x;
    int e = idx * 4;
    int row = e >> 5;          // global row b*2048+r
    int d0 = e & 31;
    int b = row >> 11, r = row & 2047;
    float4 s = make_float4(0.f, 0.f, 0.f, 0.f);
    #pragma unroll
    for (int c = 0; c < 8; ++c) {
        float4 v = *(const float4*)(part + ((size_t)(c * 8 + b) * 2048 + r) * DP + d0);
        s.x += v.x; s.y += v.y; s.z += v.z; s.w += v.w;
    }
    int n = r >> 4, a = r & 15;
    ushort4 o;
    o.x = f2bf(s.x); o.y = f2bf(s.y); o.z = f2bf(s.z); o.w = f2bf(s.w);
    *(ushort4*)(Xb + (size_t)(b * NN + n) * XDIM + 2048 + a * DP + d0) = o;
}

// ---------------------------------------------------------------------------
// Kernel D: mlp layer1 partials via bf16 MFMA.
//   Xb(1024x2560 bf16) @ ew1bT(512x2560 bf16, [n][k]) -> part f32, K split 8.
// grid 256 = rt(8: 128 rows) x ct(4: 128 cols) x kc(8: K=320), block 256
// ---------------------------------------------------------------------------
__global__ __launch_bounds__(256) void mlp1_k(
    const unsigned short* __restrict__ Xb,
    const unsigned short* __restrict__ Wt,
    float* __restrict__ part)
{
    __shared__ unsigned short As[128 * 64];
    __shared__ unsigned short Bs[128 * 64];
    const int bid = blockIdx.x;
    const int kc = bid & 7, ct = (bid >> 3) & 3, rt = bid >> 5;
    const int rbase = rt * 128, nbase = ct * 128;
    const int k0 = kc * 320;
    const int t = threadIdx.x;
    const int w = t >> 6, lane = t & 63;
    const int wm = (w >> 1) * 64, wn = (w & 1) * 64;
    const int lm = lane & 15, lg = lane >> 4;

    f32x4 acc[4][4];
    #pragma unroll
    for (int i = 0; i < 4; ++i)
        #pragma unroll
        for (int j = 0; j < 4; ++j) acc[i][j] = 0.f;

    const int srow = t >> 1;          // 0..127
    const int sh = (t & 1) * 4;       // granule half
    const unsigned short* Arow = Xb + (size_t)(rbase + srow) * XDIM + k0;
    const unsigned short* Brow = Wt + (size_t)(nbase + srow) * XDIM + k0;

    bf16x8 rA[4], rB[4];
    #pragma unroll
    for (int q = 0; q < 4; ++q) {
        rA[q] = *(const bf16x8*)(Arow + (sh + q) * 8);
        rB[q] = *(const bf16x8*)(Brow + (sh + q) * 8);
    }

    for (int it = 0; it < 5; ++it) {
        __syncthreads();
        #pragma unroll
        for (int q = 0; q < 4; ++q) {
            int g = ((sh + q) ^ (srow & 7)) * 8;
            *(bf16x8*)(As + srow * 64 + g) = rA[q];
            *(bf16x8*)(Bs + srow * 64 + g) = rB[q];
        }
        __syncthreads();
        if (it + 1 < 5) {
            int ko = (it + 1) * 64;
            #pragma unroll
            for (int q = 0; q < 4; ++q) {
                rA[q] = *(const bf16x8*)(Arow + ko + (sh + q) * 8);
                rB[q] = *(const bf16x8*)(Brow + ko + (sh + q) * 8);
            }
        }
        bf16x8 af[4][2], bfr[4][2];
        #pragma unroll
        for (int mi = 0; mi < 4; ++mi) {
            #pragma unroll
            for (int ks = 0; ks < 2; ++ks) {
                int rowa = wm + mi * 16 + lm;
                int s = ks * 4 + lg;
                af[mi][ks] = *(const bf16x8*)(As + rowa * 64 + ((s ^ (rowa & 7)) * 8));
                int rowb = wn + mi * 16 + lm;
                bfr[mi][ks] = *(const bf16x8*)(Bs + rowb * 64 + ((s ^ (rowb & 7)) * 8));
            }
        }
        #pragma unroll
        for (int ks = 0; ks < 2; ++ks)
            #pragma unroll
            for (int mi = 0; mi < 4; ++mi)
                #pragma unroll
                for (int ni = 0; ni < 4; ++ni)
                    acc[mi][ni] = __builtin_amdgcn_mfma_f32_16x16x32_bf16(
                        af[mi][ks], bfr[ni][ks], acc[mi][ni], 0, 0, 0);
    }
    float* po = part + (size_t)kc * 1024 * HH;
    #pragma unroll
    for (int mi = 0; mi < 4; ++mi) {
        #pragma unroll
        for (int ni = 0; ni < 4; ++ni) {
            #pragma unroll
            for (int r = 0; r < 4; ++r) {
                int row = rbase + wm + mi * 16 + lg * 4 + r;
                int col = nbase + wn + ni * 16 + lm;
                po[(size_t)row * HH + col] = acc[mi][ni][r];
            }
        }
    }
}

// ---------------------------------------------------------------------------
// Kernel E: reduce mlp1 partials (8) + bias + gelu -> H; H @ ew2 + eb2 -> aef
// grid 256 (4 rows each), block 256
// ---------------------------------------------------------------------------
__global__ __launch_bounds__(256) void mlp2_k(
    const float* __restrict__ part, const float* __restrict__ eb1,
    const float* __restrict__ ew2, const float* __restrict__ eb2,
    float* __restrict__ out)
{
    __shared__ float Hs[4 * 520];
    const int rbase = blockIdx.x * 4;
    const int t = threadIdx.x;
    #pragma unroll
    for (int pz = 0; pz < 2; ++pz) {
        int pos = t + pz * 256;          // 512 f4: 4 rows x 128
        int r = pos >> 7, j4 = (pos & 127) * 4;
        float4 s = *(const float4*)(eb1 + j4);
        #pragma unroll
        for (int cc = 0; cc < 8; ++cc) {
            float4 v = *(const float4*)(part + (size_t)cc * 1024 * HH +
                                        (size_t)(rbase + r) * HH + j4);
            s.x += v.x; s.y += v.y; s.z += v.z; s.w += v.w;
        }
        float4 h;
        h.x = gelu_f(s.x); h.y = gelu_f(s.y);
        h.z = gelu_f(s.z); h.w = gelu_f(s.w);
        *(float4*)(Hs + r * 520 + j4) = h;
    }
    __syncthreads();
    const int row = t >> 6;              // 0..3 (wave-uniform -> broadcast reads)
    const int c0 = (t & 63) * 4;         // 0..252
    float4 a = make_float4(0.f, 0.f, 0.f, 0.f);
    #pragma unroll 16
    for (int k = 0; k < HH; ++k) {
        float h = Hs[row * 520 + k];
        float4 w = *(const float4*)(ew2 + (size_t)k * EE + c0);
        a.x += h * w.x; a.y += h * w.y; a.z += h * w.z; a.w += h * w.w;
    }
    float4 bb = *(const float4*)(eb2 + c0);
    a.x += bb.x; a.y += bb.y; a.z += bb.z; a.w += bb.w;
    *(float4*)(out + (size_t)(rbase + row) * EE + c0) = a;
}

extern "C" void kernel_launch(void* const* d_in, const int* in_sizes, int n_in,
                              void* d_out, int out_size, void* d_ws, size_t ws_size,
                              hipStream_t stream) {
    const float* gr  = (const float*)d_in[0];
    const float* ga  = (const float*)d_in[1];
    const float* afv = (const float*)d_in[2];
    const float* cw1 = (const float*)d_in[3];
    const float* cb1 = (const float*)d_in[4];
    const float* cw2 = (const float*)d_in[5];
    const float* cb2 = (const float*)d_in[6];
    const float* ew1 = (const float*)d_in[7];
    const float* eb1 = (const float*)d_in[8];
    const float* ew2 = (const float*)d_in[9];
    const float* eb2 = (const float*)d_in[10];
    float* out = (float*)d_out;
    float* ws = (float*)d_ws;

    unsigned short* pairT  = (unsigned short*)(ws + WS_PAIRT);
    unsigned short* Xb     = (unsigned short*)(ws + WS_XB);
    float* gavp            = ws + WS_GAVP;   // aliased with mlp1 partials
    unsigned short* ew1bT  = (unsigned short*)(ws + WS_EW1B);

    stage1_k<<<dim3(3320), dim3(256), 0, stream>>>(afv, cw1, cb1, cw2, cb2, pairT,
                                                   gr, Xb, out + (size_t)BB * NN * EE,
                                                   ew1, ew1bT);
    gav_k<<<dim3(1024), dim3(256), 0, stream>>>(ga, pairT, gavp);
    gavred_k<<<dim3(512), dim3(256), 0, stream>>>(gavp, Xb);
    mlp1_k<<<dim3(256), dim3(256), 0, stream>>>(Xb, ew1bT, gavp);
    mlp2_k<<<dim3(256), dim3(256), 0, stream>>>(gavp, eb1, ew2, eb2, out);
}

// Round 6
// 237.159 us; speedup vs baseline: 1.9436x; 1.1057x over previous
//
#include <hip/hip_runtime.h>
#include <math.h>

// Problem constants (fixed by setup_inputs)
#define BB 8
#define NN 128
#define AA 64
#define RR 32
#define RA 16
#define PP 8128            // N*(N-1)/2
#define DP 32
#define HH 512
#define EE 256
#define XDIM 2560          // RR*AA + RA*DP = 2048 + 512

// workspace layout (float offsets)
static constexpr size_t WS_PAIRT = 0;                                // pair^T bf16 [b][32][8128]
static constexpr size_t WS_XB    = WS_PAIRT + (size_t)BB*DP*PP/2;    // X bf16 1024x2560
static constexpr size_t WS_GAVP  = WS_XB + (size_t)BB*NN*XDIM/2;     // gav/mlp1 partials (aliased) f32
static constexpr size_t WS_EW1B  = WS_GAVP + (size_t)8*BB*2048*DP;   // ew1^T bf16 512x2560
static constexpr size_t WS_AFVT  = WS_EW1B + (size_t)HH*XDIM/2;      // afv^T bf16 [b][64][128]
static constexpr size_t WS_CW1T  = WS_AFVT + (size_t)BB*AA*NN/2;     // cw1^T bf16 [128][128]
static constexpr size_t WS_CW2T  = WS_CW1T + (size_t)128*128/2;      // cw2^T bf16 [32][128]

typedef __attribute__((ext_vector_type(8))) short bf16x8;
typedef __attribute__((ext_vector_type(4))) float f32x4;

__device__ __forceinline__ float gelu_f(float x) {
    float u = 0.7978845608028654f * (x + 0.044715f * x * x * x);
    float au = fabsf(u);
    float e = __expf(-2.0f * au);
    float th = (1.0f - e) / (1.0f + e);
    th = copysignf(th, u);
    return 0.5f * x * (1.0f + th);
}

__device__ __forceinline__ unsigned short f2bf(float x) {
    union { float f; unsigned u; } v; v.f = x;
    unsigned r = v.u + 0x7fffu + ((v.u >> 16) & 1u);   // RTNE
    return (unsigned short)(r >> 16);
}

__device__ __forceinline__ bf16x8 pack_bf16x8(float4 a, float4 b) {
    bf16x8 r;
    r[0] = (short)f2bf(a.x); r[1] = (short)f2bf(a.y);
    r[2] = (short)f2bf(a.z); r[3] = (short)f2bf(a.w);
    r[4] = (short)f2bf(b.x); r[5] = (short)f2bf(b.y);
    r[6] = (short)f2bf(b.z); r[7] = (short)f2bf(b.w);
    return r;
}

// ---------------------------------------------------------------------------
// Kernel 0: prep — bf16 transposes of small operands + afv copy to out2.
// grid 84: [0,64) afvT + copy, [64,80) cw1T, [80,84) cw2T
// ---------------------------------------------------------------------------
__global__ __launch_bounds__(256) void prep_k(
    const float* __restrict__ afv, const float* __restrict__ cw1,
    const float* __restrict__ cw2, unsigned short* __restrict__ afvT,
    unsigned short* __restrict__ cw1T, unsigned short* __restrict__ cw2T,
    float* __restrict__ out2)
{
    const int bid = blockIdx.x, t = threadIdx.x;
    if (bid < 64) {
        int idx = bid * 256 + t;              // 16384
        int b = idx >> 11;
        int rem = idx & 2047;
        int a = rem >> 5;
        int m0 = (rem & 31) * 4;
        ushort4 o;
        o.x = f2bf(afv[((size_t)b * NN + m0 + 0) * AA + a]);
        o.y = f2bf(afv[((size_t)b * NN + m0 + 1) * AA + a]);
        o.z = f2bf(afv[((size_t)b * NN + m0 + 2) * AA + a]);
        o.w = f2bf(afv[((size_t)b * NN + m0 + 3) * AA + a]);
        *(ushort4*)(afvT + ((size_t)b * AA + a) * NN + m0) = o;
        float4 v = *(const float4*)(afv + (size_t)idx * 4);
        *(float4*)(out2 + (size_t)idx * 4) = v;
    } else if (bid < 80) {
        int idx = (bid - 64) * 256 + t;       // 4096
        int n = idx >> 5;
        int k0 = (idx & 31) * 4;
        ushort4 o;
        o.x = f2bf(cw1[(size_t)(k0 + 0) * 128 + n]);
        o.y = f2bf(cw1[(size_t)(k0 + 1) * 128 + n]);
        o.z = f2bf(cw1[(size_t)(k0 + 2) * 128 + n]);
        o.w = f2bf(cw1[(size_t)(k0 + 3) * 128 + n]);
        *(ushort4*)(cw1T + (size_t)n * 128 + k0) = o;
    } else {
        int idx = (bid - 80) * 256 + t;       // 1024
        int d = idx >> 5;
        int k0 = (idx & 31) * 4;
        ushort4 o;
        o.x = f2bf(cw2[(size_t)(k0 + 0) * DP + d]);
        o.y = f2bf(cw2[(size_t)(k0 + 1) * DP + d]);
        o.z = f2bf(cw2[(size_t)(k0 + 2) * DP + d]);
        o.w = f2bf(cw2[(size_t)(k0 + 3) * DP + d]);
        *(ushort4*)(cw2T + (size_t)d * 128 + k0) = o;
    }
}

// ---------------------------------------------------------------------------
// Kernel A: fused stage-1 (all MFMA).
//   blocks [0,256): grv GEMM per b: gr[b](4096x128) @ afvT[b]^T -> Xb[...,0:2048]
//   blocks [256,1272): pair MLP (MFMA both layers) -> pairT bf16 [b][d][p]
//   blocks [1272,2552): ew1 -> ew1bT (bf16, [n][k])
// block 256, LDS 32KB+0.5KB -> 4 blocks/CU
// ---------------------------------------------------------------------------
#define NB_GRV 256
#define NB_PAIR 1016

__global__ __launch_bounds__(256) void stage1_k(
    const float* __restrict__ afv, const unsigned short* __restrict__ cw1T,
    const float* __restrict__ cb1, const unsigned short* __restrict__ cw2T,
    const float* __restrict__ cb2, unsigned short* __restrict__ pairT,
    const float* __restrict__ gr, unsigned short* __restrict__ Xb,
    const unsigned short* __restrict__ afvT,
    const float* __restrict__ ew1, unsigned short* __restrict__ ew1bT)
{
    __shared__ unsigned short sm[16384];   // 32KB, multi-purpose
    __shared__ int iis[64], jjs[64];
    const int bid = blockIdx.x;
    const int t = threadIdx.x;
    const int w = t >> 6, lane = t & 63;
    const int lm = lane & 15, lg = lane >> 4;

    if (bid >= NB_GRV + NB_PAIR) {
        // ---------------- ew1 convert+transpose ----------------
        int q = (bid - (NB_GRV + NB_PAIR)) * 256 + t;   // 0..327679
        int n = q & 511;
        int k0 = (q >> 9) * 4;
        ushort4 o;
        o.x = f2bf(ew1[(size_t)(k0 + 0) * HH + n]);
        o.y = f2bf(ew1[(size_t)(k0 + 1) * HH + n]);
        o.z = f2bf(ew1[(size_t)(k0 + 2) * HH + n]);
        o.w = f2bf(ew1[(size_t)(k0 + 3) * HH + n]);
        *(ushort4*)(ew1bT + (size_t)n * XDIM + k0) = o;
        return;
    }

    if (bid < NB_GRV) {
        // ---------------- grv MFMA path ----------------
        // block: b = bid>>5, rows rbase..rbase+127 of the 4096x128 gr[b] matrix
        const int b = bid >> 5;
        const int rbase = (bid & 31) * 128;
        const float* gab = gr + ((size_t)b * 4096 + rbase) * NN;
        unsigned short* As = sm;            // [128][128] bf16 swizzled
        // stage gr f32 -> bf16 LDS
        const int srow = t >> 1, half = t & 1;
        const float* arow = gab + (size_t)srow * NN + half * 64;
        #pragma unroll
        for (int q = 0; q < 8; ++q) {
            float4 x0 = *(const float4*)(arow + q * 8);
            float4 x1 = *(const float4*)(arow + q * 8 + 4);
            bf16x8 v = pack_bf16x8(x0, x1);
            int g = half * 8 + q;
            *(bf16x8*)(As + srow * 128 + ((g ^ (srow & 7)) * 8)) = v;
        }
        __syncthreads();
        const int wm = w * 32;
        f32x4 acc[2][4];
        #pragma unroll
        for (int i = 0; i < 2; ++i)
            #pragma unroll
            for (int j = 0; j < 4; ++j) acc[i][j] = 0.f;
        const unsigned short* Bb = afvT + (size_t)b * AA * NN;   // [64][128]
        #pragma unroll
        for (int ks = 0; ks < 4; ++ks) {
            int g = ks * 4 + lg;
            int r0 = wm + lm, r1 = wm + 16 + lm;
            bf16x8 a0 = *(const bf16x8*)(As + r0 * 128 + ((g ^ (r0 & 7)) * 8));
            bf16x8 a1 = *(const bf16x8*)(As + r1 * 128 + ((g ^ (r1 & 7)) * 8));
            #pragma unroll
            for (int ni = 0; ni < 4; ++ni) {
                bf16x8 bv = *(const bf16x8*)(Bb + (size_t)(ni * 16 + lm) * NN + ks * 32 + lg * 8);
                acc[0][ni] = __builtin_amdgcn_mfma_f32_16x16x32_bf16(a0, bv, acc[0][ni], 0, 0, 0);
                acc[1][ni] = __builtin_amdgcn_mfma_f32_16x16x32_bf16(a1, bv, acc[1][ni], 0, 0, 0);
            }
        }
        __syncthreads();
        unsigned short* T = sm;             // [128][64] bf16
        #pragma unroll
        for (int mi = 0; mi < 2; ++mi)
            #pragma unroll
            for (int ni = 0; ni < 4; ++ni)
                #pragma unroll
                for (int r = 0; r < 4; ++r)
                    T[(wm + mi * 16 + lg * 4 + r) * 64 + ni * 16 + lm] =
                        f2bf(acc[mi][ni][r]);
        __syncthreads();
        #pragma unroll
        for (int q = 0; q < 4; ++q) {
            int idx = t + q * 256;          // 1024 slots
            int rr2 = idx >> 3, slot = idx & 7;
            bf16x8 v = *(const bf16x8*)(T + rr2 * 64 + slot * 8);
            int grow = rbase + rr2;
            *(bf16x8*)(Xb + ((size_t)(b * NN) + (grow >> 5)) * XDIM +
                       (grow & 31) * 64 + slot * 8) = v;
        }
        return;
    }

    // ---------------- pair MLP MFMA path ----------------
    const int bid2 = bid - NB_GRV;
    const int b = bid2 / 127;
    const int pbase = (bid2 % 127) * 64;
    unsigned short* X = sm;                 // [64][128] bf16 swizzled
    unsigned short* Hs = sm + 8192;         // [64][128] bf16 swizzled

    if (t < 64) {
        int p = pbase + t;
        int i = 0;
        while (i < 126) {
            int nx = i + 1;
            int off = nx * 127 - (nx * (nx - 1)) / 2;
            if (off <= p) i = nx; else break;
        }
        int off = i * 127 - (i * (i - 1)) / 2;
        iis[t] = i;
        jjs[t] = i + 1 + (p - off);
    }
    __syncthreads();
    {
        int pp = t & 63, seg = t >> 6;      // k-range seg*16..+15
        const float* ar = afv + (size_t)(b * NN + iis[pp]) * AA + seg * 16;
        const float* br = afv + (size_t)(b * NN + jjs[pp]) * AA + seg * 16;
        float4 xa = *(const float4*)(ar),     xb2 = *(const float4*)(ar + 4);
        float4 xc = *(const float4*)(ar + 8), xd = *(const float4*)(ar + 12);
        float4 ya = *(const float4*)(br),     yb = *(const float4*)(br + 4);
        float4 yc = *(const float4*)(br + 8), yd = *(const float4*)(br + 12);
        float4 s0 = make_float4(xa.x + ya.x, xa.y + ya.y, xa.z + ya.z, xa.w + ya.w);
        float4 s1 = make_float4(xb2.x + yb.x, xb2.y + yb.y, xb2.z + yb.z, xb2.w + yb.w);
        float4 s2 = make_float4(xc.x + yc.x, xc.y + yc.y, xc.z + yc.z, xc.w + yc.w);
        float4 s3 = make_float4(xd.x + yd.x, xd.y + yd.y, xd.z + yd.z, xd.w + yd.w);
        float4 p0 = make_float4(xa.x * ya.x, xa.y * ya.y, xa.z * ya.z, xa.w * ya.w);
        float4 p1 = make_float4(xb2.x * yb.x, xb2.y * yb.y, xb2.z * yb.z, xb2.w * yb.w);
        float4 p2 = make_float4(xc.x * yc.x, xc.y * yc.y, xc.z * yc.z, xc.w * yc.w);
        float4 p3 = make_float4(xd.x * yd.x, xd.y * yd.y, xd.z * yd.z, xd.w * yd.w);
        int gs = seg * 2, gp = 8 + seg * 2, sw = pp & 7;
        *(bf16x8*)(X + pp * 128 + (((gs + 0) ^ sw) * 8)) = pack_bf16x8(s0, s1);
        *(bf16x8*)(X + pp * 128 + (((gs + 1) ^ sw) * 8)) = pack_bf16x8(s2, s3);
        *(bf16x8*)(X + pp * 128 + (((gp + 0) ^ sw) * 8)) = pack_bf16x8(p0, p1);
        *(bf16x8*)(X + pp * 128 + (((gp + 1) ^ sw) * 8)) = pack_bf16x8(p2, p3);
    }
    __syncthreads();
    // layer 1: X(64x128) @ cw1T-frags (global, L2) -> acc1, wave w: cols w*32..+31
    const int wn = w * 32;
    f32x4 acc1[4][2];
    #pragma unroll
    for (int i = 0; i < 4; ++i)
        #pragma unroll
        for (int j = 0; j < 2; ++j) acc1[i][j] = 0.f;
    #pragma unroll
    for (int ks = 0; ks < 4; ++ks) {
        int g = ks * 4 + lg;
        bf16x8 a[4];
        #pragma unroll
        for (int mi = 0; mi < 4; ++mi) {
            int row = mi * 16 + lm;
            a[mi] = *(const bf16x8*)(X + row * 128 + ((g ^ (row & 7)) * 8));
        }
        #pragma unroll
        for (int ni = 0; ni < 2; ++ni) {
            bf16x8 bv = *(const bf16x8*)(cw1T + (size_t)(wn + ni * 16 + lm) * 128 +
                                         ks * 32 + lg * 8);
            #pragma unroll
            for (int mi = 0; mi < 4; ++mi)
                acc1[mi][ni] = __builtin_amdgcn_mfma_f32_16x16x32_bf16(
                    a[mi], bv, acc1[mi][ni], 0, 0, 0);
        }
    }
    // bias + gelu -> Hs (bf16, swizzled).  C layout: row=mi*16+lg*4+r, col=wn+ni*16+lm
    #pragma unroll
    for (int ni = 0; ni < 2; ++ni) {
        int n = wn + ni * 16 + lm;
        float bb = cb1[n];
        int gn = n >> 3, ne = n & 7;
        #pragma unroll
        for (int mi = 0; mi < 4; ++mi)
            #pragma unroll
            for (int r = 0; r < 4; ++r) {
                int row = mi * 16 + lg * 4 + r;
                Hs[row * 128 + ((gn ^ (row & 7)) * 8 + ne)] =
                    f2bf(gelu_f(acc1[mi][ni][r] + bb));
            }
    }
    __syncthreads();
    // layer 2: H(64x128) @ cw2T-frags -> 64x32, wave w: rows w*16..+15
    f32x4 acc2[2];
    acc2[0] = 0.f; acc2[1] = 0.f;
    #pragma unroll
    for (int ks = 0; ks < 4; ++ks) {
        int row = w * 16 + lm;
        int g = ks * 4 + lg;
        bf16x8 a2 = *(const bf16x8*)(Hs + row * 128 + ((g ^ (row & 7)) * 8));
        #pragma unroll
        for (int ni = 0; ni < 2; ++ni) {
            bf16x8 bv = *(const bf16x8*)(cw2T + (size_t)(ni * 16 + lm) * 128 +
                                         ks * 32 + lg * 8);
            acc2[ni] = __builtin_amdgcn_mfma_f32_16x16x32_bf16(a2, bv, acc2[ni], 0, 0, 0);
        }
    }
    // transpose via LDS (alias X region): T[32 d][64 p]
    {
        unsigned short* T = sm;
        #pragma unroll
        for (int ni = 0; ni < 2; ++ni) {
            int d = ni * 16 + lm;
            float bb = cb2[d];
            #pragma unroll
            for (int r = 0; r < 4; ++r) {
                int p = w * 16 + lg * 4 + r;
                T[d * 64 + p] = f2bf(acc2[ni][r] + bb);
            }
        }
        __syncthreads();
        int d = t >> 3, slot = t & 7;
        bf16x8 v = *(const bf16x8*)(T + d * 64 + slot * 8);
        *(bf16x8*)(pairT + ((size_t)b * DP + d) * PP + pbase + slot * 8) = v;
    }
}

// ---------------------------------------------------------------------------
// Kernel B: gav partials via bf16 MFMA with on-the-fly f32->bf16 conversion.
// grid 1024 = b(8) x rowtile(16: 128 rows) x kchunk(8), block 256, 4 blk/CU
// ---------------------------------------------------------------------------
__global__ __launch_bounds__(256, 4) void gav_k(
    const float* __restrict__ ga, const unsigned short* __restrict__ pairT,
    float* __restrict__ part)
{
    __shared__ unsigned short As[128 * 64];
    __shared__ unsigned short Bs[32 * 64];
    const int bid = blockIdx.x;
    const int c = bid & 7, rt = (bid >> 3) & 15, b = bid >> 7;
    const int rbase = rt * 128;
    const int kstart = c * 1024;
    const int kend = (kstart + 1024 < PP) ? (kstart + 1024) : PP;
    const int niter = (kend - kstart) >> 6;
    const int t = threadIdx.x;
    const int srow = t >> 1;
    const int khalf = (t & 1) * 32;
    const int bd = t >> 3, bslot = t & 7;
    const int w = t >> 6, lane = t & 63;
    const int wm = w * 32;
    const int lm = lane & 15, lg = lane >> 4;

    f32x4 acc[2][2];
    #pragma unroll
    for (int i = 0; i < 2; ++i)
        #pragma unroll
        for (int j = 0; j < 2; ++j) acc[i][j] = 0.f;

    const float* gab = ga + (size_t)(b * 2048 + rbase) * PP;
    const unsigned short* pbT = pairT + (size_t)b * DP * PP;

    float4 ra[8];
    bf16x8 rb;
    #pragma unroll
    for (int q = 0; q < 8; ++q)
        ra[q] = *(const float4*)(gab + (size_t)srow * PP + kstart + khalf + q * 4);
    rb = *(const bf16x8*)(pbT + (size_t)bd * PP + kstart + bslot * 8);

    for (int it = 0; it < niter; ++it) {
        __syncthreads();
        #pragma unroll
        for (int q2 = 0; q2 < 4; ++q2) {
            bf16x8 v = pack_bf16x8(ra[2 * q2], ra[2 * q2 + 1]);
            int g = ((khalf >> 3) + q2) ^ (srow & 7);
            *(bf16x8*)(As + srow * 64 + g * 8) = v;
        }
        *(bf16x8*)(Bs + bd * 64 + ((bslot ^ (bd & 7)) * 8)) = rb;
        __syncthreads();
        if (it + 1 < niter) {
            int kn = kstart + (it + 1) * 64;
            #pragma unroll
            for (int q = 0; q < 8; ++q)
                ra[q] = *(const float4*)(gab + (size_t)srow * PP + kn + khalf + q * 4);
            rb = *(const bf16x8*)(pbT + (size_t)bd * PP + kn + bslot * 8);
        }
        bf16x8 af[2][2], bf_[2][2];
        #pragma unroll
        for (int mi = 0; mi < 2; ++mi)
            #pragma unroll
            for (int ks = 0; ks < 2; ++ks) {
                int row = wm + mi * 16 + lm;
                int s = ks * 4 + lg;
                af[mi][ks] = *(const bf16x8*)(As + row * 64 + ((s ^ (row & 7)) * 8));
            }
        #pragma unroll
        for (int ni = 0; ni < 2; ++ni)
            #pragma unroll
            for (int ks = 0; ks < 2; ++ks) {
                int col = ni * 16 + lm;
                int s = ks * 4 + lg;
                bf_[ni][ks] = *(const bf16x8*)(Bs + col * 64 + ((s ^ (col & 7)) * 8));
            }
        #pragma unroll
        for (int ks = 0; ks < 2; ++ks)
            #pragma unroll
            for (int mi = 0; mi < 2; ++mi)
                #pragma unroll
                for (int ni = 0; ni < 2; ++ni)
                    acc[mi][ni] = __builtin_amdgcn_mfma_f32_16x16x32_bf16(
                        af[mi][ks], bf_[ni][ks], acc[mi][ni], 0, 0, 0);
    }
    float* pout = part + ((size_t)(c * 8 + b) * 2048 + rbase) * DP;
    #pragma unroll
    for (int mi = 0; mi < 2; ++mi)
        #pragma unroll
        for (int ni = 0; ni < 2; ++ni)
            #pragma unroll
            for (int r = 0; r < 4; ++r)
                pout[(size_t)(wm + mi * 16 + lg * 4 + r) * DP + ni * 16 + lm] =
                    acc[mi][ni][r];
}

// ---------------------------------------------------------------------------
// Kernel C: reduce gav partials (8 chunks) -> Xb[..., 2048 + a*32 + d] (bf16)
// ---------------------------------------------------------------------------
__global__ __launch_bounds__(256) void gavred_k(
    const float* __restrict__ part, unsigned short* __restrict__ Xb)
{
    int idx = blockIdx.x * 256 + threadIdx.x;
    int e = idx * 4;
    int row = e >> 5;
    int d0 = e & 31;
    int b = row >> 11, r = row & 2047;
    float4 s = make_float4(0.f, 0.f, 0.f, 0.f);
    #pragma unroll
    for (int c = 0; c < 8; ++c) {
        float4 v = *(const float4*)(part + ((size_t)(c * 8 + b) * 2048 + r) * DP + d0);
        s.x += v.x; s.y += v.y; s.z += v.z; s.w += v.w;
    }
    int n = r >> 4, a = r & 15;
    ushort4 o;
    o.x = f2bf(s.x); o.y = f2bf(s.y); o.z = f2bf(s.z); o.w = f2bf(s.w);
    *(ushort4*)(Xb + (size_t)(b * NN + n) * XDIM + 2048 + a * DP + d0) = o;
}

// ---------------------------------------------------------------------------
// Kernel D: mlp layer1 partials via bf16 MFMA.  K split 8.
// grid 256 = rt(8: 128 rows) x ct(4: 128 cols) x kc(8: K=320), block 256
// ---------------------------------------------------------------------------
__global__ __launch_bounds__(256) void mlp1_k(
    const unsigned short* __restrict__ Xb,
    const unsigned short* __restrict__ Wt,
    float* __restrict__ part)
{
    __shared__ unsigned short As[128 * 64];
    __shared__ unsigned short Bs[128 * 64];
    const int bid = blockIdx.x;
    const int kc = bid & 7, ct = (bid >> 3) & 3, rt = bid >> 5;
    const int rbase = rt * 128, nbase = ct * 128;
    const int k0 = kc * 320;
    const int t = threadIdx.x;
    const int w = t >> 6, lane = t & 63;
    const int wm = (w >> 1) * 64, wn = (w & 1) * 64;
    const int lm = lane & 15, lg = lane >> 4;

    f32x4 acc[4][4];
    #pragma unroll
    for (int i = 0; i < 4; ++i)
        #pragma unroll
        for (int j = 0; j < 4; ++j) acc[i][j] = 0.f;

    const int srow = t >> 1;
    const int sh = (t & 1) * 4;
    const unsigned short* Arow = Xb + (size_t)(rbase + srow) * XDIM + k0;
    const unsigned short* Brow = Wt + (size_t)(nbase + srow) * XDIM + k0;

    bf16x8 rA[4], rB[4];
    #pragma unroll
    for (int q = 0; q < 4; ++q) {
        rA[q] = *(const bf16x8*)(Arow + (sh + q) * 8);
        rB[q] = *(const bf16x8*)(Brow + (sh + q) * 8);
    }

    for (int it = 0; it < 5; ++it) {
        __syncthreads();
        #pragma unroll
        for (int q = 0; q < 4; ++q) {
            int g = ((sh + q) ^ (srow & 7)) * 8;
            *(bf16x8*)(As + srow * 64 + g) = rA[q];
            *(bf16x8*)(Bs + srow * 64 + g) = rB[q];
        }
        __syncthreads();
        if (it + 1 < 5) {
            int ko = (it + 1) * 64;
            #pragma unroll
            for (int q = 0; q < 4; ++q) {
                rA[q] = *(const bf16x8*)(Arow + ko + (sh + q) * 8);
                rB[q] = *(const bf16x8*)(Brow + ko + (sh + q) * 8);
            }
        }
        bf16x8 af[4][2], bfr[4][2];
        #pragma unroll
        for (int mi = 0; mi < 4; ++mi) {
            #pragma unroll
            for (int ks = 0; ks < 2; ++ks) {
                int rowa = wm + mi * 16 + lm;
                int s = ks * 4 + lg;
                af[mi][ks] = *(const bf16x8*)(As + rowa * 64 + ((s ^ (rowa & 7)) * 8));
                int rowb = wn + mi * 16 + lm;
                bfr[mi][ks] = *(const bf16x8*)(Bs + rowb * 64 + ((s ^ (rowb & 7)) * 8));
            }
        }
        #pragma unroll
        for (int ks = 0; ks < 2; ++ks)
            #pragma unroll
            for (int mi = 0; mi < 4; ++mi)
                #pragma unroll
                for (int ni = 0; ni < 4; ++ni)
                    acc[mi][ni] = __builtin_amdgcn_mfma_f32_16x16x32_bf16(
                        af[mi][ks], bfr[ni][ks], acc[mi][ni], 0, 0, 0);
    }
    float* po = part + (size_t)kc * 1024 * HH;
    #pragma unroll
    for (int mi = 0; mi < 4; ++mi) {
        #pragma unroll
        for (int ni = 0; ni < 4; ++ni) {
            #pragma unroll
            for (int r = 0; r < 4; ++r) {
                int row = rbase + wm + mi * 16 + lg * 4 + r;
                int col = nbase + wn + ni * 16 + lm;
                po[(size_t)row * HH + col] = acc[mi][ni][r];
            }
        }
    }
}

// ---------------------------------------------------------------------------
// Kernel E: reduce mlp1 partials (8) + bias + gelu -> H; H @ ew2 + eb2 -> aef
// grid 256 (4 rows each), block 256
// ---------------------------------------------------------------------------
__global__ __launch_bounds__(256) void mlp2_k(
    const float* __restrict__ part, const float* __restrict__ eb1,
    const float* __restrict__ ew2, const float* __restrict__ eb2,
    float* __restrict__ out)
{
    __shared__ float Hs[4 * 520];
    const int rbase = blockIdx.x * 4;
    const int t = threadIdx.x;
    #pragma unroll
    for (int pz = 0; pz < 2; ++pz) {
        int pos = t + pz * 256;
        int r = pos >> 7, j4 = (pos & 127) * 4;
        float4 s = *(const float4*)(eb1 + j4);
        #pragma unroll
        for (int cc = 0; cc < 8; ++cc) {
            float4 v = *(const float4*)(part + (size_t)cc * 1024 * HH +
                                        (size_t)(rbase + r) * HH + j4);
            s.x += v.x; s.y += v.y; s.z += v.z; s.w += v.w;
        }
        float4 h;
        h.x = gelu_f(s.x); h.y = gelu_f(s.y);
        h.z = gelu_f(s.z); h.w = gelu_f(s.w);
        *(float4*)(Hs + r * 520 + j4) = h;
    }
    __syncthreads();
    const int row = t >> 6;
    const int c0 = (t & 63) * 4;
    float4 a = make_float4(0.f, 0.f, 0.f, 0.f);
    #pragma unroll 16
    for (int k = 0; k < HH; ++k) {
        float h = Hs[row * 520 + k];
        float4 w = *(const float4*)(ew2 + (size_t)k * EE + c0);
        a.x += h * w.x; a.y += h * w.y; a.z += h * w.z; a.w += h * w.w;
    }
    float4 bb = *(const float4*)(eb2 + c0);
    a.x += bb.x; a.y += bb.y; a.z += bb.z; a.w += bb.w;
    *(float4*)(out + (size_t)(rbase + row) * EE + c0) = a;
}

extern "C" void kernel_launch(void* const* d_in, const int* in_sizes, int n_in,
                              void* d_out, int out_size, void* d_ws, size_t ws_size,
                              hipStream_t stream) {
    const float* gr  = (const float*)d_in[0];
    const float* ga  = (const float*)d_in[1];
    const float* afv = (const float*)d_in[2];
    const float* cw1 = (const float*)d_in[3];
    const float* cb1 = (const float*)d_in[4];
    const float* cw2 = (const float*)d_in[5];
    const float* cb2 = (const float*)d_in[6];
    const float* ew1 = (const float*)d_in[7];
    const float* eb1 = (const float*)d_in[8];
    const float* ew2 = (const float*)d_in[9];
    const float* eb2 = (const float*)d_in[10];
    float* out = (float*)d_out;
    float* ws = (float*)d_ws;

    unsigned short* pairT  = (unsigned short*)(ws + WS_PAIRT);
    unsigned short* Xb     = (unsigned short*)(ws + WS_XB);
    float* gavp            = ws + WS_GAVP;   // aliased with mlp1 partials
    unsigned short* ew1bT  = (unsigned short*)(ws + WS_EW1B);
    unsigned short* afvT   = (unsigned short*)(ws + WS_AFVT);
    unsigned short* cw1T   = (unsigned short*)(ws + WS_CW1T);
    unsigned short* cw2T   = (unsigned short*)(ws + WS_CW2T);

    prep_k<<<dim3(84), dim3(256), 0, stream>>>(afv, cw1, cw2, afvT, cw1T, cw2T,
                                               out + (size_t)BB * NN * EE);
    stage1_k<<<dim3(2552), dim3(256), 0, stream>>>(afv, cw1T, cb1, cw2T, cb2, pairT,
                                                   gr, Xb, afvT, ew1, ew1bT);
    gav_k<<<dim3(1024), dim3(256), 0, stream>>>(ga, pairT, gavp);
    gavred_k<<<dim3(512), dim3(256), 0, stream>>>(gavp, Xb);
    mlp1_k<<<dim3(256), dim3(256), 0, stream>>>(Xb, ew1bT, gavp);
    mlp2_k<<<dim3(256), dim3(256), 0, stream>>>(gavp, eb1, ew2, eb2, out);
}

// Round 7
// 201.272 us; speedup vs baseline: 2.2902x; 1.1783x over previous
//
#include <hip/hip_runtime.h>
#include <math.h>

// Problem constants (fixed by setup_inputs)
#define BB 8
#define NN 128
#define AA 64
#define RR 32
#define RA 16
#define PP 8128            // N*(N-1)/2 = 127*64
#define DP 32
#define HH 512
#define EE 256
#define XDIM 2560          // RR*AA + RA*DP = 2048 + 512

// workspace layout (float offsets)
static constexpr size_t WS_PAIRT = 0;                                // pair^T bf16 [b][32][8128]
static constexpr size_t WS_XB    = WS_PAIRT + (size_t)BB*DP*PP/2;    // X bf16 1024x2560
static constexpr size_t WS_EW1B  = WS_XB + (size_t)BB*NN*XDIM/2;     // ew1^T bf16 [512][2560]
static constexpr size_t WS_AFVT  = WS_EW1B + (size_t)HH*XDIM/2;      // afv^T bf16 [b][64][128]
static constexpr size_t WS_CW1T  = WS_AFVT + (size_t)BB*AA*NN/2;     // cw1^T bf16 [128][128]
static constexpr size_t WS_CW2T  = WS_CW1T + (size_t)128*128/2;      // cw2^T bf16 [32][128]
static constexpr size_t WS_EW2B  = WS_CW2T + (size_t)DP*128/2;       // ew2^T bf16 [256][512]
static constexpr size_t WS_HB    = WS_EW2B + (size_t)EE*HH/2;        // H bf16 [1024][512]

typedef __attribute__((ext_vector_type(8))) short bf16x8;
typedef __attribute__((ext_vector_type(4))) float f32x4;

__device__ __forceinline__ float gelu_f(float x) {
    float u = 0.7978845608028654f * (x + 0.044715f * x * x * x);
    float au = fabsf(u);
    float e = __expf(-2.0f * au);
    float th = (1.0f - e) / (1.0f + e);
    th = copysignf(th, u);
    return 0.5f * x * (1.0f + th);
}

__device__ __forceinline__ unsigned short f2bf(float x) {
    union { float f; unsigned u; } v; v.f = x;
    unsigned r = v.u + 0x7fffu + ((v.u >> 16) & 1u);   // RTNE
    return (unsigned short)(r >> 16);
}

__device__ __forceinline__ bf16x8 pack_bf16x8(float4 a, float4 b) {
    bf16x8 r;
    r[0] = (short)f2bf(a.x); r[1] = (short)f2bf(a.y);
    r[2] = (short)f2bf(a.z); r[3] = (short)f2bf(a.w);
    r[4] = (short)f2bf(b.x); r[5] = (short)f2bf(b.y);
    r[6] = (short)f2bf(b.z); r[7] = (short)f2bf(b.w);
    return r;
}

// ---------------------------------------------------------------------------
// Kernel 0: prep — bf16 transposes of small operands + afv copy to out2.
// grid 84: [0,64) afvT + copy, [64,80) cw1T, [80,84) cw2T
// ---------------------------------------------------------------------------
__global__ __launch_bounds__(256) void prep_k(
    const float* __restrict__ afv, const float* __restrict__ cw1,
    const float* __restrict__ cw2, unsigned short* __restrict__ afvT,
    unsigned short* __restrict__ cw1T, unsigned short* __restrict__ cw2T,
    float* __restrict__ out2)
{
    const int bid = blockIdx.x, t = threadIdx.x;
    if (bid < 64) {
        int idx = bid * 256 + t;              // 16384
        int b = idx >> 11;
        int rem = idx & 2047;
        int a = rem >> 5;
        int m0 = (rem & 31) * 4;
        ushort4 o;
        o.x = f2bf(afv[((size_t)b * NN + m0 + 0) * AA + a]);
        o.y = f2bf(afv[((size_t)b * NN + m0 + 1) * AA + a]);
        o.z = f2bf(afv[((size_t)b * NN + m0 + 2) * AA + a]);
        o.w = f2bf(afv[((size_t)b * NN + m0 + 3) * AA + a]);
        *(ushort4*)(afvT + ((size_t)b * AA + a) * NN + m0) = o;
        float4 v = *(const float4*)(afv + (size_t)idx * 4);
        *(float4*)(out2 + (size_t)idx * 4) = v;
    } else if (bid < 80) {
        int idx = (bid - 64) * 256 + t;       // 4096
        int n = idx >> 5;
        int k0 = (idx & 31) * 4;
        ushort4 o;
        o.x = f2bf(cw1[(size_t)(k0 + 0) * 128 + n]);
        o.y = f2bf(cw1[(size_t)(k0 + 1) * 128 + n]);
        o.z = f2bf(cw1[(size_t)(k0 + 2) * 128 + n]);
        o.w = f2bf(cw1[(size_t)(k0 + 3) * 128 + n]);
        *(ushort4*)(cw1T + (size_t)n * 128 + k0) = o;
    } else {
        int idx = (bid - 80) * 256 + t;       // 1024
        int d = idx >> 5;
        int k0 = (idx & 31) * 4;
        ushort4 o;
        o.x = f2bf(cw2[(size_t)(k0 + 0) * DP + d]);
        o.y = f2bf(cw2[(size_t)(k0 + 1) * DP + d]);
        o.z = f2bf(cw2[(size_t)(k0 + 2) * DP + d]);
        o.w = f2bf(cw2[(size_t)(k0 + 3) * DP + d]);
        *(ushort4*)(cw2T + (size_t)d * 128 + k0) = o;
    }
}

// ---------------------------------------------------------------------------
// Kernel A: fused stage-1 (all MFMA).
//   blocks [0,256): grv GEMM per b -> Xb[...,0:2048]
//   blocks [256,1272): pair MLP -> pairT bf16 [b][d][p]
//   blocks [1272,2552): ew1 -> ew1bT (bf16, [n][k])
//   blocks [2552,2680): ew2 -> ew2bT (bf16, [n][k])
// block 256
// ---------------------------------------------------------------------------
#define NB_GRV 256
#define NB_PAIR 1016
#define NB_EW1 1280

__global__ __launch_bounds__(256) void stage1_k(
    const float* __restrict__ afv, const unsigned short* __restrict__ cw1T,
    const float* __restrict__ cb1, const unsigned short* __restrict__ cw2T,
    const float* __restrict__ cb2, unsigned short* __restrict__ pairT,
    const float* __restrict__ gr, unsigned short* __restrict__ Xb,
    const unsigned short* __restrict__ afvT,
    const float* __restrict__ ew1, unsigned short* __restrict__ ew1bT,
    const float* __restrict__ ew2, unsigned short* __restrict__ ew2bT)
{
    __shared__ unsigned short sm[16384];   // 32KB, multi-purpose
    __shared__ int iis[64], jjs[64];
    const int bid = blockIdx.x;
    const int t = threadIdx.x;
    const int w = t >> 6, lane = t & 63;
    const int lm = lane & 15, lg = lane >> 4;

    if (bid >= NB_GRV + NB_PAIR + NB_EW1) {
        // ---------------- ew2 convert+transpose ----------------
        int q = (bid - (NB_GRV + NB_PAIR + NB_EW1)) * 256 + t;  // 0..32767
        int n = q & 255;
        int k0 = (q >> 8) * 4;
        ushort4 o;
        o.x = f2bf(ew2[(size_t)(k0 + 0) * EE + n]);
        o.y = f2bf(ew2[(size_t)(k0 + 1) * EE + n]);
        o.z = f2bf(ew2[(size_t)(k0 + 2) * EE + n]);
        o.w = f2bf(ew2[(size_t)(k0 + 3) * EE + n]);
        *(ushort4*)(ew2bT + (size_t)n * HH + k0) = o;
        return;
    }
    if (bid >= NB_GRV + NB_PAIR) {
        // ---------------- ew1 convert+transpose ----------------
        int q = (bid - (NB_GRV + NB_PAIR)) * 256 + t;   // 0..327679
        int n = q & 511;
        int k0 = (q >> 9) * 4;
        ushort4 o;
        o.x = f2bf(ew1[(size_t)(k0 + 0) * HH + n]);
        o.y = f2bf(ew1[(size_t)(k0 + 1) * HH + n]);
        o.z = f2bf(ew1[(size_t)(k0 + 2) * HH + n]);
        o.w = f2bf(ew1[(size_t)(k0 + 3) * HH + n]);
        *(ushort4*)(ew1bT + (size_t)n * XDIM + k0) = o;
        return;
    }

    if (bid < NB_GRV) {
        // ---------------- grv MFMA path ----------------
        const int b = bid >> 5;
        const int rbase = (bid & 31) * 128;
        const float* gab = gr + ((size_t)b * 4096 + rbase) * NN;
        unsigned short* As = sm;            // [128][128] bf16 swizzled
        const int srow = t >> 1, half = t & 1;
        const float* arow = gab + (size_t)srow * NN + half * 64;
        #pragma unroll
        for (int q = 0; q < 8; ++q) {
            float4 x0 = *(const float4*)(arow + q * 8);
            float4 x1 = *(const float4*)(arow + q * 8 + 4);
            bf16x8 v = pack_bf16x8(x0, x1);
            int g = half * 8 + q;
            *(bf16x8*)(As + srow * 128 + ((g ^ (srow & 7)) * 8)) = v;
        }
        __syncthreads();
        const int wm = w * 32;
        f32x4 acc[2][4];
        #pragma unroll
        for (int i = 0; i < 2; ++i)
            #pragma unroll
            for (int j = 0; j < 4; ++j) acc[i][j] = 0.f;
        const unsigned short* Bb = afvT + (size_t)b * AA * NN;   // [64][128]
        #pragma unroll
        for (int ks = 0; ks < 4; ++ks) {
            int g = ks * 4 + lg;
            int r0 = wm + lm, r1 = wm + 16 + lm;
            bf16x8 a0 = *(const bf16x8*)(As + r0 * 128 + ((g ^ (r0 & 7)) * 8));
            bf16x8 a1 = *(const bf16x8*)(As + r1 * 128 + ((g ^ (r1 & 7)) * 8));
            #pragma unroll
            for (int ni = 0; ni < 4; ++ni) {
                bf16x8 bv = *(const bf16x8*)(Bb + (size_t)(ni * 16 + lm) * NN + ks * 32 + lg * 8);
                acc[0][ni] = __builtin_amdgcn_mfma_f32_16x16x32_bf16(a0, bv, acc[0][ni], 0, 0, 0);
                acc[1][ni] = __builtin_amdgcn_mfma_f32_16x16x32_bf16(a1, bv, acc[1][ni], 0, 0, 0);
            }
        }
        __syncthreads();
        unsigned short* T = sm;             // [128][64] bf16
        #pragma unroll
        for (int mi = 0; mi < 2; ++mi)
            #pragma unroll
            for (int ni = 0; ni < 4; ++ni)
                #pragma unroll
                for (int r = 0; r < 4; ++r)
                    T[(wm + mi * 16 + lg * 4 + r) * 64 + ni * 16 + lm] =
                        f2bf(acc[mi][ni][r]);
        __syncthreads();
        #pragma unroll
        for (int q = 0; q < 4; ++q) {
            int idx = t + q * 256;
            int rr2 = idx >> 3, slot = idx & 7;
            bf16x8 v = *(const bf16x8*)(T + rr2 * 64 + slot * 8);
            int grow = rbase + rr2;
            *(bf16x8*)(Xb + ((size_t)(b * NN) + (grow >> 5)) * XDIM +
                       (grow & 31) * 64 + slot * 8) = v;
        }
        return;
    }

    // ---------------- pair MLP MFMA path ----------------
    const int bid2 = bid - NB_GRV;
    const int b = bid2 / 127;
    const int pbase = (bid2 % 127) * 64;
    unsigned short* X = sm;                 // [64][128] bf16 swizzled
    unsigned short* Hs = sm + 8192;         // [64][128] bf16 swizzled

    if (t < 64) {
        int p = pbase + t;
        int i = 0;
        while (i < 126) {
            int nx = i + 1;
            int off = nx * 127 - (nx * (nx - 1)) / 2;
            if (off <= p) i = nx; else break;
        }
        int off = i * 127 - (i * (i - 1)) / 2;
        iis[t] = i;
        jjs[t] = i + 1 + (p - off);
    }
    __syncthreads();
    {
        int pp = t & 63, seg = t >> 6;
        const float* ar = afv + (size_t)(b * NN + iis[pp]) * AA + seg * 16;
        const float* br = afv + (size_t)(b * NN + jjs[pp]) * AA + seg * 16;
        float4 xa = *(const float4*)(ar),     xb2 = *(const float4*)(ar + 4);
        float4 xc = *(const float4*)(ar + 8), xd = *(const float4*)(ar + 12);
        float4 ya = *(const float4*)(br),     yb = *(const float4*)(br + 4);
        float4 yc = *(const float4*)(br + 8), yd = *(const float4*)(br + 12);
        float4 s0 = make_float4(xa.x + ya.x, xa.y + ya.y, xa.z + ya.z, xa.w + ya.w);
        float4 s1 = make_float4(xb2.x + yb.x, xb2.y + yb.y, xb2.z + yb.z, xb2.w + yb.w);
        float4 s2 = make_float4(xc.x + yc.x, xc.y + yc.y, xc.z + yc.z, xc.w + yc.w);
        float4 s3 = make_float4(xd.x + yd.x, xd.y + yd.y, xd.z + yd.z, xd.w + yd.w);
        float4 p0 = make_float4(xa.x * ya.x, xa.y * ya.y, xa.z * ya.z, xa.w * ya.w);
        float4 p1 = make_float4(xb2.x * yb.x, xb2.y * yb.y, xb2.z * yb.z, xb2.w * yb.w);
        float4 p2 = make_float4(xc.x * yc.x, xc.y * yc.y, xc.z * yc.z, xc.w * yc.w);
        float4 p3 = make_float4(xd.x * yd.x, xd.y * yd.y, xd.z * yd.z, xd.w * yd.w);
        int gs = seg * 2, gp = 8 + seg * 2, sw = pp & 7;
        *(bf16x8*)(X + pp * 128 + (((gs + 0) ^ sw) * 8)) = pack_bf16x8(s0, s1);
        *(bf16x8*)(X + pp * 128 + (((gs + 1) ^ sw) * 8)) = pack_bf16x8(s2, s3);
        *(bf16x8*)(X + pp * 128 + (((gp + 0) ^ sw) * 8)) = pack_bf16x8(p0, p1);
        *(bf16x8*)(X + pp * 128 + (((gp + 1) ^ sw) * 8)) = pack_bf16x8(p2, p3);
    }
    __syncthreads();
    const int wn = w * 32;
    f32x4 acc1[4][2];
    #pragma unroll
    for (int i = 0; i < 4; ++i)
        #pragma unroll
        for (int j = 0; j < 2; ++j) acc1[i][j] = 0.f;
    #pragma unroll
    for (int ks = 0; ks < 4; ++ks) {
        int g = ks * 4 + lg;
        bf16x8 a[4];
        #pragma unroll
        for (int mi = 0; mi < 4; ++mi) {
            int row = mi * 16 + lm;
            a[mi] = *(const bf16x8*)(X + row * 128 + ((g ^ (row & 7)) * 8));
        }
        #pragma unroll
        for (int ni = 0; ni < 2; ++ni) {
            bf16x8 bv = *(const bf16x8*)(cw1T + (size_t)(wn + ni * 16 + lm) * 128 +
                                         ks * 32 + lg * 8);
            #pragma unroll
            for (int mi = 0; mi < 4; ++mi)
                acc1[mi][ni] = __builtin_amdgcn_mfma_f32_16x16x32_bf16(
                    a[mi], bv, acc1[mi][ni], 0, 0, 0);
        }
    }
    #pragma unroll
    for (int ni = 0; ni < 2; ++ni) {
        int n = wn + ni * 16 + lm;
        float bb = cb1[n];
        int gn = n >> 3, ne = n & 7;
        #pragma unroll
        for (int mi = 0; mi < 4; ++mi)
            #pragma unroll
            for (int r = 0; r < 4; ++r) {
                int row = mi * 16 + lg * 4 + r;
                Hs[row * 128 + ((gn ^ (row & 7)) * 8 + ne)] =
                    f2bf(gelu_f(acc1[mi][ni][r] + bb));
            }
    }
    __syncthreads();
    f32x4 acc2[2];
    acc2[0] = 0.f; acc2[1] = 0.f;
    #pragma unroll
    for (int ks = 0; ks < 4; ++ks) {
        int row = w * 16 + lm;
        int g = ks * 4 + lg;
        bf16x8 a2 = *(const bf16x8*)(Hs + row * 128 + ((g ^ (row & 7)) * 8));
        #pragma unroll
        for (int ni = 0; ni < 2; ++ni) {
            bf16x8 bv = *(const bf16x8*)(cw2T + (size_t)(ni * 16 + lm) * 128 +
                                         ks * 32 + lg * 8);
            acc2[ni] = __builtin_amdgcn_mfma_f32_16x16x32_bf16(a2, bv, acc2[ni], 0, 0, 0);
        }
    }
    {
        unsigned short* T = sm;
        #pragma unroll
        for (int ni = 0; ni < 2; ++ni) {
            int d = ni * 16 + lm;
            float bb = cb2[d];
            #pragma unroll
            for (int r = 0; r < 4; ++r) {
                int p = w * 16 + lg * 4 + r;
                T[d * 64 + p] = f2bf(acc2[ni][r] + bb);
            }
        }
        __syncthreads();
        int d = t >> 3, slot = t & 7;
        bf16x8 v = *(const bf16x8*)(T + d * 64 + slot * 8);
        *(bf16x8*)(pairT + ((size_t)b * DP + d) * PP + pbase + slot * 8) = v;
    }
}

// ---------------------------------------------------------------------------
// Kernel B: gav via bf16 MFMA, full K (127 iters of 64), DIRECT bf16 -> Xb.
// grid 512 = b(8) x rowtile(64: 32 rows), block 256 (4 waves, each one 16x16)
// ---------------------------------------------------------------------------
__global__ __launch_bounds__(256) void gav_k(
    const float* __restrict__ ga, const unsigned short* __restrict__ pairT,
    unsigned short* __restrict__ Xb)
{
    __shared__ unsigned short As[32 * 64];   // [row][k] bf16, swizzled
    __shared__ unsigned short Bs[32 * 64];   // [d][k] bf16, swizzled
    const int bid = blockIdx.x;
    const int rt = bid & 63, b = bid >> 6;
    const int rbase = rt * 32;
    const int t = threadIdx.x;
    const int srow = t >> 3, slot = t & 7;
    const int w = t >> 6, lane = t & 63;
    const int lm = lane & 15, lg = lane >> 4;
    const int wr = (w & 1) * 16, wc = (w >> 1) * 16;

    f32x4 acc = 0.f;

    const float* gab = ga + (size_t)(b * 2048 + rbase) * PP;
    const unsigned short* pbT = pairT + (size_t)b * DP * PP;

    float4 ra0, ra1;
    bf16x8 rb;
    ra0 = *(const float4*)(gab + (size_t)srow * PP + slot * 8);
    ra1 = *(const float4*)(gab + (size_t)srow * PP + slot * 8 + 4);
    rb  = *(const bf16x8*)(pbT + (size_t)srow * PP + slot * 8);

    for (int it = 0; it < 127; ++it) {
        __syncthreads();
        int g = (slot ^ (srow & 7)) * 8;
        *(bf16x8*)(As + srow * 64 + g) = pack_bf16x8(ra0, ra1);
        *(bf16x8*)(Bs + srow * 64 + g) = rb;
        __syncthreads();
        if (it + 1 < 127) {
            int kn = (it + 1) * 64;
            ra0 = *(const float4*)(gab + (size_t)srow * PP + kn + slot * 8);
            ra1 = *(const float4*)(gab + (size_t)srow * PP + kn + slot * 8 + 4);
            rb  = *(const bf16x8*)(pbT + (size_t)srow * PP + kn + slot * 8);
        }
        #pragma unroll
        for (int ks = 0; ks < 2; ++ks) {
            int gg = ks * 4 + lg;
            int rowa = wr + lm;
            int rowb = wc + lm;
            bf16x8 a  = *(const bf16x8*)(As + rowa * 64 + ((gg ^ (rowa & 7)) * 8));
            bf16x8 bv = *(const bf16x8*)(Bs + rowb * 64 + ((gg ^ (rowb & 7)) * 8));
            acc = __builtin_amdgcn_mfma_f32_16x16x32_bf16(a, bv, acc, 0, 0, 0);
        }
    }
    // C layout: col = lane&15, row = (lane>>4)*4 + reg.  row r = n*16+a.
    #pragma unroll
    for (int r = 0; r < 4; ++r) {
        int grow = rbase + wr + lg * 4 + r;
        int n = grow >> 4, a2 = grow & 15;
        int d = wc + lm;
        Xb[(size_t)(b * NN + n) * XDIM + 2048 + a2 * DP + d] = f2bf(acc[r]);
    }
}

// ---------------------------------------------------------------------------
// Kernel C: mlp layer1, full K=2560 (40 iters), fused bias+gelu -> Hb bf16.
// grid 128 = rt(16: 64 rows) x ct(8: 64 cols), block 256
// ---------------------------------------------------------------------------
__global__ __launch_bounds__(256) void mlp1_k(
    const unsigned short* __restrict__ Xb,
    const unsigned short* __restrict__ Wt,
    const float* __restrict__ eb1, unsigned short* __restrict__ Hb)
{
    __shared__ unsigned short As[64 * 64];
    __shared__ unsigned short Bs[64 * 64];
    const int bid = blockIdx.x;
    const int ct = bid & 7, rt = bid >> 3;
    const int rbase = rt * 64, nbase = ct * 64;
    const int t = threadIdx.x;
    const int w = t >> 6, lane = t & 63;
    const int lm = lane & 15, lg = lane >> 4;
    const int srow = t >> 2, sg = (t & 3) * 2;   // 2 granules per thread

    f32x4 acc[4];
    #pragma unroll
    for (int i = 0; i < 4; ++i) acc[i] = 0.f;

    const unsigned short* Arow = Xb + (size_t)(rbase + srow) * XDIM;
    const unsigned short* Brow = Wt + (size_t)(nbase + srow) * XDIM;

    bf16x8 rA0, rA1, rB0, rB1;
    rA0 = *(const bf16x8*)(Arow + sg * 8);
    rA1 = *(const bf16x8*)(Arow + sg * 8 + 8);
    rB0 = *(const bf16x8*)(Brow + sg * 8);
    rB1 = *(const bf16x8*)(Brow + sg * 8 + 8);

    for (int it = 0; it < 40; ++it) {
        __syncthreads();
        int sw = srow & 7;
        *(bf16x8*)(As + srow * 64 + (((sg + 0) ^ sw) * 8)) = rA0;
        *(bf16x8*)(As + srow * 64 + (((sg + 1) ^ sw) * 8)) = rA1;
        *(bf16x8*)(Bs + srow * 64 + (((sg + 0) ^ sw) * 8)) = rB0;
        *(bf16x8*)(Bs + srow * 64 + (((sg + 1) ^ sw) * 8)) = rB1;
        __syncthreads();
        if (it + 1 < 40) {
            int kn = (it + 1) * 64;
            rA0 = *(const bf16x8*)(Arow + kn + sg * 8);
            rA1 = *(const bf16x8*)(Arow + kn + sg * 8 + 8);
            rB0 = *(const bf16x8*)(Brow + kn + sg * 8);
            rB1 = *(const bf16x8*)(Brow + kn + sg * 8 + 8);
        }
        #pragma unroll
        for (int ks = 0; ks < 2; ++ks) {
            int rowa = w * 16 + lm;
            int g = ks * 4 + lg;
            bf16x8 a = *(const bf16x8*)(As + rowa * 64 + ((g ^ (rowa & 7)) * 8));
            #pragma unroll
            for (int ni = 0; ni < 4; ++ni) {
                int rowb = ni * 16 + lm;
                bf16x8 bv = *(const bf16x8*)(Bs + rowb * 64 + ((g ^ (rowb & 7)) * 8));
                acc[ni] = __builtin_amdgcn_mfma_f32_16x16x32_bf16(a, bv, acc[ni], 0, 0, 0);
            }
        }
    }
    #pragma unroll
    for (int ni = 0; ni < 4; ++ni) {
        int col = nbase + ni * 16 + lm;
        float bb = eb1[col];
        #pragma unroll
        for (int r = 0; r < 4; ++r) {
            int row = rbase + w * 16 + lg * 4 + r;
            Hb[(size_t)row * HH + col] = f2bf(gelu_f(acc[ni][r] + bb));
        }
    }
}

// ---------------------------------------------------------------------------
// Kernel D: mlp layer2.  Hb(1024x512) @ ew2bT(256x512) + eb2 -> out f32.
// grid 64 = rt(16: 64 rows) x ct(4: 64 cols), block 256, K=512 (8 iters)
// ---------------------------------------------------------------------------
__global__ __launch_bounds__(256) void mlp2_k(
    const unsigned short* __restrict__ Hb,
    const unsigned short* __restrict__ Wt,
    const float* __restrict__ eb2, float* __restrict__ out)
{
    __shared__ unsigned short As[64 * 64];
    __shared__ unsigned short Bs[64 * 64];
    const int bid = blockIdx.x;
    const int ct = bid & 3, rt = bid >> 2;
    const int rbase = rt * 64, nbase = ct * 64;
    const int t = threadIdx.x;
    const int w = t >> 6, lane = t & 63;
    const int lm = lane & 15, lg = lane >> 4;
    const int srow = t >> 2, sg = (t & 3) * 2;

    f32x4 acc[4];
    #pragma unroll
    for (int i = 0; i < 4; ++i) acc[i] = 0.f;

    const unsigned short* Arow = Hb + (size_t)(rbase + srow) * HH;
    const unsigned short* Brow = Wt + (size_t)(nbase + srow) * HH;

    bf16x8 rA0, rA1, rB0, rB1;
    rA0 = *(const bf16x8*)(Arow + sg * 8);
    rA1 = *(const bf16x8*)(Arow + sg * 8 + 8);
    rB0 = *(const bf16x8*)(Brow + sg * 8);
    rB1 = *(const bf16x8*)(Brow + sg * 8 + 8);

    for (int it = 0; it < 8; ++it) {
        __syncthreads();
        int sw = srow & 7;
        *(bf16x8*)(As + srow * 64 + (((sg + 0) ^ sw) * 8)) = rA0;
        *(bf16x8*)(As + srow * 64 + (((sg + 1) ^ sw) * 8)) = rA1;
        *(bf16x8*)(Bs + srow * 64 + (((sg + 0) ^ sw) * 8)) = rB0;
        *(bf16x8*)(Bs + srow * 64 + (((sg + 1) ^ sw) * 8)) = rB1;
        __syncthreads();
        if (it + 1 < 8) {
            int kn = (it + 1) * 64;
            rA0 = *(const bf16x8*)(Arow + kn + sg * 8);
            rA1 = *(const bf16x8*)(Arow + kn + sg * 8 + 8);
            rB0 = *(const bf16x8*)(Brow + kn + sg * 8);
            rB1 = *(const bf16x8*)(Brow + kn + sg * 8 + 8);
        }
        #pragma unroll
        for (int ks = 0; ks < 2; ++ks) {
            int rowa = w * 16 + lm;
            int g = ks * 4 + lg;
            bf16x8 a = *(const bf16x8*)(As + rowa * 64 + ((g ^ (rowa & 7)) * 8));
            #pragma unroll
            for (int ni = 0; ni < 4; ++ni) {
                int rowb = ni * 16 + lm;
                bf16x8 bv = *(const bf16x8*)(Bs + rowb * 64 + ((g ^ (rowb & 7)) * 8));
                acc[ni] = __builtin_amdgcn_mfma_f32_16x16x32_bf16(a, bv, acc[ni], 0, 0, 0);
            }
        }
    }
    #pragma unroll
    for (int ni = 0; ni < 4; ++ni) {
        int col = nbase + ni * 16 + lm;
        float bb = eb2[col];
        #pragma unroll
        for (int r = 0; r < 4; ++r) {
            int row = rbase + w * 16 + lg * 4 + r;
            out[(size_t)row * EE + col] = acc[ni][r] + bb;
        }
    }
}

extern "C" void kernel_launch(void* const* d_in, const int* in_sizes, int n_in,
                              void* d_out, int out_size, void* d_ws, size_t ws_size,
                              hipStream_t stream) {
    const float* gr  = (const float*)d_in[0];
    const float* ga  = (const float*)d_in[1];
    const float* afv = (const float*)d_in[2];
    const float* cw1 = (const float*)d_in[3];
    const float* cb1 = (const float*)d_in[4];
    const float* cw2 = (const float*)d_in[5];
    const float* cb2 = (const float*)d_in[6];
    const float* ew1 = (const float*)d_in[7];
    const float* eb1 = (const float*)d_in[8];
    const float* ew2 = (const float*)d_in[9];
    const float* eb2 = (const float*)d_in[10];
    float* out = (float*)d_out;
    float* ws = (float*)d_ws;

    unsigned short* pairT  = (unsigned short*)(ws + WS_PAIRT);
    unsigned short* Xb     = (unsigned short*)(ws + WS_XB);
    unsigned short* ew1bT  = (unsigned short*)(ws + WS_EW1B);
    unsigned short* afvT   = (unsigned short*)(ws + WS_AFVT);
    unsigned short* cw1T   = (unsigned short*)(ws + WS_CW1T);
    unsigned short* cw2T   = (unsigned short*)(ws + WS_CW2T);
    unsigned short* ew2bT  = (unsigned short*)(ws + WS_EW2B);
    unsigned short* Hb     = (unsigned short*)(ws + WS_HB);

    prep_k<<<dim3(84), dim3(256), 0, stream>>>(afv, cw1, cw2, afvT, cw1T, cw2T,
                                               out + (size_t)BB * NN * EE);
    stage1_k<<<dim3(2680), dim3(256), 0, stream>>>(afv, cw1T, cb1, cw2T, cb2, pairT,
                                                   gr, Xb, afvT, ew1, ew1bT,
                                                   ew2, ew2bT);
    gav_k<<<dim3(512), dim3(256), 0, stream>>>(ga, pairT, Xb);
    mlp1_k<<<dim3(128), dim3(256), 0, stream>>>(Xb, ew1bT, eb1, Hb);
    mlp2_k<<<dim3(64), dim3(256), 0, stream>>>(Hb, ew2bT, eb2, out);
}

// Round 8
// 187.737 us; speedup vs baseline: 2.4553x; 1.0721x over previous
//
#include <hip/hip_runtime.h>
#include <math.h>

// Problem constants (fixed by setup_inputs)
#define BB 8
#define NN 128
#define AA 64
#define RR 32
#define RA 16
#define PP 8128            // N*(N-1)/2 = 127*64
#define DP 32
#define HH 512
#define EE 256
#define XDIM 2560          // RR*AA + RA*DP = 2048 + 512

// workspace layout (float offsets)
static constexpr size_t WS_PAIRT = 0;                                // pair^T bf16 [b][32][8128]
static constexpr size_t WS_XB    = WS_PAIRT + (size_t)BB*DP*PP/2;    // X bf16 1024x2560
static constexpr size_t WS_EW1B  = WS_XB + (size_t)BB*NN*XDIM/2;     // ew1^T bf16 [512][2560]
static constexpr size_t WS_AFVT  = WS_EW1B + (size_t)HH*XDIM/2;      // afv^T bf16 [b][64][128]
static constexpr size_t WS_CW1T  = WS_AFVT + (size_t)BB*AA*NN/2;     // cw1^T bf16 [128][128]
static constexpr size_t WS_CW2T  = WS_CW1T + (size_t)128*128/2;      // cw2^T bf16 [32][128]
static constexpr size_t WS_EW2B  = WS_CW2T + (size_t)DP*128/2;       // ew2^T bf16 [256][512]
static constexpr size_t WS_HB    = WS_EW2B + (size_t)EE*HH/2;        // H bf16 [1024][512]

typedef __attribute__((ext_vector_type(8))) short bf16x8;
typedef __attribute__((ext_vector_type(4))) float f32x4;

__device__ __forceinline__ float gelu_f(float x) {
    float u = 0.7978845608028654f * (x + 0.044715f * x * x * x);
    float au = fabsf(u);
    float e = __expf(-2.0f * au);
    float th = (1.0f - e) / (1.0f + e);
    th = copysignf(th, u);
    return 0.5f * x * (1.0f + th);
}

__device__ __forceinline__ unsigned short f2bf(float x) {
    union { float f; unsigned u; } v; v.f = x;
    unsigned r = v.u + 0x7fffu + ((v.u >> 16) & 1u);   // RTNE
    return (unsigned short)(r >> 16);
}

__device__ __forceinline__ bf16x8 pack_bf16x8(float4 a, float4 b) {
    bf16x8 r;
    r[0] = (short)f2bf(a.x); r[1] = (short)f2bf(a.y);
    r[2] = (short)f2bf(a.z); r[3] = (short)f2bf(a.w);
    r[4] = (short)f2bf(b.x); r[5] = (short)f2bf(b.y);
    r[6] = (short)f2bf(b.z); r[7] = (short)f2bf(b.w);
    return r;
}

// ---------------------------------------------------------------------------
// Kernel 0: prep — bf16 transposes of small operands + afv copy to out2.
// grid 84: [0,64) afvT + copy, [64,80) cw1T, [80,84) cw2T
// ---------------------------------------------------------------------------
__global__ __launch_bounds__(256) void prep_k(
    const float* __restrict__ afv, const float* __restrict__ cw1,
    const float* __restrict__ cw2, unsigned short* __restrict__ afvT,
    unsigned short* __restrict__ cw1T, unsigned short* __restrict__ cw2T,
    float* __restrict__ out2)
{
    const int bid = blockIdx.x, t = threadIdx.x;
    if (bid < 64) {
        int idx = bid * 256 + t;              // 16384
        int b = idx >> 11;
        int rem = idx & 2047;
        int a = rem >> 5;
        int m0 = (rem & 31) * 4;
        ushort4 o;
        o.x = f2bf(afv[((size_t)b * NN + m0 + 0) * AA + a]);
        o.y = f2bf(afv[((size_t)b * NN + m0 + 1) * AA + a]);
        o.z = f2bf(afv[((size_t)b * NN + m0 + 2) * AA + a]);
        o.w = f2bf(afv[((size_t)b * NN + m0 + 3) * AA + a]);
        *(ushort4*)(afvT + ((size_t)b * AA + a) * NN + m0) = o;
        float4 v = *(const float4*)(afv + (size_t)idx * 4);
        *(float4*)(out2 + (size_t)idx * 4) = v;
    } else if (bid < 80) {
        int idx = (bid - 64) * 256 + t;       // 4096
        int n = idx >> 5;
        int k0 = (idx & 31) * 4;
        ushort4 o;
        o.x = f2bf(cw1[(size_t)(k0 + 0) * 128 + n]);
        o.y = f2bf(cw1[(size_t)(k0 + 1) * 128 + n]);
        o.z = f2bf(cw1[(size_t)(k0 + 2) * 128 + n]);
        o.w = f2bf(cw1[(size_t)(k0 + 3) * 128 + n]);
        *(ushort4*)(cw1T + (size_t)n * 128 + k0) = o;
    } else {
        int idx = (bid - 80) * 256 + t;       // 1024
        int d = idx >> 5;
        int k0 = (idx & 31) * 4;
        ushort4 o;
        o.x = f2bf(cw2[(size_t)(k0 + 0) * DP + d]);
        o.y = f2bf(cw2[(size_t)(k0 + 1) * DP + d]);
        o.z = f2bf(cw2[(size_t)(k0 + 2) * DP + d]);
        o.w = f2bf(cw2[(size_t)(k0 + 3) * DP + d]);
        *(ushort4*)(cw2T + (size_t)d * 128 + k0) = o;
    }
}

// ---------------------------------------------------------------------------
// Kernel A: fused stage-1 (all MFMA).
//   blocks [0,256): grv GEMM per b -> Xb[...,0:2048]
//   blocks [256,1272): pair MLP -> pairT bf16 [b][d][p]
// ---------------------------------------------------------------------------
#define NB_GRV 256
#define NB_PAIR 1016

__global__ __launch_bounds__(256) void stage1_k(
    const float* __restrict__ afv, const unsigned short* __restrict__ cw1T,
    const float* __restrict__ cb1, const unsigned short* __restrict__ cw2T,
    const float* __restrict__ cb2, unsigned short* __restrict__ pairT,
    const float* __restrict__ gr, unsigned short* __restrict__ Xb,
    const unsigned short* __restrict__ afvT)
{
    __shared__ unsigned short sm[16384];   // 32KB, multi-purpose
    __shared__ int iis[64], jjs[64];
    const int bid = blockIdx.x;
    const int t = threadIdx.x;
    const int w = t >> 6, lane = t & 63;
    const int lm = lane & 15, lg = lane >> 4;

    if (bid < NB_GRV) {
        // ---------------- grv MFMA path ----------------
        const int b = bid >> 5;
        const int rbase = (bid & 31) * 128;
        const float* gab = gr + ((size_t)b * 4096 + rbase) * NN;
        unsigned short* As = sm;            // [128][128] bf16 swizzled
        const int srow = t >> 1, half = t & 1;
        const float* arow = gab + (size_t)srow * NN + half * 64;
        #pragma unroll
        for (int q = 0; q < 8; ++q) {
            float4 x0 = *(const float4*)(arow + q * 8);
            float4 x1 = *(const float4*)(arow + q * 8 + 4);
            bf16x8 v = pack_bf16x8(x0, x1);
            int g = half * 8 + q;
            *(bf16x8*)(As + srow * 128 + ((g ^ (srow & 7)) * 8)) = v;
        }
        __syncthreads();
        const int wm = w * 32;
        f32x4 acc[2][4];
        #pragma unroll
        for (int i = 0; i < 2; ++i)
            #pragma unroll
            for (int j = 0; j < 4; ++j) acc[i][j] = 0.f;
        const unsigned short* Bb = afvT + (size_t)b * AA * NN;   // [64][128]
        #pragma unroll
        for (int ks = 0; ks < 4; ++ks) {
            int g = ks * 4 + lg;
            int r0 = wm + lm, r1 = wm + 16 + lm;
            bf16x8 a0 = *(const bf16x8*)(As + r0 * 128 + ((g ^ (r0 & 7)) * 8));
            bf16x8 a1 = *(const bf16x8*)(As + r1 * 128 + ((g ^ (r1 & 7)) * 8));
            #pragma unroll
            for (int ni = 0; ni < 4; ++ni) {
                bf16x8 bv = *(const bf16x8*)(Bb + (size_t)(ni * 16 + lm) * NN + ks * 32 + lg * 8);
                acc[0][ni] = __builtin_amdgcn_mfma_f32_16x16x32_bf16(a0, bv, acc[0][ni], 0, 0, 0);
                acc[1][ni] = __builtin_amdgcn_mfma_f32_16x16x32_bf16(a1, bv, acc[1][ni], 0, 0, 0);
            }
        }
        __syncthreads();
        unsigned short* T = sm;             // [128][64] bf16
        #pragma unroll
        for (int mi = 0; mi < 2; ++mi)
            #pragma unroll
            for (int ni = 0; ni < 4; ++ni)
                #pragma unroll
                for (int r = 0; r < 4; ++r)
                    T[(wm + mi * 16 + lg * 4 + r) * 64 + ni * 16 + lm] =
                        f2bf(acc[mi][ni][r]);
        __syncthreads();
        #pragma unroll
        for (int q = 0; q < 4; ++q) {
            int idx = t + q * 256;
            int rr2 = idx >> 3, slot = idx & 7;
            bf16x8 v = *(const bf16x8*)(T + rr2 * 64 + slot * 8);
            int grow = rbase + rr2;
            *(bf16x8*)(Xb + ((size_t)(b * NN) + (grow >> 5)) * XDIM +
                       (grow & 31) * 64 + slot * 8) = v;
        }
        return;
    }

    // ---------------- pair MLP MFMA path ----------------
    const int bid2 = bid - NB_GRV;
    const int b = bid2 / 127;
    const int pbase = (bid2 % 127) * 64;
    unsigned short* X = sm;                 // [64][128] bf16 swizzled
    unsigned short* Hs = sm + 8192;         // [64][128] bf16 swizzled

    if (t < 64) {
        int p = pbase + t;
        int i = 0;
        while (i < 126) {
            int nx = i + 1;
            int off = nx * 127 - (nx * (nx - 1)) / 2;
            if (off <= p) i = nx; else break;
        }
        int off = i * 127 - (i * (i - 1)) / 2;
        iis[t] = i;
        jjs[t] = i + 1 + (p - off);
    }
    __syncthreads();
    {
        int pp = t & 63, seg = t >> 6;
        const float* ar = afv + (size_t)(b * NN + iis[pp]) * AA + seg * 16;
        const float* br = afv + (size_t)(b * NN + jjs[pp]) * AA + seg * 16;
        float4 xa = *(const float4*)(ar),     xb2 = *(const float4*)(ar + 4);
        float4 xc = *(const float4*)(ar + 8), xd = *(const float4*)(ar + 12);
        float4 ya = *(const float4*)(br),     yb = *(const float4*)(br + 4);
        float4 yc = *(const float4*)(br + 8), yd = *(const float4*)(br + 12);
        float4 s0 = make_float4(xa.x + ya.x, xa.y + ya.y, xa.z + ya.z, xa.w + ya.w);
        float4 s1 = make_float4(xb2.x + yb.x, xb2.y + yb.y, xb2.z + yb.z, xb2.w + yb.w);
        float4 s2 = make_float4(xc.x + yc.x, xc.y + yc.y, xc.z + yc.z, xc.w + yc.w);
        float4 s3 = make_float4(xd.x + yd.x, xd.y + yd.y, xd.z + yd.z, xd.w + yd.w);
        float4 p0 = make_float4(xa.x * ya.x, xa.y * ya.y, xa.z * ya.z, xa.w * ya.w);
        float4 p1 = make_float4(xb2.x * yb.x, xb2.y * yb.y, xb2.z * yb.z, xb2.w * yb.w);
        float4 p2 = make_float4(xc.x * yc.x, xc.y * yc.y, xc.z * yc.z, xc.w * yc.w);
        float4 p3 = make_float4(xd.x * yd.x, xd.y * yd.y, xd.z * yd.z, xd.w * yd.w);
        int gs = seg * 2, gp = 8 + seg * 2, sw = pp & 7;
        *(bf16x8*)(X + pp * 128 + (((gs + 0) ^ sw) * 8)) = pack_bf16x8(s0, s1);
        *(bf16x8*)(X + pp * 128 + (((gs + 1) ^ sw) * 8)) = pack_bf16x8(s2, s3);
        *(bf16x8*)(X + pp * 128 + (((gp + 0) ^ sw) * 8)) = pack_bf16x8(p0, p1);
        *(bf16x8*)(X + pp * 128 + (((gp + 1) ^ sw) * 8)) = pack_bf16x8(p2, p3);
    }
    __syncthreads();
    const int wn = w * 32;
    f32x4 acc1[4][2];
    #pragma unroll
    for (int i = 0; i < 4; ++i)
        #pragma unroll
        for (int j = 0; j < 2; ++j) acc1[i][j] = 0.f;
    #pragma unroll
    for (int ks = 0; ks < 4; ++ks) {
        int g = ks * 4 + lg;
        bf16x8 a[4];
        #pragma unroll
        for (int mi = 0; mi < 4; ++mi) {
            int row = mi * 16 + lm;
            a[mi] = *(const bf16x8*)(X + row * 128 + ((g ^ (row & 7)) * 8));
        }
        #pragma unroll
        for (int ni = 0; ni < 2; ++ni) {
            bf16x8 bv = *(const bf16x8*)(cw1T + (size_t)(wn + ni * 16 + lm) * 128 +
                                         ks * 32 + lg * 8);
            #pragma unroll
            for (int mi = 0; mi < 4; ++mi)
                acc1[mi][ni] = __builtin_amdgcn_mfma_f32_16x16x32_bf16(
                    a[mi], bv, acc1[mi][ni], 0, 0, 0);
        }
    }
    #pragma unroll
    for (int ni = 0; ni < 2; ++ni) {
        int n = wn + ni * 16 + lm;
        float bb = cb1[n];
        int gn = n >> 3, ne = n & 7;
        #pragma unroll
        for (int mi = 0; mi < 4; ++mi)
            #pragma unroll
            for (int r = 0; r < 4; ++r) {
                int row = mi * 16 + lg * 4 + r;
                Hs[row * 128 + ((gn ^ (row & 7)) * 8 + ne)] =
                    f2bf(gelu_f(acc1[mi][ni][r] + bb));
            }
    }
    __syncthreads();
    f32x4 acc2[2];
    acc2[0] = 0.f; acc2[1] = 0.f;
    #pragma unroll
    for (int ks = 0; ks < 4; ++ks) {
        int row = w * 16 + lm;
        int g = ks * 4 + lg;
        bf16x8 a2 = *(const bf16x8*)(Hs + row * 128 + ((g ^ (row & 7)) * 8));
        #pragma unroll
        for (int ni = 0; ni < 2; ++ni) {
            bf16x8 bv = *(const bf16x8*)(cw2T + (size_t)(ni * 16 + lm) * 128 +
                                         ks * 32 + lg * 8);
            acc2[ni] = __builtin_amdgcn_mfma_f32_16x16x32_bf16(a2, bv, acc2[ni], 0, 0, 0);
        }
    }
    {
        unsigned short* T = sm;
        #pragma unroll
        for (int ni = 0; ni < 2; ++ni) {
            int d = ni * 16 + lm;
            float bb = cb2[d];
            #pragma unroll
            for (int r = 0; r < 4; ++r) {
                int p = w * 16 + lg * 4 + r;
                T[d * 64 + p] = f2bf(acc2[ni][r] + bb);
            }
        }
        __syncthreads();
        int d = t >> 3, slot = t & 7;
        bf16x8 v = *(const bf16x8*)(T + d * 64 + slot * 8);
        *(bf16x8*)(pairT + ((size_t)b * DP + d) * PP + pbase + slot * 8) = v;
    }
}

// ---------------------------------------------------------------------------
// Kernel B: gav via bf16 MFMA, K-tile 128 (63 full iters + 64-wide tail),
// direct bf16 -> Xb.  Also carries ew1/ew2 bf16-transpose blocks (they only
// feed mlp1, so they overlap with HBM-bound gav instead of gating it).
// grid 1920 = 512 gav (b(8) x rowtile(64: 32 rows)) + 1280 ew1 + 128 ew2
// ---------------------------------------------------------------------------
__global__ __launch_bounds__(256) void gav_k(
    const float* __restrict__ ga, const unsigned short* __restrict__ pairT,
    unsigned short* __restrict__ Xb,
    const float* __restrict__ ew1, unsigned short* __restrict__ ew1bT,
    const float* __restrict__ ew2, unsigned short* __restrict__ ew2bT)
{
    __shared__ unsigned short As[32 * 128];   // [row][k] bf16, swizzled (8KB)
    __shared__ unsigned short Bs[32 * 128];   // [d][k] bf16, swizzled (8KB)
    const int bid = blockIdx.x;
    const int t = threadIdx.x;

    if (bid >= 512 + 1280) {
        // ---------------- ew2 convert+transpose ----------------
        int q = (bid - (512 + 1280)) * 256 + t;   // 0..32767
        int n = q & 255;
        int k0 = (q >> 8) * 4;
        ushort4 o;
        o.x = f2bf(ew2[(size_t)(k0 + 0) * EE + n]);
        o.y = f2bf(ew2[(size_t)(k0 + 1) * EE + n]);
        o.z = f2bf(ew2[(size_t)(k0 + 2) * EE + n]);
        o.w = f2bf(ew2[(size_t)(k0 + 3) * EE + n]);
        *(ushort4*)(ew2bT + (size_t)n * HH + k0) = o;
        return;
    }
    if (bid >= 512) {
        // ---------------- ew1 convert+transpose ----------------
        int q = (bid - 512) * 256 + t;            // 0..327679
        int n = q & 511;
        int k0 = (q >> 9) * 4;
        ushort4 o;
        o.x = f2bf(ew1[(size_t)(k0 + 0) * HH + n]);
        o.y = f2bf(ew1[(size_t)(k0 + 1) * HH + n]);
        o.z = f2bf(ew1[(size_t)(k0 + 2) * HH + n]);
        o.w = f2bf(ew1[(size_t)(k0 + 3) * HH + n]);
        *(ushort4*)(ew1bT + (size_t)n * XDIM + k0) = o;
        return;
    }

    // ---------------- gav ----------------
    const int rt = bid & 63, b = bid >> 6;
    const int rbase = rt * 32;
    const int srow = t >> 3, slot = t & 7;
    const int w = t >> 6, lane = t & 63;
    const int lm = lane & 15, lg = lane >> 4;
    const int wr = (w & 1) * 16, wc = (w >> 1) * 16;

    f32x4 acc = 0.f;

    const float* gab = ga + (size_t)(b * 2048 + rbase) * PP;
    const unsigned short* pbT = pairT + (size_t)b * DP * PP;

    // per iter the thread stages k-segments [slot*8, slot*8+8) and +64
    float4 ra[4];
    bf16x8 rb0, rb1;
    {
        int k0 = slot * 8;
        ra[0] = *(const float4*)(gab + (size_t)srow * PP + k0);
        ra[1] = *(const float4*)(gab + (size_t)srow * PP + k0 + 4);
        ra[2] = *(const float4*)(gab + (size_t)srow * PP + k0 + 64);
        ra[3] = *(const float4*)(gab + (size_t)srow * PP + k0 + 68);
        rb0 = *(const bf16x8*)(pbT + (size_t)srow * PP + k0);
        rb1 = *(const bf16x8*)(pbT + (size_t)srow * PP + k0 + 64);
    }

    for (int it = 0; it < 64; ++it) {
        __syncthreads();
        const int sw = srow & 7;
        const int g0 = (slot ^ sw) * 8;            // granule slot   (k seg slot)
        const int g1 = ((slot ^ sw) + 8) * 8;      // granule slot+8 (k seg slot+8)
        *(bf16x8*)(As + srow * 128 + g0) = pack_bf16x8(ra[0], ra[1]);
        *(bf16x8*)(As + srow * 128 + g1) = pack_bf16x8(ra[2], ra[3]);
        *(bf16x8*)(Bs + srow * 128 + g0) = rb0;
        *(bf16x8*)(Bs + srow * 128 + g1) = rb1;
        __syncthreads();
        if (it + 1 < 64) {
            int kn = (it + 1) * 128 + slot * 8;       // always <= 8120 = PP-8
            int k1 = kn + 64; if (k1 > PP - 8) k1 = PP - 8;   // clamp tail garbage (unread)
            ra[0] = *(const float4*)(gab + (size_t)srow * PP + kn);
            ra[1] = *(const float4*)(gab + (size_t)srow * PP + kn + 4);
            ra[2] = *(const float4*)(gab + (size_t)srow * PP + k1);
            ra[3] = *(const float4*)(gab + (size_t)srow * PP + k1 + 4);
            rb0 = *(const bf16x8*)(pbT + (size_t)srow * PP + kn);
            rb1 = *(const bf16x8*)(pbT + (size_t)srow * PP + k1);
        }
        if (it < 63) {
            #pragma unroll
            for (int ks = 0; ks < 4; ++ks) {
                int gg = ks * 4 + lg;
                int rowa = wr + lm;
                int rowb = wc + lm;
                bf16x8 a  = *(const bf16x8*)(As + rowa * 128 + ((gg ^ (rowa & 7)) * 8));
                bf16x8 bv = *(const bf16x8*)(Bs + rowb * 128 + ((gg ^ (rowb & 7)) * 8));
                acc = __builtin_amdgcn_mfma_f32_16x16x32_bf16(a, bv, acc, 0, 0, 0);
            }
        } else {
            // tail: only k 8064..8127 valid (granules 0..7)
            #pragma unroll
            for (int ks = 0; ks < 2; ++ks) {
                int gg = ks * 4 + lg;
                int rowa = wr + lm;
                int rowb = wc + lm;
                bf16x8 a  = *(const bf16x8*)(As + rowa * 128 + ((gg ^ (rowa & 7)) * 8));
                bf16x8 bv = *(const bf16x8*)(Bs + rowb * 128 + ((gg ^ (rowb & 7)) * 8));
                acc = __builtin_amdgcn_mfma_f32_16x16x32_bf16(a, bv, acc, 0, 0, 0);
            }
        }
    }
    // C layout: col = lane&15, row = (lane>>4)*4 + reg.  row r = n*16+a.
    #pragma unroll
    for (int r = 0; r < 4; ++r) {
        int grow = rbase + wr + lg * 4 + r;
        int n = grow >> 4, a2 = grow & 15;
        int d = wc + lm;
        Xb[(size_t)(b * NN + n) * XDIM + 2048 + a2 * DP + d] = f2bf(acc[r]);
    }
}

// ---------------------------------------------------------------------------
// Kernel C: mlp layer1, full K=2560 (40 iters), fused bias+gelu -> Hb bf16.
// grid 256 = rt(32: 32 rows) x ct(8: 64 cols), block 256 (wave = 32x16 out)
// ---------------------------------------------------------------------------
__global__ __launch_bounds__(256) void mlp1_k(
    const unsigned short* __restrict__ Xb,
    const unsigned short* __restrict__ Wt,
    const float* __restrict__ eb1, unsigned short* __restrict__ Hb)
{
    __shared__ unsigned short As[32 * 64];   // 4KB
    __shared__ unsigned short Bs[64 * 64];   // 8KB
    const int bid = blockIdx.x;
    const int ct = bid & 7, rt = bid >> 3;
    const int rbase = rt * 32, nbase = ct * 64;
    const int t = threadIdx.x;
    const int w = t >> 6, lane = t & 63;
    const int lm = lane & 15, lg = lane >> 4;
    const int srow = t >> 3, sg = t & 7;

    f32x4 acc[2];
    acc[0] = 0.f; acc[1] = 0.f;

    const unsigned short* Arow  = Xb + (size_t)(rbase + srow) * XDIM;
    const unsigned short* Brow0 = Wt + (size_t)(nbase + srow) * XDIM;
    const unsigned short* Brow1 = Wt + (size_t)(nbase + srow + 32) * XDIM;

    bf16x8 rA, rB0, rB1;
    rA  = *(const bf16x8*)(Arow + sg * 8);
    rB0 = *(const bf16x8*)(Brow0 + sg * 8);
    rB1 = *(const bf16x8*)(Brow1 + sg * 8);

    for (int it = 0; it < 40; ++it) {
        __syncthreads();
        const int sw = srow & 7;
        *(bf16x8*)(As + srow * 64 + ((sg ^ sw) * 8)) = rA;
        *(bf16x8*)(Bs + srow * 64 + ((sg ^ sw) * 8)) = rB0;
        *(bf16x8*)(Bs + (srow + 32) * 64 + ((sg ^ sw) * 8)) = rB1;
        __syncthreads();
        if (it + 1 < 40) {
            int kn = (it + 1) * 64;
            rA  = *(const bf16x8*)(Arow + kn + sg * 8);
            rB0 = *(const bf16x8*)(Brow0 + kn + sg * 8);
            rB1 = *(const bf16x8*)(Brow1 + kn + sg * 8);
        }
        #pragma unroll
        for (int ks = 0; ks < 2; ++ks) {
            int g = ks * 4 + lg;
            int r0 = lm, r1 = 16 + lm, rb_ = w * 16 + lm;
            bf16x8 a0 = *(const bf16x8*)(As + r0 * 64 + ((g ^ (r0 & 7)) * 8));
            bf16x8 a1 = *(const bf16x8*)(As + r1 * 64 + ((g ^ (r1 & 7)) * 8));
            bf16x8 bv = *(const bf16x8*)(Bs + rb_ * 64 + ((g ^ (rb_ & 7)) * 8));
            acc[0] = __builtin_amdgcn_mfma_f32_16x16x32_bf16(a0, bv, acc[0], 0, 0, 0);
            acc[1] = __builtin_amdgcn_mfma_f32_16x16x32_bf16(a1, bv, acc[1], 0, 0, 0);
        }
    }
    const int col = nbase + w * 16 + lm;
    const float bb = eb1[col];
    #pragma unroll
    for (int mi = 0; mi < 2; ++mi)
        #pragma unroll
        for (int r = 0; r < 4; ++r) {
            int row = rbase + mi * 16 + lg * 4 + r;
            Hb[(size_t)row * HH + col] = f2bf(gelu_f(acc[mi][r] + bb));
        }
}

// ---------------------------------------------------------------------------
// Kernel D: mlp layer2.  Hb(1024x512) @ ew2bT(256x512) + eb2 -> out f32.
// grid 128 = rt(32: 32 rows) x ct(4: 64 cols), block 256, K=512 (8 iters)
// ---------------------------------------------------------------------------
__global__ __launch_bounds__(256) void mlp2_k(
    const unsigned short* __restrict__ Hb,
    const unsigned short* __restrict__ Wt,
    const float* __restrict__ eb2, float* __restrict__ out)
{
    __shared__ unsigned short As[32 * 64];
    __shared__ unsigned short Bs[64 * 64];
    const int bid = blockIdx.x;
    const int ct = bid & 3, rt = bid >> 2;
    const int rbase = rt * 32, nbase = ct * 64;
    const int t = threadIdx.x;
    const int w = t >> 6, lane = t & 63;
    const int lm = lane & 15, lg = lane >> 4;
    const int srow = t >> 3, sg = t & 7;

    f32x4 acc[2];
    acc[0] = 0.f; acc[1] = 0.f;

    const unsigned short* Arow  = Hb + (size_t)(rbase + srow) * HH;
    const unsigned short* Brow0 = Wt + (size_t)(nbase + srow) * HH;
    const unsigned short* Brow1 = Wt + (size_t)(nbase + srow + 32) * HH;

    bf16x8 rA, rB0, rB1;
    rA  = *(const bf16x8*)(Arow + sg * 8);
    rB0 = *(const bf16x8*)(Brow0 + sg * 8);
    rB1 = *(const bf16x8*)(Brow1 + sg * 8);

    for (int it = 0; it < 8; ++it) {
        __syncthreads();
        const int sw = srow & 7;
        *(bf16x8*)(As + srow * 64 + ((sg ^ sw) * 8)) = rA;
        *(bf16x8*)(Bs + srow * 64 + ((sg ^ sw) * 8)) = rB0;
        *(bf16x8*)(Bs + (srow + 32) * 64 + ((sg ^ sw) * 8)) = rB1;
        __syncthreads();
        if (it + 1 < 8) {
            int kn = (it + 1) * 64;
            rA  = *(const bf16x8*)(Arow + kn + sg * 8);
            rB0 = *(const bf16x8*)(Brow0 + kn + sg * 8);
            rB1 = *(const bf16x8*)(Brow1 + kn + sg * 8);
        }
        #pragma unroll
        for (int ks = 0; ks < 2; ++ks) {
            int g = ks * 4 + lg;
            int r0 = lm, r1 = 16 + lm, rb_ = w * 16 + lm;
            bf16x8 a0 = *(const bf16x8*)(As + r0 * 64 + ((g ^ (r0 & 7)) * 8));
            bf16x8 a1 = *(const bf16x8*)(As + r1 * 64 + ((g ^ (r1 & 7)) * 8));
            bf16x8 bv = *(const bf16x8*)(Bs + rb_ * 64 + ((g ^ (rb_ & 7)) * 8));
            acc[0] = __builtin_amdgcn_mfma_f32_16x16x32_bf16(a0, bv, acc[0], 0, 0, 0);
            acc[1] = __builtin_amdgcn_mfma_f32_16x16x32_bf16(a1, bv, acc[1], 0, 0, 0);
        }
    }
    const int col = nbase + w * 16 + lm;
    const float bb = eb2[col];
    #pragma unroll
    for (int mi = 0; mi < 2; ++mi)
        #pragma unroll
        for (int r = 0; r < 4; ++r) {
            int row = rbase + mi * 16 + lg * 4 + r;
            out[(size_t)row * EE + col] = acc[mi][r] + bb;
        }
}

extern "C" void kernel_launch(void* const* d_in, const int* in_sizes, int n_in,
                              void* d_out, int out_size, void* d_ws, size_t ws_size,
                              hipStream_t stream) {
    const float* gr  = (const float*)d_in[0];
    const float* ga  = (const float*)d_in[1];
    const float* afv = (const float*)d_in[2];
    const float* cw1 = (const float*)d_in[3];
    const float* cb1 = (const float*)d_in[4];
    const float* cw2 = (const float*)d_in[5];
    const float* cb2 = (const float*)d_in[6];
    const float* ew1 = (const float*)d_in[7];
    const float* eb1 = (const float*)d_in[8];
    const float* ew2 = (const float*)d_in[9];
    const float* eb2 = (const float*)d_in[10];
    float* out = (float*)d_out;
    float* ws = (float*)d_ws;

    unsigned short* pairT  = (unsigned short*)(ws + WS_PAIRT);
    unsigned short* Xb     = (unsigned short*)(ws + WS_XB);
    unsigned short* ew1bT  = (unsigned short*)(ws + WS_EW1B);
    unsigned short* afvT   = (unsigned short*)(ws + WS_AFVT);
    unsigned short* cw1T   = (unsigned short*)(ws + WS_CW1T);
    unsigned short* cw2T   = (unsigned short*)(ws + WS_CW2T);
    unsigned short* ew2bT  = (unsigned short*)(ws + WS_EW2B);
    unsigned short* Hb     = (unsigned short*)(ws + WS_HB);

    prep_k<<<dim3(84), dim3(256), 0, stream>>>(afv, cw1, cw2, afvT, cw1T, cw2T,
                                               out + (size_t)BB * NN * EE);
    stage1_k<<<dim3(NB_GRV + NB_PAIR), dim3(256), 0, stream>>>(
        afv, cw1T, cb1, cw2T, cb2, pairT, gr, Xb, afvT);
    gav_k<<<dim3(1920), dim3(256), 0, stream>>>(ga, pairT, Xb, ew1, ew1bT, ew2, ew2bT);
    mlp1_k<<<dim3(256), dim3(256), 0, stream>>>(Xb, ew1bT, eb1, Hb);
    mlp2_k<<<dim3(128), dim3(256), 0, stream>>>(Hb, ew2bT, eb2, out);
}

// Round 9
// 180.710 us; speedup vs baseline: 2.5508x; 1.0389x over previous
//
#include <hip/hip_runtime.h>
#include <math.h>

// Problem constants (fixed by setup_inputs)
#define BB 8
#define NN 128
#define AA 64
#define RR 32
#define RA 16
#define PP 8128            // N*(N-1)/2 = 127*64
#define DP 32
#define HH 512
#define EE 256
#define XDIM 2560          // RR*AA + RA*DP = 2048 + 512

// workspace layout (float offsets)
static constexpr size_t WS_PAIRT = 0;                                // pair^T bf16 [b][32][8128]
static constexpr size_t WS_XB    = WS_PAIRT + (size_t)BB*DP*PP/2;    // X bf16 1024x2560
static constexpr size_t WS_EW1B  = WS_XB + (size_t)BB*NN*XDIM/2;     // ew1^T bf16 [512][2560]
static constexpr size_t WS_CW1T  = WS_EW1B + (size_t)HH*XDIM/2;      // cw1^T bf16 [128][128]
static constexpr size_t WS_CW2T  = WS_CW1T + (size_t)128*128/2;      // cw2^T bf16 [32][128]
static constexpr size_t WS_EW2B  = WS_CW2T + (size_t)DP*128/2;       // ew2^T bf16 [256][512]
static constexpr size_t WS_HB    = WS_EW2B + (size_t)EE*HH/2;        // H bf16 [1024][512]

typedef __attribute__((ext_vector_type(8))) short bf16x8;
typedef __attribute__((ext_vector_type(4))) float f32x4;

__device__ __forceinline__ float gelu_f(float x) {
    float u = 0.7978845608028654f * (x + 0.044715f * x * x * x);
    float au = fabsf(u);
    float e = __expf(-2.0f * au);
    float th = (1.0f - e) / (1.0f + e);
    th = copysignf(th, u);
    return 0.5f * x * (1.0f + th);
}

__device__ __forceinline__ unsigned short f2bf(float x) {
    union { float f; unsigned u; } v; v.f = x;
    unsigned r = v.u + 0x7fffu + ((v.u >> 16) & 1u);   // RTNE
    return (unsigned short)(r >> 16);
}

__device__ __forceinline__ bf16x8 pack_bf16x8(float4 a, float4 b) {
    bf16x8 r;
    r[0] = (short)f2bf(a.x); r[1] = (short)f2bf(a.y);
    r[2] = (short)f2bf(a.z); r[3] = (short)f2bf(a.w);
    r[4] = (short)f2bf(b.x); r[5] = (short)f2bf(b.y);
    r[6] = (short)f2bf(b.z); r[7] = (short)f2bf(b.w);
    return r;
}

// ---------------------------------------------------------------------------
// Kernel 0: prep — cw1/cw2 bf16 transposes (needed by stage1 pair path).
// grid 20: [0,16) cw1T, [16,20) cw2T
// ---------------------------------------------------------------------------
__global__ __launch_bounds__(256) void prep_k(
    const float* __restrict__ cw1, const float* __restrict__ cw2,
    unsigned short* __restrict__ cw1T, unsigned short* __restrict__ cw2T)
{
    const int bid = blockIdx.x, t = threadIdx.x;
    if (bid < 16) {
        int idx = bid * 256 + t;              // 4096
        int n = idx >> 5;
        int k0 = (idx & 31) * 4;
        ushort4 o;
        o.x = f2bf(cw1[(size_t)(k0 + 0) * 128 + n]);
        o.y = f2bf(cw1[(size_t)(k0 + 1) * 128 + n]);
        o.z = f2bf(cw1[(size_t)(k0 + 2) * 128 + n]);
        o.w = f2bf(cw1[(size_t)(k0 + 3) * 128 + n]);
        *(ushort4*)(cw1T + (size_t)n * 128 + k0) = o;
    } else {
        int idx = (bid - 16) * 256 + t;       // 1024
        int d = idx >> 5;
        int k0 = (idx & 31) * 4;
        ushort4 o;
        o.x = f2bf(cw2[(size_t)(k0 + 0) * DP + d]);
        o.y = f2bf(cw2[(size_t)(k0 + 1) * DP + d]);
        o.z = f2bf(cw2[(size_t)(k0 + 2) * DP + d]);
        o.w = f2bf(cw2[(size_t)(k0 + 3) * DP + d]);
        *(ushort4*)(cw2T + (size_t)d * 128 + k0) = o;
    }
}

// ---------------------------------------------------------------------------
// Kernel A: pair MLP (MFMA both layers) -> pairT bf16 [b][d][p]
// grid 1016 (8 b x 127 pair-tiles of 64), block 256, LDS 32KB
// ---------------------------------------------------------------------------
__global__ __launch_bounds__(256) void stage1_k(
    const float* __restrict__ afv, const unsigned short* __restrict__ cw1T,
    const float* __restrict__ cb1, const unsigned short* __restrict__ cw2T,
    const float* __restrict__ cb2, unsigned short* __restrict__ pairT)
{
    __shared__ unsigned short sm[16384];   // 32KB
    __shared__ int iis[64], jjs[64];
    const int bid = blockIdx.x;
    const int t = threadIdx.x;
    const int w = t >> 6, lane = t & 63;
    const int lm = lane & 15, lg = lane >> 4;

    const int b = bid / 127;
    const int pbase = (bid % 127) * 64;
    unsigned short* X = sm;                 // [64][128] bf16 swizzled
    unsigned short* Hs = sm + 8192;         // [64][128] bf16 swizzled

    if (t < 64) {
        int p = pbase + t;
        int i = 0;
        while (i < 126) {
            int nx = i + 1;
            int off = nx * 127 - (nx * (nx - 1)) / 2;
            if (off <= p) i = nx; else break;
        }
        int off = i * 127 - (i * (i - 1)) / 2;
        iis[t] = i;
        jjs[t] = i + 1 + (p - off);
    }
    __syncthreads();
    {
        int pp = t & 63, seg = t >> 6;
        const float* ar = afv + (size_t)(b * NN + iis[pp]) * AA + seg * 16;
        const float* br = afv + (size_t)(b * NN + jjs[pp]) * AA + seg * 16;
        float4 xa = *(const float4*)(ar),     xb2 = *(const float4*)(ar + 4);
        float4 xc = *(const float4*)(ar + 8), xd = *(const float4*)(ar + 12);
        float4 ya = *(const float4*)(br),     yb = *(const float4*)(br + 4);
        float4 yc = *(const float4*)(br + 8), yd = *(const float4*)(br + 12);
        float4 s0 = make_float4(xa.x + ya.x, xa.y + ya.y, xa.z + ya.z, xa.w + ya.w);
        float4 s1 = make_float4(xb2.x + yb.x, xb2.y + yb.y, xb2.z + yb.z, xb2.w + yb.w);
        float4 s2 = make_float4(xc.x + yc.x, xc.y + yc.y, xc.z + yc.z, xc.w + yc.w);
        float4 s3 = make_float4(xd.x + yd.x, xd.y + yd.y, xd.z + yd.z, xd.w + yd.w);
        float4 p0 = make_float4(xa.x * ya.x, xa.y * ya.y, xa.z * ya.z, xa.w * ya.w);
        float4 p1 = make_float4(xb2.x * yb.x, xb2.y * yb.y, xb2.z * yb.z, xb2.w * yb.w);
        float4 p2 = make_float4(xc.x * yc.x, xc.y * yc.y, xc.z * yc.z, xc.w * yc.w);
        float4 p3 = make_float4(xd.x * yd.x, xd.y * yd.y, xd.z * yd.z, xd.w * yd.w);
        int gs = seg * 2, gp = 8 + seg * 2, sw = pp & 7;
        *(bf16x8*)(X + pp * 128 + (((gs + 0) ^ sw) * 8)) = pack_bf16x8(s0, s1);
        *(bf16x8*)(X + pp * 128 + (((gs + 1) ^ sw) * 8)) = pack_bf16x8(s2, s3);
        *(bf16x8*)(X + pp * 128 + (((gp + 0) ^ sw) * 8)) = pack_bf16x8(p0, p1);
        *(bf16x8*)(X + pp * 128 + (((gp + 1) ^ sw) * 8)) = pack_bf16x8(p2, p3);
    }
    __syncthreads();
    const int wn = w * 32;
    f32x4 acc1[4][2];
    #pragma unroll
    for (int i = 0; i < 4; ++i)
        #pragma unroll
        for (int j = 0; j < 2; ++j) acc1[i][j] = 0.f;
    #pragma unroll
    for (int ks = 0; ks < 4; ++ks) {
        int g = ks * 4 + lg;
        bf16x8 a[4];
        #pragma unroll
        for (int mi = 0; mi < 4; ++mi) {
            int row = mi * 16 + lm;
            a[mi] = *(const bf16x8*)(X + row * 128 + ((g ^ (row & 7)) * 8));
        }
        #pragma unroll
        for (int ni = 0; ni < 2; ++ni) {
            bf16x8 bv = *(const bf16x8*)(cw1T + (size_t)(wn + ni * 16 + lm) * 128 +
                                         ks * 32 + lg * 8);
            #pragma unroll
            for (int mi = 0; mi < 4; ++mi)
                acc1[mi][ni] = __builtin_amdgcn_mfma_f32_16x16x32_bf16(
                    a[mi], bv, acc1[mi][ni], 0, 0, 0);
        }
    }
    #pragma unroll
    for (int ni = 0; ni < 2; ++ni) {
        int n = wn + ni * 16 + lm;
        float bb = cb1[n];
        int gn = n >> 3, ne = n & 7;
        #pragma unroll
        for (int mi = 0; mi < 4; ++mi)
            #pragma unroll
            for (int r = 0; r < 4; ++r) {
                int row = mi * 16 + lg * 4 + r;
                Hs[row * 128 + ((gn ^ (row & 7)) * 8 + ne)] =
                    f2bf(gelu_f(acc1[mi][ni][r] + bb));
            }
    }
    __syncthreads();
    f32x4 acc2[2];
    acc2[0] = 0.f; acc2[1] = 0.f;
    #pragma unroll
    for (int ks = 0; ks < 4; ++ks) {
        int row = w * 16 + lm;
        int g = ks * 4 + lg;
        bf16x8 a2 = *(const bf16x8*)(Hs + row * 128 + ((g ^ (row & 7)) * 8));
        #pragma unroll
        for (int ni = 0; ni < 2; ++ni) {
            bf16x8 bv = *(const bf16x8*)(cw2T + (size_t)(ni * 16 + lm) * 128 +
                                         ks * 32 + lg * 8);
            acc2[ni] = __builtin_amdgcn_mfma_f32_16x16x32_bf16(a2, bv, acc2[ni], 0, 0, 0);
        }
    }
    {
        unsigned short* T = sm;
        __syncthreads();
        #pragma unroll
        for (int ni = 0; ni < 2; ++ni) {
            int d = ni * 16 + lm;
            float bb = cb2[d];
            #pragma unroll
            for (int r = 0; r < 4; ++r) {
                int p = w * 16 + lg * 4 + r;
                T[d * 64 + p] = f2bf(acc2[ni][r] + bb);
            }
        }
        __syncthreads();
        int d = t >> 3, slot = t & 7;
        bf16x8 v = *(const bf16x8*)(T + d * 64 + slot * 8);
        *(bf16x8*)(pairT + ((size_t)b * DP + d) * PP + pbase + slot * 8) = v;
    }
}

// ---------------------------------------------------------------------------
// Kernel B (big): gav + grv + ew1/ew2 conversions + afv copy.
//   [0,512):    gav, b = bid&7 (XCD-pinned: all blocks of b on XCD b so
//               pairT[b] (520KB) stays L2-resident), rt = bid>>3.
//   [512,768):  grv per b (self-staged afv transpose in LDS)
//   [768,2048): ew1 -> ew1bT
//   [2048,2176): ew2 -> ew2bT
//   [2176,2240): afv copy -> out2
// ---------------------------------------------------------------------------
__global__ __launch_bounds__(256) void gav_k(
    const float* __restrict__ ga, const unsigned short* __restrict__ pairT,
    unsigned short* __restrict__ Xb,
    const float* __restrict__ gr, const float* __restrict__ afv,
    const float* __restrict__ ew1, unsigned short* __restrict__ ew1bT,
    const float* __restrict__ ew2, unsigned short* __restrict__ ew2bT,
    float* __restrict__ out2)
{
    __shared__ unsigned short sm[24576];   // 48KB multi-purpose
    const int bid = blockIdx.x;
    const int t = threadIdx.x;
    const int w = t >> 6, lane = t & 63;
    const int lm = lane & 15, lg = lane >> 4;

    if (bid >= 2176) {
        // ---------------- afv copy ----------------
        int idx = (bid - 2176) * 256 + t;   // 16384 f4
        float4 v = *(const float4*)(afv + (size_t)idx * 4);
        *(float4*)(out2 + (size_t)idx * 4) = v;
        return;
    }
    if (bid >= 2048) {
        // ---------------- ew2 convert+transpose ----------------
        int q = (bid - 2048) * 256 + t;     // 0..32767
        int n = q & 255;
        int k0 = (q >> 8) * 4;
        ushort4 o;
        o.x = f2bf(ew2[(size_t)(k0 + 0) * EE + n]);
        o.y = f2bf(ew2[(size_t)(k0 + 1) * EE + n]);
        o.z = f2bf(ew2[(size_t)(k0 + 2) * EE + n]);
        o.w = f2bf(ew2[(size_t)(k0 + 3) * EE + n]);
        *(ushort4*)(ew2bT + (size_t)n * HH + k0) = o;
        return;
    }
    if (bid >= 768) {
        // ---------------- ew1 convert+transpose ----------------
        int q = (bid - 768) * 256 + t;      // 0..327679
        int n = q & 511;
        int k0 = (q >> 9) * 4;
        ushort4 o;
        o.x = f2bf(ew1[(size_t)(k0 + 0) * HH + n]);
        o.y = f2bf(ew1[(size_t)(k0 + 1) * HH + n]);
        o.z = f2bf(ew1[(size_t)(k0 + 2) * HH + n]);
        o.w = f2bf(ew1[(size_t)(k0 + 3) * HH + n]);
        *(ushort4*)(ew1bT + (size_t)n * XDIM + k0) = o;
        return;
    }

    if (bid >= 512) {
        // ---------------- grv MFMA path (self-contained) ----------------
        const int gb = bid - 512;
        const int b = gb >> 5;
        const int rbase = (gb & 31) * 128;
        const float* gab = gr + ((size_t)b * 4096 + rbase) * NN;
        unsigned short* As  = sm;            // [128][128] bf16 swizzled (32KB)
        unsigned short* Bs2 = sm + 16384;    // [64][128]  bf16 swizzled (16KB)
        // stage gr f32 -> bf16 LDS
        {
            const int srow = t >> 1, half = t & 1;
            const float* arow = gab + (size_t)srow * NN + half * 64;
            #pragma unroll
            for (int q = 0; q < 8; ++q) {
                float4 x0 = *(const float4*)(arow + q * 8);
                float4 x1 = *(const float4*)(arow + q * 8 + 4);
                bf16x8 v = pack_bf16x8(x0, x1);
                int g = half * 8 + q;
                *(bf16x8*)(As + srow * 128 + ((g ^ (srow & 7)) * 8)) = v;
            }
        }
        // stage afv[b] transposed: Bs2[a][m]
        #pragma unroll
        for (int q = 0; q < 8; ++q) {
            int pos = t + q * 256;           // 2048 f4: 128 m x 16 f4
            int m = pos >> 4, f4i = pos & 15;
            float4 v = *(const float4*)(afv + (size_t)(b * NN + m) * AA + f4i * 4);
            int gm = m >> 3, me = m & 7;
            float vv[4] = {v.x, v.y, v.z, v.w};
            #pragma unroll
            for (int i = 0; i < 4; ++i) {
                int a = f4i * 4 + i;
                Bs2[a * 128 + ((gm ^ (a & 7)) * 8 + me)] = f2bf(vv[i]);
            }
        }
        __syncthreads();
        const int wm = w * 32;
        f32x4 acc[2][4];
        #pragma unroll
        for (int i = 0; i < 2; ++i)
            #pragma unroll
            for (int j = 0; j < 4; ++j) acc[i][j] = 0.f;
        #pragma unroll
        for (int ks = 0; ks < 4; ++ks) {
            int g = ks * 4 + lg;
            int r0 = wm + lm, r1 = wm + 16 + lm;
            bf16x8 a0 = *(const bf16x8*)(As + r0 * 128 + ((g ^ (r0 & 7)) * 8));
            bf16x8 a1 = *(const bf16x8*)(As + r1 * 128 + ((g ^ (r1 & 7)) * 8));
            #pragma unroll
            for (int ni = 0; ni < 4; ++ni) {
                int a = ni * 16 + lm;
                bf16x8 bv = *(const bf16x8*)(Bs2 + a * 128 + ((g ^ (a & 7)) * 8));
                acc[0][ni] = __builtin_amdgcn_mfma_f32_16x16x32_bf16(a0, bv, acc[0][ni], 0, 0, 0);
                acc[1][ni] = __builtin_amdgcn_mfma_f32_16x16x32_bf16(a1, bv, acc[1][ni], 0, 0, 0);
            }
        }
        __syncthreads();
        unsigned short* T = sm;             // [128][64] bf16
        #pragma unroll
        for (int mi = 0; mi < 2; ++mi)
            #pragma unroll
            for (int ni = 0; ni < 4; ++ni)
                #pragma unroll
                for (int r = 0; r < 4; ++r)
                    T[(wm + mi * 16 + lg * 4 + r) * 64 + ni * 16 + lm] =
                        f2bf(acc[mi][ni][r]);
        __syncthreads();
        #pragma unroll
        for (int q = 0; q < 4; ++q) {
            int idx = t + q * 256;
            int rr2 = idx >> 3, slot = idx & 7;
            bf16x8 v = *(const bf16x8*)(T + rr2 * 64 + slot * 8);
            int grow = rbase + rr2;
            *(bf16x8*)(Xb + ((size_t)(b * NN) + (grow >> 5)) * XDIM +
                       (grow & 31) * 64 + slot * 8) = v;
        }
        return;
    }

    // ---------------- gav (XCD-pinned by b) ----------------
    const int b = bid & 7, rt = bid >> 3;
    const int rbase = rt * 32;
    const int srow = t >> 3, slot = t & 7;
    const int wr = (w & 1) * 16, wc = (w >> 1) * 16;
    unsigned short* As = sm;                // [32][128] (8KB)
    unsigned short* Bs = sm + 4096;         // [32][128] (8KB)

    f32x4 acc = 0.f;

    const float* gab = ga + (size_t)(b * 2048 + rbase) * PP;
    const unsigned short* pbT = pairT + (size_t)b * DP * PP;

    float4 ra[4];
    bf16x8 rb0, rb1;
    {
        int k0 = slot * 8;
        ra[0] = *(const float4*)(gab + (size_t)srow * PP + k0);
        ra[1] = *(const float4*)(gab + (size_t)srow * PP + k0 + 4);
        ra[2] = *(const float4*)(gab + (size_t)srow * PP + k0 + 64);
        ra[3] = *(const float4*)(gab + (size_t)srow * PP + k0 + 68);
        rb0 = *(const bf16x8*)(pbT + (size_t)srow * PP + k0);
        rb1 = *(const bf16x8*)(pbT + (size_t)srow * PP + k0 + 64);
    }

    for (int it = 0; it < 64; ++it) {
        __syncthreads();
        const int sw = srow & 7;
        const int g0 = (slot ^ sw) * 8;
        const int g1 = ((slot ^ sw) + 8) * 8;
        *(bf16x8*)(As + srow * 128 + g0) = pack_bf16x8(ra[0], ra[1]);
        *(bf16x8*)(As + srow * 128 + g1) = pack_bf16x8(ra[2], ra[3]);
        *(bf16x8*)(Bs + srow * 128 + g0) = rb0;
        *(bf16x8*)(Bs + srow * 128 + g1) = rb1;
        __syncthreads();
        if (it + 1 < 64) {
            int kn = (it + 1) * 128 + slot * 8;
            int k1 = kn + 64; if (k1 > PP - 8) k1 = PP - 8;
            ra[0] = *(const float4*)(gab + (size_t)srow * PP + kn);
            ra[1] = *(const float4*)(gab + (size_t)srow * PP + kn + 4);
            ra[2] = *(const float4*)(gab + (size_t)srow * PP + k1);
            ra[3] = *(const float4*)(gab + (size_t)srow * PP + k1 + 4);
            rb0 = *(const bf16x8*)(pbT + (size_t)srow * PP + kn);
            rb1 = *(const bf16x8*)(pbT + (size_t)srow * PP + k1);
        }
        if (it < 63) {
            #pragma unroll
            for (int ks = 0; ks < 4; ++ks) {
                int gg = ks * 4 + lg;
                int rowa = wr + lm;
                int rowb = wc + lm;
                bf16x8 a  = *(const bf16x8*)(As + rowa * 128 + ((gg ^ (rowa & 7)) * 8));
                bf16x8 bv = *(const bf16x8*)(Bs + rowb * 128 + ((gg ^ (rowb & 7)) * 8));
                acc = __builtin_amdgcn_mfma_f32_16x16x32_bf16(a, bv, acc, 0, 0, 0);
            }
        } else {
            #pragma unroll
            for (int ks = 0; ks < 2; ++ks) {
                int gg = ks * 4 + lg;
                int rowa = wr + lm;
                int rowb = wc + lm;
                bf16x8 a  = *(const bf16x8*)(As + rowa * 128 + ((gg ^ (rowa & 7)) * 8));
                bf16x8 bv = *(const bf16x8*)(Bs + rowb * 128 + ((gg ^ (rowb & 7)) * 8));
                acc = __builtin_amdgcn_mfma_f32_16x16x32_bf16(a, bv, acc, 0, 0, 0);
            }
        }
    }
    #pragma unroll
    for (int r = 0; r < 4; ++r) {
        int grow = rbase + wr + lg * 4 + r;
        int n = grow >> 4, a2 = grow & 15;
        int d = wc + lm;
        Xb[(size_t)(b * NN + n) * XDIM + 2048 + a2 * DP + d] = f2bf(acc[r]);
    }
}

// ---------------------------------------------------------------------------
// Kernel C: mlp layer1, 32x32 tiles, grid 512 (2 blk/CU), K=2560 (40 iters),
// fused bias+gelu -> Hb bf16.
// ---------------------------------------------------------------------------
__global__ __launch_bounds__(256) void mlp1_k(
    const unsigned short* __restrict__ Xb,
    const unsigned short* __restrict__ Wt,
    const float* __restrict__ eb1, unsigned short* __restrict__ Hb)
{
    __shared__ unsigned short As[32 * 64];   // 4KB
    __shared__ unsigned short Bs[32 * 64];   // 4KB
    const int bid = blockIdx.x;
    const int ct = bid & 15, rt = bid >> 4;
    const int rbase = rt * 32, nbase = ct * 32;
    const int t = threadIdx.x;
    const int w = t >> 6, lane = t & 63;
    const int lm = lane & 15, lg = lane >> 4;
    const int wr = (w & 1) * 16, wc = (w >> 1) * 16;
    const int srow = t >> 3, sg = t & 7;

    f32x4 acc = 0.f;

    const unsigned short* Arow = Xb + (size_t)(rbase + srow) * XDIM;
    const unsigned short* Brow = Wt + (size_t)(nbase + srow) * XDIM;

    bf16x8 rA = *(const bf16x8*)(Arow + sg * 8);
    bf16x8 rB = *(const bf16x8*)(Brow + sg * 8);

    for (int it = 0; it < 40; ++it) {
        __syncthreads();
        const int sw = srow & 7;
        *(bf16x8*)(As + srow * 64 + ((sg ^ sw) * 8)) = rA;
        *(bf16x8*)(Bs + srow * 64 + ((sg ^ sw) * 8)) = rB;
        __syncthreads();
        if (it + 1 < 40) {
            int kn = (it + 1) * 64;
            rA = *(const bf16x8*)(Arow + kn + sg * 8);
            rB = *(const bf16x8*)(Brow + kn + sg * 8);
        }
        #pragma unroll
        for (int ks = 0; ks < 2; ++ks) {
            int g = ks * 4 + lg;
            int r0 = wr + lm, r1 = wc + lm;
            bf16x8 a  = *(const bf16x8*)(As + r0 * 64 + ((g ^ (r0 & 7)) * 8));
            bf16x8 bv = *(const bf16x8*)(Bs + r1 * 64 + ((g ^ (r1 & 7)) * 8));
            acc = __builtin_amdgcn_mfma_f32_16x16x32_bf16(a, bv, acc, 0, 0, 0);
        }
    }
    const int col = nbase + wc + lm;
    const float bb = eb1[col];
    #pragma unroll
    for (int r = 0; r < 4; ++r) {
        int row = rbase + wr + lg * 4 + r;
        Hb[(size_t)row * HH + col] = f2bf(gelu_f(acc[r] + bb));
    }
}

// ---------------------------------------------------------------------------
// Kernel D: mlp layer2, 32x32 tiles, grid 256, K=512 (8 iters), f32 out + eb2.
// ---------------------------------------------------------------------------
__global__ __launch_bounds__(256) void mlp2_k(
    const unsigned short* __restrict__ Hb,
    const unsigned short* __restrict__ Wt,
    const float* __restrict__ eb2, float* __restrict__ out)
{
    __shared__ unsigned short As[32 * 64];
    __shared__ unsigned short Bs[32 * 64];
    const int bid = blockIdx.x;
    const int ct = bid & 7, rt = bid >> 3;
    const int rbase = rt * 32, nbase = ct * 32;
    const int t = threadIdx.x;
    const int w = t >> 6, lane = t & 63;
    const int lm = lane & 15, lg = lane >> 4;
    const int wr = (w & 1) * 16, wc = (w >> 1) * 16;
    const int srow = t >> 3, sg = t & 7;

    f32x4 acc = 0.f;

    const unsigned short* Arow = Hb + (size_t)(rbase + srow) * HH;
    const unsigned short* Brow = Wt + (size_t)(nbase + srow) * HH;

    bf16x8 rA = *(const bf16x8*)(Arow + sg * 8);
    bf16x8 rB = *(const bf16x8*)(Brow + sg * 8);

    for (int it = 0; it < 8; ++it) {
        __syncthreads();
        const int sw = srow & 7;
        *(bf16x8*)(As + srow * 64 + ((sg ^ sw) * 8)) = rA;
        *(bf16x8*)(Bs + srow * 64 + ((sg ^ sw) * 8)) = rB;
        __syncthreads();
        if (it + 1 < 8) {
            int kn = (it + 1) * 64;
            rA = *(const bf16x8*)(Arow + kn + sg * 8);
            rB = *(const bf16x8*)(Brow + kn + sg * 8);
        }
        #pragma unroll
        for (int ks = 0; ks < 2; ++ks) {
            int g = ks * 4 + lg;
            int r0 = wr + lm, r1 = wc + lm;
            bf16x8 a  = *(const bf16x8*)(As + r0 * 64 + ((g ^ (r0 & 7)) * 8));
            bf16x8 bv = *(const bf16x8*)(Bs + r1 * 64 + ((g ^ (r1 & 7)) * 8));
            acc = __builtin_amdgcn_mfma_f32_16x16x32_bf16(a, bv, acc, 0, 0, 0);
        }
    }
    const int col = nbase + wc + lm;
    const float bb = eb2[col];
    #pragma unroll
    for (int r = 0; r < 4; ++r) {
        int row = rbase + wr + lg * 4 + r;
        out[(size_t)row * EE + col] = acc[r] + bb;
    }
}

extern "C" void kernel_launch(void* const* d_in, const int* in_sizes, int n_in,
                              void* d_out, int out_size, void* d_ws, size_t ws_size,
                              hipStream_t stream) {
    const float* gr  = (const float*)d_in[0];
    const float* ga  = (const float*)d_in[1];
    const float* afv = (const float*)d_in[2];
    const float* cw1 = (const float*)d_in[3];
    const float* cb1 = (const float*)d_in[4];
    const float* cw2 = (const float*)d_in[5];
    const float* cb2 = (const float*)d_in[6];
    const float* ew1 = (const float*)d_in[7];
    const float* eb1 = (const float*)d_in[8];
    const float* ew2 = (const float*)d_in[9];
    const float* eb2 = (const float*)d_in[10];
    float* out = (float*)d_out;
    float* ws = (float*)d_ws;

    unsigned short* pairT  = (unsigned short*)(ws + WS_PAIRT);
    unsigned short* Xb     = (unsigned short*)(ws + WS_XB);
    unsigned short* ew1bT  = (unsigned short*)(ws + WS_EW1B);
    unsigned short* cw1T   = (unsigned short*)(ws + WS_CW1T);
    unsigned short* cw2T   = (unsigned short*)(ws + WS_CW2T);
    unsigned short* ew2bT  = (unsigned short*)(ws + WS_EW2B);
    unsigned short* Hb     = (unsigned short*)(ws + WS_HB);

    prep_k<<<dim3(20), dim3(256), 0, stream>>>(cw1, cw2, cw1T, cw2T);
    stage1_k<<<dim3(1016), dim3(256), 0, stream>>>(afv, cw1T, cb1, cw2T, cb2, pairT);
    gav_k<<<dim3(2240), dim3(256), 0, stream>>>(ga, pairT, Xb, gr, afv,
                                                ew1, ew1bT, ew2, ew2bT,
                                                out + (size_t)BB * NN * EE);
    mlp1_k<<<dim3(512), dim3(256), 0, stream>>>(Xb, ew1bT, eb1, Hb);
    mlp2_k<<<dim3(256), dim3(256), 0, stream>>>(Hb, ew2bT, eb2, out);
}

// Round 10
// 170.979 us; speedup vs baseline: 2.6959x; 1.0569x over previous
//
#include <hip/hip_runtime.h>
#include <math.h>

// Problem constants (fixed by setup_inputs)
#define BB 8
#define NN 128
#define AA 64
#define RR 32
#define RA 16
#define PP 8128            // N*(N-1)/2 = 127*64
#define DP 32
#define HH 512
#define EE 256
#define XDIM 2560          // RR*AA + RA*DP = 2048 + 512

// workspace layout (float offsets)
static constexpr size_t WS_PAIRT = 0;                                // pair^T bf16 [b][32][8128]
static constexpr size_t WS_XB    = WS_PAIRT + (size_t)BB*DP*PP/2;    // X bf16 1024x2560
static constexpr size_t WS_EW1B  = WS_XB + (size_t)BB*NN*XDIM/2;     // ew1^T bf16 [512][2560]
static constexpr size_t WS_CW1T  = WS_EW1B + (size_t)HH*XDIM/2;      // cw1^T bf16 [128][128]
static constexpr size_t WS_CW2T  = WS_CW1T + (size_t)128*128/2;      // cw2^T bf16 [32][128]
static constexpr size_t WS_EW2B  = WS_CW2T + (size_t)DP*128/2;       // ew2^T bf16 [256][512]
static constexpr size_t WS_HB    = WS_EW2B + (size_t)EE*HH/2;        // H bf16 [1024][512]

typedef __attribute__((ext_vector_type(8))) short bf16x8;
typedef __attribute__((ext_vector_type(4))) float f32x4;

__device__ __forceinline__ float gelu_f(float x) {
    float u = 0.7978845608028654f * (x + 0.044715f * x * x * x);
    float au = fabsf(u);
    float e = __expf(-2.0f * au);
    float th = (1.0f - e) / (1.0f + e);
    th = copysignf(th, u);
    return 0.5f * x * (1.0f + th);
}

__device__ __forceinline__ unsigned short f2bf(float x) {
    union { float f; unsigned u; } v; v.f = x;
    unsigned r = v.u + 0x7fffu + ((v.u >> 16) & 1u);   // RTNE
    return (unsigned short)(r >> 16);
}

__device__ __forceinline__ bf16x8 pack_bf16x8(float4 a, float4 b) {
    bf16x8 r;
    r[0] = (short)f2bf(a.x); r[1] = (short)f2bf(a.y);
    r[2] = (short)f2bf(a.z); r[3] = (short)f2bf(a.w);
    r[4] = (short)f2bf(b.x); r[5] = (short)f2bf(b.y);
    r[6] = (short)f2bf(b.z); r[7] = (short)f2bf(b.w);
    return r;
}

// ---------------------------------------------------------------------------
// Kernel 0: prep — cw1/cw2 bf16 transposes (needed by stage1 pair path).
// grid 20: [0,16) cw1T, [16,20) cw2T
// ---------------------------------------------------------------------------
__global__ __launch_bounds__(256) void prep_k(
    const float* __restrict__ cw1, const float* __restrict__ cw2,
    unsigned short* __restrict__ cw1T, unsigned short* __restrict__ cw2T)
{
    const int bid = blockIdx.x, t = threadIdx.x;
    if (bid < 16) {
        int idx = bid * 256 + t;              // 4096
        int n = idx >> 5;
        int k0 = (idx & 31) * 4;
        ushort4 o;
        o.x = f2bf(cw1[(size_t)(k0 + 0) * 128 + n]);
        o.y = f2bf(cw1[(size_t)(k0 + 1) * 128 + n]);
        o.z = f2bf(cw1[(size_t)(k0 + 2) * 128 + n]);
        o.w = f2bf(cw1[(size_t)(k0 + 3) * 128 + n]);
        *(ushort4*)(cw1T + (size_t)n * 128 + k0) = o;
    } else {
        int idx = (bid - 16) * 256 + t;       // 1024
        int d = idx >> 5;
        int k0 = (idx & 31) * 4;
        ushort4 o;
        o.x = f2bf(cw2[(size_t)(k0 + 0) * DP + d]);
        o.y = f2bf(cw2[(size_t)(k0 + 1) * DP + d]);
        o.z = f2bf(cw2[(size_t)(k0 + 2) * DP + d]);
        o.w = f2bf(cw2[(size_t)(k0 + 3) * DP + d]);
        *(ushort4*)(cw2T + (size_t)d * 128 + k0) = o;
    }
}

// ---------------------------------------------------------------------------
// Kernel A: pair MLP (MFMA both layers) -> pairT bf16 [b][d][p]
// grid 1016 (8 b x 127 pair-tiles of 64), block 256, LDS 32KB
// ---------------------------------------------------------------------------
__global__ __launch_bounds__(256) void stage1_k(
    const float* __restrict__ afv, const unsigned short* __restrict__ cw1T,
    const float* __restrict__ cb1, const unsigned short* __restrict__ cw2T,
    const float* __restrict__ cb2, unsigned short* __restrict__ pairT)
{
    __shared__ unsigned short sm[16384];   // 32KB
    __shared__ int iis[64], jjs[64];
    const int bid = blockIdx.x;
    const int t = threadIdx.x;
    const int w = t >> 6, lane = t & 63;
    const int lm = lane & 15, lg = lane >> 4;

    const int b = bid / 127;
    const int pbase = (bid % 127) * 64;
    unsigned short* X = sm;                 // [64][128] bf16 swizzled
    unsigned short* Hs = sm + 8192;         // [64][128] bf16 swizzled

    if (t < 64) {
        int p = pbase + t;
        int i = 0;
        while (i < 126) {
            int nx = i + 1;
            int off = nx * 127 - (nx * (nx - 1)) / 2;
            if (off <= p) i = nx; else break;
        }
        int off = i * 127 - (i * (i - 1)) / 2;
        iis[t] = i;
        jjs[t] = i + 1 + (p - off);
    }
    __syncthreads();
    {
        int pp = t & 63, seg = t >> 6;
        const float* ar = afv + (size_t)(b * NN + iis[pp]) * AA + seg * 16;
        const float* br = afv + (size_t)(b * NN + jjs[pp]) * AA + seg * 16;
        float4 xa = *(const float4*)(ar),     xb2 = *(const float4*)(ar + 4);
        float4 xc = *(const float4*)(ar + 8), xd = *(const float4*)(ar + 12);
        float4 ya = *(const float4*)(br),     yb = *(const float4*)(br + 4);
        float4 yc = *(const float4*)(br + 8), yd = *(const float4*)(br + 12);
        float4 s0 = make_float4(xa.x + ya.x, xa.y + ya.y, xa.z + ya.z, xa.w + ya.w);
        float4 s1 = make_float4(xb2.x + yb.x, xb2.y + yb.y, xb2.z + yb.z, xb2.w + yb.w);
        float4 s2 = make_float4(xc.x + yc.x, xc.y + yc.y, xc.z + yc.z, xc.w + yc.w);
        float4 s3 = make_float4(xd.x + yd.x, xd.y + yd.y, xd.z + yd.z, xd.w + yd.w);
        float4 p0 = make_float4(xa.x * ya.x, xa.y * ya.y, xa.z * ya.z, xa.w * ya.w);
        float4 p1 = make_float4(xb2.x * yb.x, xb2.y * yb.y, xb2.z * yb.z, xb2.w * yb.w);
        float4 p2 = make_float4(xc.x * yc.x, xc.y * yc.y, xc.z * yc.z, xc.w * yc.w);
        float4 p3 = make_float4(xd.x * yd.x, xd.y * yd.y, xd.z * yd.z, xd.w * yd.w);
        int gs = seg * 2, gp = 8 + seg * 2, sw = pp & 7;
        *(bf16x8*)(X + pp * 128 + (((gs + 0) ^ sw) * 8)) = pack_bf16x8(s0, s1);
        *(bf16x8*)(X + pp * 128 + (((gs + 1) ^ sw) * 8)) = pack_bf16x8(s2, s3);
        *(bf16x8*)(X + pp * 128 + (((gp + 0) ^ sw) * 8)) = pack_bf16x8(p0, p1);
        *(bf16x8*)(X + pp * 128 + (((gp + 1) ^ sw) * 8)) = pack_bf16x8(p2, p3);
    }
    __syncthreads();
    const int wn = w * 32;
    f32x4 acc1[4][2];
    #pragma unroll
    for (int i = 0; i < 4; ++i)
        #pragma unroll
        for (int j = 0; j < 2; ++j) acc1[i][j] = 0.f;
    #pragma unroll
    for (int ks = 0; ks < 4; ++ks) {
        int g = ks * 4 + lg;
        bf16x8 a[4];
        #pragma unroll
        for (int mi = 0; mi < 4; ++mi) {
            int row = mi * 16 + lm;
            a[mi] = *(const bf16x8*)(X + row * 128 + ((g ^ (row & 7)) * 8));
        }
        #pragma unroll
        for (int ni = 0; ni < 2; ++ni) {
            bf16x8 bv = *(const bf16x8*)(cw1T + (size_t)(wn + ni * 16 + lm) * 128 +
                                         ks * 32 + lg * 8);
            #pragma unroll
            for (int mi = 0; mi < 4; ++mi)
                acc1[mi][ni] = __builtin_amdgcn_mfma_f32_16x16x32_bf16(
                    a[mi], bv, acc1[mi][ni], 0, 0, 0);
        }
    }
    #pragma unroll
    for (int ni = 0; ni < 2; ++ni) {
        int n = wn + ni * 16 + lm;
        float bb = cb1[n];
        int gn = n >> 3, ne = n & 7;
        #pragma unroll
        for (int mi = 0; mi < 4; ++mi)
            #pragma unroll
            for (int r = 0; r < 4; ++r) {
                int row = mi * 16 + lg * 4 + r;
                Hs[row * 128 + ((gn ^ (row & 7)) * 8 + ne)] =
                    f2bf(gelu_f(acc1[mi][ni][r] + bb));
            }
    }
    __syncthreads();
    f32x4 acc2[2];
    acc2[0] = 0.f; acc2[1] = 0.f;
    #pragma unroll
    for (int ks = 0; ks < 4; ++ks) {
        int row = w * 16 + lm;
        int g = ks * 4 + lg;
        bf16x8 a2 = *(const bf16x8*)(Hs + row * 128 + ((g ^ (row & 7)) * 8));
        #pragma unroll
        for (int ni = 0; ni < 2; ++ni) {
            bf16x8 bv = *(const bf16x8*)(cw2T + (size_t)(ni * 16 + lm) * 128 +
                                         ks * 32 + lg * 8);
            acc2[ni] = __builtin_amdgcn_mfma_f32_16x16x32_bf16(a2, bv, acc2[ni], 0, 0, 0);
        }
    }
    {
        unsigned short* T = sm;
        __syncthreads();
        #pragma unroll
        for (int ni = 0; ni < 2; ++ni) {
            int d = ni * 16 + lm;
            float bb = cb2[d];
            #pragma unroll
            for (int r = 0; r < 4; ++r) {
                int p = w * 16 + lg * 4 + r;
                T[d * 64 + p] = f2bf(acc2[ni][r] + bb);
            }
        }
        __syncthreads();
        int d = t >> 3, slot = t & 7;
        bf16x8 v = *(const bf16x8*)(T + d * 64 + slot * 8);
        *(bf16x8*)(pairT + ((size_t)b * DP + d) * PP + pbase + slot * 8) = v;
    }
}

// ---------------------------------------------------------------------------
// Kernel B (big): gav + grv + ew1/ew2 conversions + afv copy.
//   [0,512):    gav, b = bid&7 (XCD-pinned), rt = bid>>3.  DOUBLE-BUFFERED:
//               one barrier/iter; MFMA(buf[cur]) overlaps writes(buf[cur^1]).
//   [512,768):  grv per b (self-staged afv transpose in LDS)
//   [768,2048): ew1 -> ew1bT
//   [2048,2176): ew2 -> ew2bT
//   [2176,2240): afv copy -> out2
// ---------------------------------------------------------------------------
__global__ __launch_bounds__(256) void gav_k(
    const float* __restrict__ ga, const unsigned short* __restrict__ pairT,
    unsigned short* __restrict__ Xb,
    const float* __restrict__ gr, const float* __restrict__ afv,
    const float* __restrict__ ew1, unsigned short* __restrict__ ew1bT,
    const float* __restrict__ ew2, unsigned short* __restrict__ ew2bT,
    float* __restrict__ out2)
{
    __shared__ unsigned short sm[24576];   // 48KB multi-purpose
    const int bid = blockIdx.x;
    const int t = threadIdx.x;
    const int w = t >> 6, lane = t & 63;
    const int lm = lane & 15, lg = lane >> 4;

    if (bid >= 2176) {
        int idx = (bid - 2176) * 256 + t;   // 16384 f4
        float4 v = *(const float4*)(afv + (size_t)idx * 4);
        *(float4*)(out2 + (size_t)idx * 4) = v;
        return;
    }
    if (bid >= 2048) {
        int q = (bid - 2048) * 256 + t;     // 0..32767
        int n = q & 255;
        int k0 = (q >> 8) * 4;
        ushort4 o;
        o.x = f2bf(ew2[(size_t)(k0 + 0) * EE + n]);
        o.y = f2bf(ew2[(size_t)(k0 + 1) * EE + n]);
        o.z = f2bf(ew2[(size_t)(k0 + 2) * EE + n]);
        o.w = f2bf(ew2[(size_t)(k0 + 3) * EE + n]);
        *(ushort4*)(ew2bT + (size_t)n * HH + k0) = o;
        return;
    }
    if (bid >= 768) {
        int q = (bid - 768) * 256 + t;      // 0..327679
        int n = q & 511;
        int k0 = (q >> 9) * 4;
        ushort4 o;
        o.x = f2bf(ew1[(size_t)(k0 + 0) * HH + n]);
        o.y = f2bf(ew1[(size_t)(k0 + 1) * HH + n]);
        o.z = f2bf(ew1[(size_t)(k0 + 2) * HH + n]);
        o.w = f2bf(ew1[(size_t)(k0 + 3) * HH + n]);
        *(ushort4*)(ew1bT + (size_t)n * XDIM + k0) = o;
        return;
    }

    if (bid >= 512) {
        // ---------------- grv MFMA path (self-contained) ----------------
        const int gb = bid - 512;
        const int b = gb >> 5;
        const int rbase = (gb & 31) * 128;
        const float* gab = gr + ((size_t)b * 4096 + rbase) * NN;
        unsigned short* As  = sm;            // [128][128] bf16 swizzled (32KB)
        unsigned short* Bs2 = sm + 16384;    // [64][128]  bf16 swizzled (16KB)
        {
            const int srow = t >> 1, half = t & 1;
            const float* arow = gab + (size_t)srow * NN + half * 64;
            #pragma unroll
            for (int q = 0; q < 8; ++q) {
                float4 x0 = *(const float4*)(arow + q * 8);
                float4 x1 = *(const float4*)(arow + q * 8 + 4);
                bf16x8 v = pack_bf16x8(x0, x1);
                int g = half * 8 + q;
                *(bf16x8*)(As + srow * 128 + ((g ^ (srow & 7)) * 8)) = v;
            }
        }
        #pragma unroll
        for (int q = 0; q < 8; ++q) {
            int pos = t + q * 256;           // 2048 f4: 128 m x 16 f4
            int m = pos >> 4, f4i = pos & 15;
            float4 v = *(const float4*)(afv + (size_t)(b * NN + m) * AA + f4i * 4);
            int gm = m >> 3, me = m & 7;
            float vv[4] = {v.x, v.y, v.z, v.w};
            #pragma unroll
            for (int i = 0; i < 4; ++i) {
                int a = f4i * 4 + i;
                Bs2[a * 128 + ((gm ^ (a & 7)) * 8 + me)] = f2bf(vv[i]);
            }
        }
        __syncthreads();
        const int wm = w * 32;
        f32x4 acc[2][4];
        #pragma unroll
        for (int i = 0; i < 2; ++i)
            #pragma unroll
            for (int j = 0; j < 4; ++j) acc[i][j] = 0.f;
        #pragma unroll
        for (int ks = 0; ks < 4; ++ks) {
            int g = ks * 4 + lg;
            int r0 = wm + lm, r1 = wm + 16 + lm;
            bf16x8 a0 = *(const bf16x8*)(As + r0 * 128 + ((g ^ (r0 & 7)) * 8));
            bf16x8 a1 = *(const bf16x8*)(As + r1 * 128 + ((g ^ (r1 & 7)) * 8));
            #pragma unroll
            for (int ni = 0; ni < 4; ++ni) {
                int a = ni * 16 + lm;
                bf16x8 bv = *(const bf16x8*)(Bs2 + a * 128 + ((g ^ (a & 7)) * 8));
                acc[0][ni] = __builtin_amdgcn_mfma_f32_16x16x32_bf16(a0, bv, acc[0][ni], 0, 0, 0);
                acc[1][ni] = __builtin_amdgcn_mfma_f32_16x16x32_bf16(a1, bv, acc[1][ni], 0, 0, 0);
            }
        }
        __syncthreads();
        unsigned short* T = sm;             // [128][64] bf16
        #pragma unroll
        for (int mi = 0; mi < 2; ++mi)
            #pragma unroll
            for (int ni = 0; ni < 4; ++ni)
                #pragma unroll
                for (int r = 0; r < 4; ++r)
                    T[(wm + mi * 16 + lg * 4 + r) * 64 + ni * 16 + lm] =
                        f2bf(acc[mi][ni][r]);
        __syncthreads();
        #pragma unroll
        for (int q = 0; q < 4; ++q) {
            int idx = t + q * 256;
            int rr2 = idx >> 3, slot = idx & 7;
            bf16x8 v = *(const bf16x8*)(T + rr2 * 64 + slot * 8);
            int grow = rbase + rr2;
            *(bf16x8*)(Xb + ((size_t)(b * NN) + (grow >> 5)) * XDIM +
                       (grow & 31) * 64 + slot * 8) = v;
        }
        return;
    }

    // ---------------- gav (XCD-pinned by b, double-buffered) ----------------
    const int b = bid & 7, rt = bid >> 3;
    const int rbase = rt * 32;
    const int srow = t >> 3, slot = t & 7;
    const int wr = (w & 1) * 16, wc = (w >> 1) * 16;

    f32x4 acc = 0.f;

    const float* gab = ga + (size_t)(b * 2048 + rbase) * PP;
    const unsigned short* pbT = pairT + (size_t)b * DP * PP;

    float4 ra[4];
    bf16x8 rb0, rb1;

#define GAV_LOAD(IT)                                                         \
    {                                                                        \
        int kn = (IT) * 128 + slot * 8;                                      \
        int k1 = kn + 64; if (k1 > PP - 8) k1 = PP - 8;                      \
        ra[0] = *(const float4*)(gab + (size_t)srow * PP + kn);              \
        ra[1] = *(const float4*)(gab + (size_t)srow * PP + kn + 4);          \
        ra[2] = *(const float4*)(gab + (size_t)srow * PP + k1);              \
        ra[3] = *(const float4*)(gab + (size_t)srow * PP + k1 + 4);          \
        rb0 = *(const bf16x8*)(pbT + (size_t)srow * PP + kn);                \
        rb1 = *(const bf16x8*)(pbT + (size_t)srow * PP + k1);                \
    }

#define GAV_WRITE(BUF)                                                      \
    {                                                                        \
        unsigned short* A_ = sm + (BUF) * 8192;                              \
        unsigned short* B_ = A_ + 4096;                                      \
        const int sw_ = srow & 7;                                            \
        const int g0_ = (slot ^ sw_) * 8;                                    \
        const int g1_ = ((slot ^ sw_) + 8) * 8;                              \
        *(bf16x8*)(A_ + srow * 128 + g0_) = pack_bf16x8(ra[0], ra[1]);       \
        *(bf16x8*)(A_ + srow * 128 + g1_) = pack_bf16x8(ra[2], ra[3]);       \
        *(bf16x8*)(B_ + srow * 128 + g0_) = rb0;                             \
        *(bf16x8*)(B_ + srow * 128 + g1_) = rb1;                             \
    }

    GAV_LOAD(0);
    GAV_WRITE(0);
    __syncthreads();
    GAV_LOAD(1);

    for (int it = 0; it < 64; ++it) {
        const int cur = it & 1;
        const unsigned short* Ac = sm + cur * 8192;
        const unsigned short* Bc = Ac + 4096;
        if (it + 1 < 64) GAV_WRITE(cur ^ 1);
        if (it + 2 < 64) GAV_LOAD(it + 2);
        if (it < 63) {
            #pragma unroll
            for (int ks = 0; ks < 4; ++ks) {
                int gg = ks * 4 + lg;
                int rowa = wr + lm;
                int rowb = wc + lm;
                bf16x8 a  = *(const bf16x8*)(Ac + rowa * 128 + ((gg ^ (rowa & 7)) * 8));
                bf16x8 bv = *(const bf16x8*)(Bc + rowb * 128 + ((gg ^ (rowb & 7)) * 8));
                acc = __builtin_amdgcn_mfma_f32_16x16x32_bf16(a, bv, acc, 0, 0, 0);
            }
        } else {
            // tail: only k 8064..8127 valid (granules 0..7)
            #pragma unroll
            for (int ks = 0; ks < 2; ++ks) {
                int gg = ks * 4 + lg;
                int rowa = wr + lm;
                int rowb = wc + lm;
                bf16x8 a  = *(const bf16x8*)(Ac + rowa * 128 + ((gg ^ (rowa & 7)) * 8));
                bf16x8 bv = *(const bf16x8*)(Bc + rowb * 128 + ((gg ^ (rowb & 7)) * 8));
                acc = __builtin_amdgcn_mfma_f32_16x16x32_bf16(a, bv, acc, 0, 0, 0);
            }
        }
        __syncthreads();
    }
    // C layout: col = lane&15, row = (lane>>4)*4 + reg.  row r = n*16+a.
    #pragma unroll
    for (int r = 0; r < 4; ++r) {
        int grow = rbase + wr + lg * 4 + r;
        int n = grow >> 4, a2 = grow & 15;
        int d = wc + lm;
        Xb[(size_t)(b * NN + n) * XDIM + 2048 + a2 * DP + d] = f2bf(acc[r]);
    }
}

// ---------------------------------------------------------------------------
// Kernel C: mlp layer1, 32x32 tiles, grid 512, XCD-swizzled, double-buffered,
// K=2560 (40 iters), fused bias+gelu -> Hb bf16.
// ---------------------------------------------------------------------------
__global__ __launch_bounds__(256) void mlp1_k(
    const unsigned short* __restrict__ Xb,
    const unsigned short* __restrict__ Wt,
    const float* __restrict__ eb1, unsigned short* __restrict__ Hb)
{
    __shared__ unsigned short sm[8192];   // 16KB: 2 x (A 2048 + B 2048)
    const int bid = blockIdx.x;
    // XCD swizzle: xcd = bid&7 gets rts {xcd*4..+3} x all cts ->
    // per-XCD working set: A 640KB + B 2.6MB, both L2-resident.
    const int xcd = bid & 7, idx = bid >> 3;      // idx 0..63
    const int rt = (xcd << 2) | (idx & 3);        // 0..31
    const int ct = idx >> 2;                      // 0..15
    const int rbase = rt * 32, nbase = ct * 32;
    const int t = threadIdx.x;
    const int w = t >> 6, lane = t & 63;
    const int lm = lane & 15, lg = lane >> 4;
    const int wr = (w & 1) * 16, wc = (w >> 1) * 16;
    const int srow = t >> 3, sg = t & 7;

    f32x4 acc = 0.f;

    const unsigned short* Arow = Xb + (size_t)(rbase + srow) * XDIM;
    const unsigned short* Brow = Wt + (size_t)(nbase + srow) * XDIM;

    bf16x8 rA, rB;

#define M1_LOAD(IT)  { rA = *(const bf16x8*)(Arow + (IT) * 64 + sg * 8);     \
                       rB = *(const bf16x8*)(Brow + (IT) * 64 + sg * 8); }
#define M1_WRITE(BUF) { unsigned short* A_ = sm + (BUF) * 4096;              \
                        unsigned short* B_ = A_ + 2048;                      \
                        const int sw_ = srow & 7;                            \
                        *(bf16x8*)(A_ + srow * 64 + ((sg ^ sw_) * 8)) = rA;  \
                        *(bf16x8*)(B_ + srow * 64 + ((sg ^ sw_) * 8)) = rB; }

    M1_LOAD(0); M1_WRITE(0);
    __syncthreads();
    M1_LOAD(1);

    for (int it = 0; it < 40; ++it) {
        const int cur = it & 1;
        const unsigned short* Ac = sm + cur * 4096;
        const unsigned short* Bc = Ac + 2048;
        if (it + 1 < 40) M1_WRITE(cur ^ 1);
        if (it + 2 < 40) M1_LOAD(it + 2);
        #pragma unroll
        for (int ks = 0; ks < 2; ++ks) {
            int g = ks * 4 + lg;
            int r0 = wr + lm, r1 = wc + lm;
            bf16x8 a  = *(const bf16x8*)(Ac + r0 * 64 + ((g ^ (r0 & 7)) * 8));
            bf16x8 bv = *(const bf16x8*)(Bc + r1 * 64 + ((g ^ (r1 & 7)) * 8));
            acc = __builtin_amdgcn_mfma_f32_16x16x32_bf16(a, bv, acc, 0, 0, 0);
        }
        __syncthreads();
    }
    const int col = nbase + wc + lm;
    const float bb = eb1[col];
    #pragma unroll
    for (int r = 0; r < 4; ++r) {
        int row = rbase + wr + lg * 4 + r;
        Hb[(size_t)row * HH + col] = f2bf(gelu_f(acc[r] + bb));
    }
}

// ---------------------------------------------------------------------------
// Kernel D: mlp layer2, 32x32 tiles, grid 256, XCD-swizzled, double-buffered,
// K=512 (8 iters), f32 out + eb2.
// ---------------------------------------------------------------------------
__global__ __launch_bounds__(256) void mlp2_k(
    const unsigned short* __restrict__ Hb,
    const unsigned short* __restrict__ Wt,
    const float* __restrict__ eb2, float* __restrict__ out)
{
    __shared__ unsigned short sm[8192];
    const int bid = blockIdx.x;
    const int xcd = bid & 7, idx = bid >> 3;      // idx 0..31
    const int rt = (xcd << 2) | (idx & 3);        // 0..31
    const int ct = idx >> 2;                      // 0..7
    const int rbase = rt * 32, nbase = ct * 32;
    const int t = threadIdx.x;
    const int w = t >> 6, lane = t & 63;
    const int lm = lane & 15, lg = lane >> 4;
    const int wr = (w & 1) * 16, wc = (w >> 1) * 16;
    const int srow = t >> 3, sg = t & 7;

    f32x4 acc = 0.f;

    const unsigned short* Arow = Hb + (size_t)(rbase + srow) * HH;
    const unsigned short* Brow = Wt + (size_t)(nbase + srow) * HH;

    bf16x8 rA, rB;

#define M2_LOAD(IT)  { rA = *(const bf16x8*)(Arow + (IT) * 64 + sg * 8);     \
                       rB = *(const bf16x8*)(Brow + (IT) * 64 + sg * 8); }
#define M2_WRITE(BUF) { unsigned short* A_ = sm + (BUF) * 4096;              \
                        unsigned short* B_ = A_ + 2048;                      \
                        const int sw_ = srow & 7;                            \
                        *(bf16x8*)(A_ + srow * 64 + ((sg ^ sw_) * 8)) = rA;  \
                        *(bf16x8*)(B_ + srow * 64 + ((sg ^ sw_) * 8)) = rB; }

    M2_LOAD(0); M2_WRITE(0);
    __syncthreads();
    M2_LOAD(1);

    for (int it = 0; it < 8; ++it) {
        const int cur = it & 1;
        const unsigned short* Ac = sm + cur * 4096;
        const unsigned short* Bc = Ac + 2048;
        if (it + 1 < 8) M2_WRITE(cur ^ 1);
        if (it + 2 < 8) M2_LOAD(it + 2);
        #pragma unroll
        for (int ks = 0; ks < 2; ++ks) {
            int g = ks * 4 + lg;
            int r0 = wr + lm, r1 = wc + lm;
            bf16x8 a  = *(const bf16x8*)(Ac + r0 * 64 + ((g ^ (r0 & 7)) * 8));
            bf16x8 bv = *(const bf16x8*)(Bc + r1 * 64 + ((g ^ (r1 & 7)) * 8));
            acc = __builtin_amdgcn_mfma_f32_16x16x32_bf16(a, bv, acc, 0, 0, 0);
        }
        __syncthreads();
    }
    const int col = nbase + wc + lm;
    const float bb = eb2[col];
    #pragma unroll
    for (int r = 0; r < 4; ++r) {
        int row = rbase + wr + lg * 4 + r;
        out[(size_t)row * EE + col] = acc[r] + bb;
    }
}

extern "C" void kernel_launch(void* const* d_in, const int* in_sizes, int n_in,
                              void* d_out, int out_size, void* d_ws, size_t ws_size,
                              hipStream_t stream) {
    const float* gr  = (const float*)d_in[0];
    const float* ga  = (const float*)d_in[1];
    const float* afv = (const float*)d_in[2];
    const float* cw1 = (const float*)d_in[3];
    const float* cb1 = (const float*)d_in[4];
    const float* cw2 = (const float*)d_in[5];
    const float* cb2 = (const float*)d_in[6];
    const float* ew1 = (const float*)d_in[7];
    const float* eb1 = (const float*)d_in[8];
    const float* ew2 = (const float*)d_in[9];
    const float* eb2 = (const float*)d_in[10];
    float* out = (float*)d_out;
    float* ws = (float*)d_ws;

    unsigned short* pairT  = (unsigned short*)(ws + WS_PAIRT);
    unsigned short* Xb     = (unsigned short*)(ws + WS_XB);
    unsigned short* ew1bT  = (unsigned short*)(ws + WS_EW1B);
    unsigned short* cw1T   = (unsigned short*)(ws + WS_CW1T);
    unsigned short* cw2T   = (unsigned short*)(ws + WS_CW2T);
    unsigned short* ew2bT  = (unsigned short*)(ws + WS_EW2B);
    unsigned short* Hb     = (unsigned short*)(ws + WS_HB);

    prep_k<<<dim3(20), dim3(256), 0, stream>>>(cw1, cw2, cw1T, cw2T);
    stage1_k<<<dim3(1016), dim3(256), 0, stream>>>(afv, cw1T, cb1, cw2T, cb2, pairT);
    gav_k<<<dim3(2240), dim3(256), 0, stream>>>(ga, pairT, Xb, gr, afv,
                                                ew1, ew1bT, ew2, ew2bT,
                                                out + (size_t)BB * NN * EE);
    mlp1_k<<<dim3(512), dim3(256), 0, stream>>>(Xb, ew1bT, eb1, Hb);
    mlp2_k<<<dim3(256), dim3(256), 0, stream>>>(Hb, ew2bT, eb2, out);
}

// Round 11
// 161.894 us; speedup vs baseline: 2.8472x; 1.0561x over previous
//
#include <hip/hip_runtime.h>
#include <math.h>

// Problem constants (fixed by setup_inputs)
#define BB 8
#define NN 128
#define AA 64
#define RR 32
#define RA 16
#define PP 8128            // N*(N-1)/2 = 127*64
#define DP 32
#define HH 512
#define EE 256
#define XDIM 2560          // RR*AA + RA*DP = 2048 + 512

// workspace layout (float offsets)
static constexpr size_t WS_PAIRT = 0;                                // pair^T bf16 [b][32][8128]
static constexpr size_t WS_XB    = WS_PAIRT + (size_t)BB*DP*PP/2;    // X bf16 1024x2560
static constexpr size_t WS_EW1B  = WS_XB + (size_t)BB*NN*XDIM/2;     // ew1^T bf16 [512][2560]
static constexpr size_t WS_CW1T  = WS_EW1B + (size_t)HH*XDIM/2;      // cw1^T bf16 [128][128]
static constexpr size_t WS_CW2T  = WS_CW1T + (size_t)128*128/2;      // cw2^T bf16 [32][128]
static constexpr size_t WS_EW2B  = WS_CW2T + (size_t)DP*128/2;       // ew2^T bf16 [256][512]
static constexpr size_t WS_HB    = WS_EW2B + (size_t)EE*HH/2;        // H bf16 [1024][512]

typedef __attribute__((ext_vector_type(8))) short bf16x8;
typedef __attribute__((ext_vector_type(4))) float f32x4;

__device__ __forceinline__ float gelu_f(float x) {
    float u = 0.7978845608028654f * (x + 0.044715f * x * x * x);
    float au = fabsf(u);
    float e = __expf(-2.0f * au);
    float th = (1.0f - e) / (1.0f + e);
    th = copysignf(th, u);
    return 0.5f * x * (1.0f + th);
}

__device__ __forceinline__ unsigned short f2bf(float x) {
    union { float f; unsigned u; } v; v.f = x;
    unsigned r = v.u + 0x7fffu + ((v.u >> 16) & 1u);   // RTNE
    return (unsigned short)(r >> 16);
}

__device__ __forceinline__ bf16x8 pack_bf16x8(float4 a, float4 b) {
    bf16x8 r;
    r[0] = (short)f2bf(a.x); r[1] = (short)f2bf(a.y);
    r[2] = (short)f2bf(a.z); r[3] = (short)f2bf(a.w);
    r[4] = (short)f2bf(b.x); r[5] = (short)f2bf(b.y);
    r[6] = (short)f2bf(b.z); r[7] = (short)f2bf(b.w);
    return r;
}

// ---------------------------------------------------------------------------
// Kernel 0: prep — cw1/cw2 bf16 transposes (needed by stage1 pair path).
// grid 20: [0,16) cw1T, [16,20) cw2T
// ---------------------------------------------------------------------------
__global__ __launch_bounds__(256) void prep_k(
    const float* __restrict__ cw1, const float* __restrict__ cw2,
    unsigned short* __restrict__ cw1T, unsigned short* __restrict__ cw2T)
{
    const int bid = blockIdx.x, t = threadIdx.x;
    if (bid < 16) {
        int idx = bid * 256 + t;              // 4096
        int n = idx >> 5;
        int k0 = (idx & 31) * 4;
        ushort4 o;
        o.x = f2bf(cw1[(size_t)(k0 + 0) * 128 + n]);
        o.y = f2bf(cw1[(size_t)(k0 + 1) * 128 + n]);
        o.z = f2bf(cw1[(size_t)(k0 + 2) * 128 + n]);
        o.w = f2bf(cw1[(size_t)(k0 + 3) * 128 + n]);
        *(ushort4*)(cw1T + (size_t)n * 128 + k0) = o;
    } else {
        int idx = (bid - 16) * 256 + t;       // 1024
        int d = idx >> 5;
        int k0 = (idx & 31) * 4;
        ushort4 o;
        o.x = f2bf(cw2[(size_t)(k0 + 0) * DP + d]);
        o.y = f2bf(cw2[(size_t)(k0 + 1) * DP + d]);
        o.z = f2bf(cw2[(size_t)(k0 + 2) * DP + d]);
        o.w = f2bf(cw2[(size_t)(k0 + 3) * DP + d]);
        *(ushort4*)(cw2T + (size_t)d * 128 + k0) = o;
    }
}

// ---------------------------------------------------------------------------
// Kernel A: pair MLP (MFMA both layers) -> pairT bf16 [b][d][p]
// grid 1016 (8 b x 127 pair-tiles of 64), block 256, LDS 32KB
// ---------------------------------------------------------------------------
__global__ __launch_bounds__(256) void stage1_k(
    const float* __restrict__ afv, const unsigned short* __restrict__ cw1T,
    const float* __restrict__ cb1, const unsigned short* __restrict__ cw2T,
    const float* __restrict__ cb2, unsigned short* __restrict__ pairT)
{
    __shared__ unsigned short sm[16384];   // 32KB
    __shared__ int iis[64], jjs[64];
    const int bid = blockIdx.x;
    const int t = threadIdx.x;
    const int w = t >> 6, lane = t & 63;
    const int lm = lane & 15, lg = lane >> 4;

    const int b = bid / 127;
    const int pbase = (bid % 127) * 64;
    unsigned short* X = sm;                 // [64][128] bf16 swizzled
    unsigned short* Hs = sm + 8192;         // [64][128] bf16 swizzled

    if (t < 64) {
        int p = pbase + t;
        int i = 0;
        while (i < 126) {
            int nx = i + 1;
            int off = nx * 127 - (nx * (nx - 1)) / 2;
            if (off <= p) i = nx; else break;
        }
        int off = i * 127 - (i * (i - 1)) / 2;
        iis[t] = i;
        jjs[t] = i + 1 + (p - off);
    }
    __syncthreads();
    {
        int pp = t & 63, seg = t >> 6;
        const float* ar = afv + (size_t)(b * NN + iis[pp]) * AA + seg * 16;
        const float* br = afv + (size_t)(b * NN + jjs[pp]) * AA + seg * 16;
        float4 xa = *(const float4*)(ar),     xb2 = *(const float4*)(ar + 4);
        float4 xc = *(const float4*)(ar + 8), xd = *(const float4*)(ar + 12);
        float4 ya = *(const float4*)(br),     yb = *(const float4*)(br + 4);
        float4 yc = *(const float4*)(br + 8), yd = *(const float4*)(br + 12);
        float4 s0 = make_float4(xa.x + ya.x, xa.y + ya.y, xa.z + ya.z, xa.w + ya.w);
        float4 s1 = make_float4(xb2.x + yb.x, xb2.y + yb.y, xb2.z + yb.z, xb2.w + yb.w);
        float4 s2 = make_float4(xc.x + yc.x, xc.y + yc.y, xc.z + yc.z, xc.w + yc.w);
        float4 s3 = make_float4(xd.x + yd.x, xd.y + yd.y, xd.z + yd.z, xd.w + yd.w);
        float4 p0 = make_float4(xa.x * ya.x, xa.y * ya.y, xa.z * ya.z, xa.w * ya.w);
        float4 p1 = make_float4(xb2.x * yb.x, xb2.y * yb.y, xb2.z * yb.z, xb2.w * yb.w);
        float4 p2 = make_float4(xc.x * yc.x, xc.y * yc.y, xc.z * yc.z, xc.w * yc.w);
        float4 p3 = make_float4(xd.x * yd.x, xd.y * yd.y, xd.z * yd.z, xd.w * yd.w);
        int gs = seg * 2, gp = 8 + seg * 2, sw = pp & 7;
        *(bf16x8*)(X + pp * 128 + (((gs + 0) ^ sw) * 8)) = pack_bf16x8(s0, s1);
        *(bf16x8*)(X + pp * 128 + (((gs + 1) ^ sw) * 8)) = pack_bf16x8(s2, s3);
        *(bf16x8*)(X + pp * 128 + (((gp + 0) ^ sw) * 8)) = pack_bf16x8(p0, p1);
        *(bf16x8*)(X + pp * 128 + (((gp + 1) ^ sw) * 8)) = pack_bf16x8(p2, p3);
    }
    __syncthreads();
    const int wn = w * 32;
    f32x4 acc1[4][2];
    #pragma unroll
    for (int i = 0; i < 4; ++i)
        #pragma unroll
        for (int j = 0; j < 2; ++j) acc1[i][j] = 0.f;
    #pragma unroll
    for (int ks = 0; ks < 4; ++ks) {
        int g = ks * 4 + lg;
        bf16x8 a[4];
        #pragma unroll
        for (int mi = 0; mi < 4; ++mi) {
            int row = mi * 16 + lm;
            a[mi] = *(const bf16x8*)(X + row * 128 + ((g ^ (row & 7)) * 8));
        }
        #pragma unroll
        for (int ni = 0; ni < 2; ++ni) {
            bf16x8 bv = *(const bf16x8*)(cw1T + (size_t)(wn + ni * 16 + lm) * 128 +
                                         ks * 32 + lg * 8);
            #pragma unroll
            for (int mi = 0; mi < 4; ++mi)
                acc1[mi][ni] = __builtin_amdgcn_mfma_f32_16x16x32_bf16(
                    a[mi], bv, acc1[mi][ni], 0, 0, 0);
        }
    }
    #pragma unroll
    for (int ni = 0; ni < 2; ++ni) {
        int n = wn + ni * 16 + lm;
        float bb = cb1[n];
        int gn = n >> 3, ne = n & 7;
        #pragma unroll
        for (int mi = 0; mi < 4; ++mi)
            #pragma unroll
            for (int r = 0; r < 4; ++r) {
                int row = mi * 16 + lg * 4 + r;
                Hs[row * 128 + ((gn ^ (row & 7)) * 8 + ne)] =
                    f2bf(gelu_f(acc1[mi][ni][r] + bb));
            }
    }
    __syncthreads();
    f32x4 acc2[2];
    acc2[0] = 0.f; acc2[1] = 0.f;
    #pragma unroll
    for (int ks = 0; ks < 4; ++ks) {
        int row = w * 16 + lm;
        int g = ks * 4 + lg;
        bf16x8 a2 = *(const bf16x8*)(Hs + row * 128 + ((g ^ (row & 7)) * 8));
        #pragma unroll
        for (int ni = 0; ni < 2; ++ni) {
            bf16x8 bv = *(const bf16x8*)(cw2T + (size_t)(ni * 16 + lm) * 128 +
                                         ks * 32 + lg * 8);
            acc2[ni] = __builtin_amdgcn_mfma_f32_16x16x32_bf16(a2, bv, acc2[ni], 0, 0, 0);
        }
    }
    {
        unsigned short* T = sm;
        __syncthreads();
        #pragma unroll
        for (int ni = 0; ni < 2; ++ni) {
            int d = ni * 16 + lm;
            float bb = cb2[d];
            #pragma unroll
            for (int r = 0; r < 4; ++r) {
                int p = w * 16 + lg * 4 + r;
                T[d * 64 + p] = f2bf(acc2[ni][r] + bb);
            }
        }
        __syncthreads();
        int d = t >> 3, slot = t & 7;
        bf16x8 v = *(const bf16x8*)(T + d * 64 + slot * 8);
        *(bf16x8*)(pairT + ((size_t)b * DP + d) * PP + pbase + slot * 8) = v;
    }
}

// ---------------------------------------------------------------------------
// Kernel B (big): gav + grv + ew1/ew2 conversions + afv copy.  LDS 32KB.
//   [0,1024):    gav 16-row tiles, b = bid&7 (XCD-pinned), rt = bid>>3 = n.
//                Double-buffered K-tile 128; ~4 blocks/CU.
//   [1024,1536): grv per b, 64-row tiles (self-staged afv transpose in LDS)
//   [1536,2816): ew1 -> ew1bT
//   [2816,2944): ew2 -> ew2bT
//   [2944,3008): afv copy -> out2
// ---------------------------------------------------------------------------
__global__ __launch_bounds__(256) void gav_k(
    const float* __restrict__ ga, const unsigned short* __restrict__ pairT,
    unsigned short* __restrict__ Xb,
    const float* __restrict__ gr, const float* __restrict__ afv,
    const float* __restrict__ ew1, unsigned short* __restrict__ ew1bT,
    const float* __restrict__ ew2, unsigned short* __restrict__ ew2bT,
    float* __restrict__ out2)
{
    __shared__ unsigned short sm[16384];   // 32KB multi-purpose
    const int bid = blockIdx.x;
    const int t = threadIdx.x;
    const int w = t >> 6, lane = t & 63;
    const int lm = lane & 15, lg = lane >> 4;

    if (bid >= 2944) {
        int idx = (bid - 2944) * 256 + t;   // 16384 f4
        float4 v = *(const float4*)(afv + (size_t)idx * 4);
        *(float4*)(out2 + (size_t)idx * 4) = v;
        return;
    }
    if (bid >= 2816) {
        int q = (bid - 2816) * 256 + t;     // 0..32767
        int n = q & 255;
        int k0 = (q >> 8) * 4;
        ushort4 o;
        o.x = f2bf(ew2[(size_t)(k0 + 0) * EE + n]);
        o.y = f2bf(ew2[(size_t)(k0 + 1) * EE + n]);
        o.z = f2bf(ew2[(size_t)(k0 + 2) * EE + n]);
        o.w = f2bf(ew2[(size_t)(k0 + 3) * EE + n]);
        *(ushort4*)(ew2bT + (size_t)n * HH + k0) = o;
        return;
    }
    if (bid >= 1536) {
        int q = (bid - 1536) * 256 + t;     // 0..327679
        int n = q & 511;
        int k0 = (q >> 9) * 4;
        ushort4 o;
        o.x = f2bf(ew1[(size_t)(k0 + 0) * HH + n]);
        o.y = f2bf(ew1[(size_t)(k0 + 1) * HH + n]);
        o.z = f2bf(ew1[(size_t)(k0 + 2) * HH + n]);
        o.w = f2bf(ew1[(size_t)(k0 + 3) * HH + n]);
        *(ushort4*)(ew1bT + (size_t)n * XDIM + k0) = o;
        return;
    }

    if (bid >= 1024) {
        // ---------------- grv MFMA path, 64-row tiles (32KB LDS) ----------------
        const int gb = bid - 1024;
        const int b = gb >> 6;
        const int rbase = (gb & 63) * 64;
        const float* gab = gr + ((size_t)b * 4096 + rbase) * NN;
        unsigned short* As  = sm;            // [64][128] bf16 swizzled (16KB)
        unsigned short* Bs2 = sm + 8192;     // [64][128] bf16 swizzled (16KB)
        // stage gr f32 -> bf16 LDS: thread (srow2 = t>>2, q4 = t&3) covers k q4*32..+31
        {
            const int srow2 = t >> 2, q4 = t & 3;
            const float* arow = gab + (size_t)srow2 * NN + q4 * 32;
            #pragma unroll
            for (int j = 0; j < 4; ++j) {
                float4 x0 = *(const float4*)(arow + j * 8);
                float4 x1 = *(const float4*)(arow + j * 8 + 4);
                bf16x8 v = pack_bf16x8(x0, x1);
                int g = 4 * q4 + j;
                *(bf16x8*)(As + srow2 * 128 + ((g ^ (srow2 & 7)) * 8)) = v;
            }
        }
        // stage afv[b] transposed: Bs2[a][m]
        #pragma unroll
        for (int q = 0; q < 8; ++q) {
            int pos = t + q * 256;           // 2048 f4: 128 m x 16 f4
            int m = pos >> 4, f4i = pos & 15;
            float4 v = *(const float4*)(afv + (size_t)(b * NN + m) * AA + f4i * 4);
            int gm = m >> 3, me = m & 7;
            float vv[4] = {v.x, v.y, v.z, v.w};
            #pragma unroll
            for (int i = 0; i < 4; ++i) {
                int a = f4i * 4 + i;
                Bs2[a * 128 + ((gm ^ (a & 7)) * 8 + me)] = f2bf(vv[i]);
            }
        }
        __syncthreads();
        const int wm = w * 16;
        f32x4 acc[4];
        #pragma unroll
        for (int j = 0; j < 4; ++j) acc[j] = 0.f;
        #pragma unroll
        for (int ks = 0; ks < 4; ++ks) {
            int g = ks * 4 + lg;
            int r0 = wm + lm;
            bf16x8 a0 = *(const bf16x8*)(As + r0 * 128 + ((g ^ (r0 & 7)) * 8));
            #pragma unroll
            for (int ni = 0; ni < 4; ++ni) {
                int a = ni * 16 + lm;
                bf16x8 bv = *(const bf16x8*)(Bs2 + a * 128 + ((g ^ (a & 7)) * 8));
                acc[ni] = __builtin_amdgcn_mfma_f32_16x16x32_bf16(a0, bv, acc[ni], 0, 0, 0);
            }
        }
        __syncthreads();
        unsigned short* T = sm;             // [64][64] bf16 (8KB)
        #pragma unroll
        for (int ni = 0; ni < 4; ++ni)
            #pragma unroll
            for (int r = 0; r < 4; ++r)
                T[(wm + lg * 4 + r) * 64 + ni * 16 + lm] = f2bf(acc[ni][r]);
        __syncthreads();
        #pragma unroll
        for (int q = 0; q < 2; ++q) {
            int idx = t + q * 256;          // 512 bf16x8 slots
            int rr2 = idx >> 3, slot = idx & 7;
            bf16x8 v = *(const bf16x8*)(T + rr2 * 64 + slot * 8);
            int grow = rbase + rr2;
            *(bf16x8*)(Xb + ((size_t)(b * NN) + (grow >> 5)) * XDIM +
                       (grow & 31) * 64 + slot * 8) = v;
        }
        return;
    }

    // ---------------- gav (XCD-pinned by b, 16-row tiles, double-buffered) ----
    const int b = bid & 7, rt = bid >> 3;     // rt = n (0..127)
    const int rbase = rt * 16;
    const int srow = t >> 4, slot = t & 15;   // A staging: 16 rows x 16 k-slots
    const int bd = t >> 3, bslot = t & 7;     // B staging: 32 d x 8 slots (x2 halves)
    const int wc = w * 16;                    // waves 0,1 compute; 2,3 stage-only

    f32x4 acc = 0.f;

    const float* gab = ga + (size_t)(b * 2048 + rbase) * PP;
    const unsigned short* pbT = pairT + (size_t)b * DP * PP;

    float4 ra0, ra1;
    bf16x8 rb0, rb1;

#define GAV_LOAD(IT)                                                         \
    {                                                                        \
        int kn = (IT) * 128 + slot * 8;                                      \
        if (kn > PP - 8) kn = PP - 8;          /* tail clamp (junk unread) */ \
        ra0 = *(const float4*)(gab + (size_t)srow * PP + kn);                \
        ra1 = *(const float4*)(gab + (size_t)srow * PP + kn + 4);            \
        int kb = (IT) * 128 + bslot * 8;                                     \
        int kb1 = kb + 64; if (kb1 > PP - 8) kb1 = PP - 8;                   \
        rb0 = *(const bf16x8*)(pbT + (size_t)bd * PP + kb);                  \
        rb1 = *(const bf16x8*)(pbT + (size_t)bd * PP + kb1);                 \
    }

#define GAV_WRITE(BUF)                                                      \
    {                                                                        \
        unsigned short* A_ = sm + (BUF) * 6144;                              \
        unsigned short* B_ = A_ + 2048;                                      \
        int gA = slot ^ (srow & 7);                                          \
        *(bf16x8*)(A_ + srow * 128 + gA * 8) = pack_bf16x8(ra0, ra1);        \
        int gB = bslot ^ (bd & 7);                                           \
        *(bf16x8*)(B_ + bd * 128 + gB * 8) = rb0;                            \
        *(bf16x8*)(B_ + bd * 128 + (gB + 8) * 8) = rb1;                      \
    }

    GAV_LOAD(0);
    GAV_WRITE(0);
    __syncthreads();
    GAV_LOAD(1);

    for (int it = 0; it < 64; ++it) {
        const int cur = it & 1;
        const unsigned short* Ac = sm + cur * 6144;
        const unsigned short* Bc = Ac + 2048;
        if (it + 1 < 64) GAV_WRITE(cur ^ 1);
        if (it + 2 < 64) GAV_LOAD(it + 2);
        if (w < 2) {
            const int nk = (it < 63) ? 4 : 2;    // tail: only k 8064..8127 valid
            for (int ks = 0; ks < nk; ++ks) {
                int gg = ks * 4 + lg;
                int rowb = wc + lm;
                bf16x8 a  = *(const bf16x8*)(Ac + lm * 128 + ((gg ^ (lm & 7)) * 8));
                bf16x8 bv = *(const bf16x8*)(Bc + rowb * 128 + ((gg ^ (rowb & 7)) * 8));
                acc = __builtin_amdgcn_mfma_f32_16x16x32_bf16(a, bv, acc, 0, 0, 0);
            }
        }
        __syncthreads();
    }
    // C layout: col = lane&15, row = (lane>>4)*4 + reg.  Block = one n (=rt).
    if (w < 2) {
        #pragma unroll
        for (int r = 0; r < 4; ++r) {
            int a2 = lg * 4 + r;
            Xb[(size_t)(b * NN + rt) * XDIM + 2048 + a2 * DP + wc + lm] = f2bf(acc[r]);
        }
    }
}

// ---------------------------------------------------------------------------
// Kernel C: mlp layer1, 32x32 tiles, grid 512, XCD-swizzled, double-buffered,
// K-tile 128 (20 iters), fused bias+gelu -> Hb bf16.  LDS 32KB.
// ---------------------------------------------------------------------------
__global__ __launch_bounds__(256) void mlp1_k(
    const unsigned short* __restrict__ Xb,
    const unsigned short* __restrict__ Wt,
    const float* __restrict__ eb1, unsigned short* __restrict__ Hb)
{
    __shared__ unsigned short sm[16384];   // 32KB: 2 x (A 8KB + B 8KB)
    const int bid = blockIdx.x;
    const int xcd = bid & 7, idx = bid >> 3;      // idx 0..63
    const int rt = (xcd << 2) | (idx & 3);        // 0..31
    const int ct = idx >> 2;                      // 0..15
    const int rbase = rt * 32, nbase = ct * 32;
    const int t = threadIdx.x;
    const int w = t >> 6, lane = t & 63;
    const int lm = lane & 15, lg = lane >> 4;
    const int wr = (w & 1) * 16, wc = (w >> 1) * 16;
    const int srow = t >> 3, sg = t & 7;

    f32x4 acc = 0.f;

    const unsigned short* Arow = Xb + (size_t)(rbase + srow) * XDIM;
    const unsigned short* Brow = Wt + (size_t)(nbase + srow) * XDIM;

    bf16x8 rA0, rA1, rB0, rB1;

#define M1_LOAD(IT)  { int kn = (IT) * 128 + sg * 8;                         \
                       rA0 = *(const bf16x8*)(Arow + kn);                    \
                       rA1 = *(const bf16x8*)(Arow + kn + 64);               \
                       rB0 = *(const bf16x8*)(Brow + kn);                    \
                       rB1 = *(const bf16x8*)(Brow + kn + 64); }
#define M1_WRITE(BUF) { unsigned short* A_ = sm + (BUF) * 8192;              \
                        unsigned short* B_ = A_ + 4096;                      \
                        int g0 = sg ^ (srow & 7);                            \
                        *(bf16x8*)(A_ + srow * 128 + g0 * 8) = rA0;          \
                        *(bf16x8*)(A_ + srow * 128 + (g0 + 8) * 8) = rA1;    \
                        *(bf16x8*)(B_ + srow * 128 + g0 * 8) = rB0;          \
                        *(bf16x8*)(B_ + srow * 128 + (g0 + 8) * 8) = rB1; }

    M1_LOAD(0); M1_WRITE(0);
    __syncthreads();
    M1_LOAD(1);

    for (int it = 0; it < 20; ++it) {
        const int cur = it & 1;
        const unsigned short* Ac = sm + cur * 8192;
        const unsigned short* Bc = Ac + 4096;
        if (it + 1 < 20) M1_WRITE(cur ^ 1);
        if (it + 2 < 20) M1_LOAD(it + 2);
        #pragma unroll
        for (int ks = 0; ks < 4; ++ks) {
            int g = ks * 4 + lg;
            int r0 = wr + lm, r1 = wc + lm;
            bf16x8 a  = *(const bf16x8*)(Ac + r0 * 128 + ((g ^ (r0 & 7)) * 8));
            bf16x8 bv = *(const bf16x8*)(Bc + r1 * 128 + ((g ^ (r1 & 7)) * 8));
            acc = __builtin_amdgcn_mfma_f32_16x16x32_bf16(a, bv, acc, 0, 0, 0);
        }
        __syncthreads();
    }
    const int col = nbase + wc + lm;
    const float bb = eb1[col];
    #pragma unroll
    for (int r = 0; r < 4; ++r) {
        int row = rbase + wr + lg * 4 + r;
        Hb[(size_t)row * HH + col] = f2bf(gelu_f(acc[r] + bb));
    }
}

// ---------------------------------------------------------------------------
// Kernel D: mlp layer2, 32x32 tiles, grid 256, XCD-swizzled, double-buffered,
// K-tile 128 (4 iters), f32 out + eb2.  LDS 32KB.
// ---------------------------------------------------------------------------
__global__ __launch_bounds__(256) void mlp2_k(
    const unsigned short* __restrict__ Hb,
    const unsigned short* __restrict__ Wt,
    const float* __restrict__ eb2, float* __restrict__ out)
{
    __shared__ unsigned short sm[16384];
    const int bid = blockIdx.x;
    const int xcd = bid & 7, idx = bid >> 3;      // idx 0..31
    const int rt = (xcd << 2) | (idx & 3);        // 0..31
    const int ct = idx >> 2;                      // 0..7
    const int rbase = rt * 32, nbase = ct * 32;
    const int t = threadIdx.x;
    const int w = t >> 6, lane = t & 63;
    const int lm = lane & 15, lg = lane >> 4;
    const int wr = (w & 1) * 16, wc = (w >> 1) * 16;
    const int srow = t >> 3, sg = t & 7;

    f32x4 acc = 0.f;

    const unsigned short* Arow = Hb + (size_t)(rbase + srow) * HH;
    const unsigned short* Brow = Wt + (size_t)(nbase + srow) * HH;

    bf16x8 rA0, rA1, rB0, rB1;

#define M2_LOAD(IT)  { int kn = (IT) * 128 + sg * 8;                         \
                       rA0 = *(const bf16x8*)(Arow + kn);                    \
                       rA1 = *(const bf16x8*)(Arow + kn + 64);               \
                       rB0 = *(const bf16x8*)(Brow + kn);                    \
                       rB1 = *(const bf16x8*)(Brow + kn + 64); }
#define M2_WRITE(BUF) { unsigned short* A_ = sm + (BUF) * 8192;              \
                        unsigned short* B_ = A_ + 4096;                      \
                        int g0 = sg ^ (srow & 7);                            \
                        *(bf16x8*)(A_ + srow * 128 + g0 * 8) = rA0;          \
                        *(bf16x8*)(A_ + srow * 128 + (g0 + 8) * 8) = rA1;    \
                        *(bf16x8*)(B_ + srow * 128 + g0 * 8) = rB0;          \
                        *(bf16x8*)(B_ + srow * 128 + (g0 + 8) * 8) = rB1; }

    M2_LOAD(0); M2_WRITE(0);
    __syncthreads();
    M2_LOAD(1);

    for (int it = 0; it < 4; ++it) {
        const int cur = it & 1;
        const unsigned short* Ac = sm + cur * 8192;
        const unsigned short* Bc = Ac + 4096;
        if (it + 1 < 4) M2_WRITE(cur ^ 1);
        if (it + 2 < 4) M2_LOAD(it + 2);
        #pragma unroll
        for (int ks = 0; ks < 4; ++ks) {
            int g = ks * 4 + lg;
            int r0 = wr + lm, r1 = wc + lm;
            bf16x8 a  = *(const bf16x8*)(Ac + r0 * 128 + ((g ^ (r0 & 7)) * 8));
            bf16x8 bv = *(const bf16x8*)(Bc + r1 * 128 + ((g ^ (r1 & 7)) * 8));
            acc = __builtin_amdgcn_mfma_f32_16x16x32_bf16(a, bv, acc, 0, 0, 0);
        }
        __syncthreads();
    }
    const int col = nbase + wc + lm;
    const float bb = eb2[col];
    #pragma unroll
    for (int r = 0; r < 4; ++r) {
        int row = rbase + wr + lg * 4 + r;
        out[(size_t)row * EE + col] = acc[r] + bb;
    }
}

extern "C" void kernel_launch(void* const* d_in, const int* in_sizes, int n_in,
                              void* d_out, int out_size, void* d_ws, size_t ws_size,
                              hipStream_t stream) {
    const float* gr  = (const float*)d_in[0];
    const float* ga  = (const float*)d_in[1];
    const float* afv = (const float*)d_in[2];
    const float* cw1 = (const float*)d_in[3];
    const float* cb1 = (const float*)d_in[4];
    const float* cw2 = (const float*)d_in[5];
    const float* cb2 = (const float*)d_in[6];
    const float* ew1 = (const float*)d_in[7];
    const float* eb1 = (const float*)d_in[8];
    const float* ew2 = (const float*)d_in[9];
    const float* eb2 = (const float*)d_in[10];
    float* out = (float*)d_out;
    float* ws = (float*)d_ws;

    unsigned short* pairT  = (unsigned short*)(ws + WS_PAIRT);
    unsigned short* Xb     = (unsigned short*)(ws + WS_XB);
    unsigned short* ew1bT  = (unsigned short*)(ws + WS_EW1B);
    unsigned short* cw1T   = (unsigned short*)(ws + WS_CW1T);
    unsigned short* cw2T   = (unsigned short*)(ws + WS_CW2T);
    unsigned short* ew2bT  = (unsigned short*)(ws + WS_EW2B);
    unsigned short* Hb     = (unsigned short*)(ws + WS_HB);

    prep_k<<<dim3(20), dim3(256), 0, stream>>>(cw1, cw2, cw1T, cw2T);
    stage1_k<<<dim3(1016), dim3(256), 0, stream>>>(afv, cw1T, cb1, cw2T, cb2, pairT);
    gav_k<<<dim3(3008), dim3(256), 0, stream>>>(ga, pairT, Xb, gr, afv,
                                                ew1, ew1bT, ew2, ew2bT,
                                                out + (size_t)BB * NN * EE);
    mlp1_k<<<dim3(512), dim3(256), 0, stream>>>(Xb, ew1bT, eb1, Hb);
    mlp2_k<<<dim3(256), dim3(256), 0, stream>>>(Hb, ew2bT, eb2, out);
}